// Round 1
// baseline (2810.664 us; speedup 1.0000x reference)
//
#include <hip/hip_runtime.h>
#include <hip/hip_bf16.h>
#include <cstdint>
#include <cstddef>

// GLA forward, fp32 baseline.
// B=2, T=2048, D=1024, H=4, HK=256, HV=512, DK=1024, DV=2048, LR=16

#define NH 4
#define TSEQ 2048

// ---------------- fp32 tiled GEMM: C = A[MxK] @ B[KxN] (row-major) --------
// mode 0: plain row-major C[m*N+n]
// mode 1: head-major remap: b=m>>11, t=m&2047, h=n>>hdshift, hd=n&(HD-1)
//         C[(((b*NH+h)*TSEQ)+t)*HD + hd]
__global__ __launch_bounds__(256) void gemm_f32(
    const float* __restrict__ A, const float* __restrict__ B, float* __restrict__ C,
    int M, int N, int K, int mode, int hdshift, float scale)
{
  __shared__ float As[8][132];   // padded stride to break store conflicts
  __shared__ float Bs[8][128];
  const int tid = threadIdx.x;
  const int tx = tid & 15, ty = tid >> 4;
  const int arow = tid >> 1, acol = (tid & 1) * 4;
  const int brow = tid >> 5, bcol = (tid & 31) * 4;
  const int m0 = blockIdx.y * 128, n0 = blockIdx.x * 128;
  const float* Ap = A + (size_t)(m0 + arow) * K + acol;
  const float* Bp = B + (size_t)brow * N + n0 + bcol;

  float acc[8][8];
#pragma unroll
  for (int i = 0; i < 8; ++i)
#pragma unroll
    for (int j = 0; j < 8; ++j) acc[i][j] = 0.f;

  for (int k0 = 0; k0 < K; k0 += 8) {
    const float4 av = *(const float4*)(Ap + k0);
    const float4 bv = *(const float4*)(Bp + (size_t)k0 * N);
    __syncthreads();
    As[acol + 0][arow] = av.x;
    As[acol + 1][arow] = av.y;
    As[acol + 2][arow] = av.z;
    As[acol + 3][arow] = av.w;
    *(float4*)&Bs[brow][bcol] = bv;
    __syncthreads();
#pragma unroll
    for (int kk = 0; kk < 8; ++kk) {
      const float4 a0 = *(const float4*)&As[kk][ty * 8];
      const float4 a1 = *(const float4*)&As[kk][ty * 8 + 4];
      const float4 b0 = *(const float4*)&Bs[kk][tx * 8];
      const float4 b1 = *(const float4*)&Bs[kk][tx * 8 + 4];
      const float ar[8] = {a0.x, a0.y, a0.z, a0.w, a1.x, a1.y, a1.z, a1.w};
      const float br[8] = {b0.x, b0.y, b0.z, b0.w, b1.x, b1.y, b1.z, b1.w};
#pragma unroll
      for (int i = 0; i < 8; ++i)
#pragma unroll
        for (int j = 0; j < 8; ++j) acc[i][j] = fmaf(ar[i], br[j], acc[i][j]);
    }
  }

  // epilogue: each thread owns rows m0+ty*8.. (8), cols n0+tx*8.. (8 consecutive)
#pragma unroll
  for (int i = 0; i < 8; ++i) {
    const int m = m0 + ty * 8 + i;
    const int n = n0 + tx * 8;
    const float4 lo = make_float4(acc[i][0] * scale, acc[i][1] * scale,
                                  acc[i][2] * scale, acc[i][3] * scale);
    const float4 hi = make_float4(acc[i][4] * scale, acc[i][5] * scale,
                                  acc[i][6] * scale, acc[i][7] * scale);
    if (mode == 0) {
      float* p = C + (size_t)m * N + n;
      *(float4*)p = lo;
      *(float4*)(p + 4) = hi;
    } else {
      const int bb = m >> 11, tt = m & 2047;
      const int HD = 1 << hdshift;
      const int h = n >> hdshift, hd = n & (HD - 1);
      float* p = C + (((size_t)(bb * NH + h)) * TSEQ + tt) * HD + hd;
      *(float4*)p = lo;
      *(float4*)(p + 4) = hi;
    }
  }
}

// ---------------- low-rank gate part 1: tmp[4096,16] = x @ w1[1024,16] ----
__global__ __launch_bounds__(256) void lowrank1(
    const float* __restrict__ x, const float* __restrict__ w1, float* __restrict__ tmp)
{
  const int idx = blockIdx.x * 256 + threadIdx.x;   // 65536 outputs
  const int m = idx >> 4, i = idx & 15;
  const float* xr = x + (size_t)m * 1024;
  float acc = 0.f;
#pragma unroll 4
  for (int kk = 0; kk < 1024; kk += 4) {
    const float4 xv = *(const float4*)(xr + kk);
    acc = fmaf(xv.x, w1[(kk + 0) * 16 + i], acc);
    acc = fmaf(xv.y, w1[(kk + 1) * 16 + i], acc);
    acc = fmaf(xv.z, w1[(kk + 2) * 16 + i], acc);
    acc = fmaf(xv.w, w1[(kk + 3) * 16 + i], acc);
  }
  tmp[idx] = acc;
}

// ------- gate part 2: eg[b,h,t,hk] = exp(log_sigmoid(tmp@w2 + b)/16) ------
__global__ __launch_bounds__(256) void gatek(
    const float* __restrict__ tmp, const float* __restrict__ w2,
    const float* __restrict__ bias, float* __restrict__ eg)
{
  const int idx = blockIdx.x * 256 + threadIdx.x;   // 4096*1024
  const int m = idx >> 10, n = idx & 1023;
  const float* tr = tmp + m * 16;
  float acc = bias[n];
#pragma unroll
  for (int i = 0; i < 16; ++i) acc = fmaf(tr[i], w2[i * 1024 + n], acc);
  // stable log_sigmoid
  const float ls = fminf(acc, 0.f) - log1pf(expf(-fabsf(acc)));
  const float e = expf(ls * (1.f / 16.f));
  const int b = m >> 11, t = m & 2047, h = n >> 8, hk = n & 255;
  eg[(((size_t)(b * NH + h)) * TSEQ + t) * 256 + hk] = e;
}

// ---------------- sequential scan ----------------
// grid 256 blocks: block = (bh in 0..7) x (vtile of 16 cols).
// Each wave owns 4 full columns; lane owns 4 rows (row = lane*4) x 4 cols.
__global__ __launch_bounds__(256) void scan_kernel(
    const float* __restrict__ q, const float* __restrict__ k,
    const float* __restrict__ eg, const float* __restrict__ v,
    float* __restrict__ o)
{
  const int blk = blockIdx.x;
  const int bh = blk >> 5;          // 0..7  (b*4+h)
  const int vt = blk & 31;          // 16-col tile
  const int lane = threadIdx.x & 63;
  const int wv = threadIdx.x >> 6;  // wave id 0..3
  const int col = vt * 16 + wv * 4; // in [0,512)
  const int row = lane * 4;         // rows row..row+3

  const float* qb = q + (size_t)bh * (TSEQ * 256) + row;
  const float* kb = k + (size_t)bh * (TSEQ * 256) + row;
  const float* eb = eg + (size_t)bh * (TSEQ * 256) + row;
  const float* vp = v + (size_t)bh * (TSEQ * 512) + col;
  float* ob = o + (size_t)(bh >> 2) * (TSEQ * 2048) + (bh & 3) * 512 + col;

  float s[4][4];
#pragma unroll
  for (int i = 0; i < 4; ++i)
#pragma unroll
    for (int j = 0; j < 4; ++j) s[i][j] = 0.f;

  for (int t = 0; t < TSEQ; ++t) {
    const float4 qr = *(const float4*)(qb + t * 256);
    const float4 kr = *(const float4*)(kb + t * 256);
    const float4 er = *(const float4*)(eb + t * 256);
    const float4 vv = *(const float4*)(vp + t * 512);
    float p0, p1, p2, p3;
    // row 0
    s[0][0] = er.x * s[0][0] + kr.x * vv.x;  p0 = qr.x * s[0][0];
    s[0][1] = er.x * s[0][1] + kr.x * vv.y;  p1 = qr.x * s[0][1];
    s[0][2] = er.x * s[0][2] + kr.x * vv.z;  p2 = qr.x * s[0][2];
    s[0][3] = er.x * s[0][3] + kr.x * vv.w;  p3 = qr.x * s[0][3];
    // row 1
    s[1][0] = er.y * s[1][0] + kr.y * vv.x;  p0 += qr.y * s[1][0];
    s[1][1] = er.y * s[1][1] + kr.y * vv.y;  p1 += qr.y * s[1][1];
    s[1][2] = er.y * s[1][2] + kr.y * vv.z;  p2 += qr.y * s[1][2];
    s[1][3] = er.y * s[1][3] + kr.y * vv.w;  p3 += qr.y * s[1][3];
    // row 2
    s[2][0] = er.z * s[2][0] + kr.z * vv.x;  p0 += qr.z * s[2][0];
    s[2][1] = er.z * s[2][1] + kr.z * vv.y;  p1 += qr.z * s[2][1];
    s[2][2] = er.z * s[2][2] + kr.z * vv.z;  p2 += qr.z * s[2][2];
    s[2][3] = er.z * s[2][3] + kr.z * vv.w;  p3 += qr.z * s[2][3];
    // row 3
    s[3][0] = er.w * s[3][0] + kr.w * vv.x;  p0 += qr.w * s[3][0];
    s[3][1] = er.w * s[3][1] + kr.w * vv.y;  p1 += qr.w * s[3][1];
    s[3][2] = er.w * s[3][2] + kr.w * vv.z;  p2 += qr.w * s[3][2];
    s[3][3] = er.w * s[3][3] + kr.w * vv.w;  p3 += qr.w * s[3][3];
    // reduce across 64 lanes (all 256 rows)
#pragma unroll
    for (int off = 1; off < 64; off <<= 1) {
      p0 += __shfl_xor(p0, off, 64);
      p1 += __shfl_xor(p1, off, 64);
      p2 += __shfl_xor(p2, off, 64);
      p3 += __shfl_xor(p3, off, 64);
    }
    if (lane == 0)
      *(float4*)(ob + (size_t)t * 2048) = make_float4(p0, p1, p2, p3);
  }
}

// ---------------- group RMSNorm (512) + SiLU output gate, in-place on o ---
__global__ __launch_bounds__(256) void rms_silu(
    float* __restrict__ o, const float* __restrict__ gpre, const float* __restrict__ w)
{
  const int grp = blockIdx.x * 4 + (threadIdx.x >> 6);  // 16384 groups (b,t,h)
  const int lane = threadIdx.x & 63;
  const size_t base = (size_t)(grp >> 2) * 2048 + (grp & 3) * 512;
  float xv[8];
  float ss = 0.f;
#pragma unroll
  for (int i = 0; i < 8; ++i) {
    xv[i] = o[base + i * 64 + lane];
    ss = fmaf(xv[i], xv[i], ss);
  }
#pragma unroll
  for (int off = 1; off < 64; off <<= 1) ss += __shfl_xor(ss, off, 64);
  const float r = rsqrtf(ss * (1.f / 512.f) + 1e-5f);
#pragma unroll
  for (int i = 0; i < 8; ++i) {
    const int c = i * 64 + lane;
    const float gp = gpre[base + c];
    const float sig = 1.f / (1.f + expf(-gp));
    o[base + c] = xv[i] * r * w[c] * gp * sig;
  }
}

extern "C" void kernel_launch(void* const* d_in, const int* in_sizes, int n_in,
                              void* d_out, int out_size, void* d_ws, size_t ws_size,
                              hipStream_t stream) {
  const float* x    = (const float*)d_in[0];
  const float* Wq   = (const float*)d_in[1];
  const float* Wk   = (const float*)d_in[2];
  const float* Wv   = (const float*)d_in[3];
  const float* Wg   = (const float*)d_in[4];
  const float* w1   = (const float*)d_in[5];
  const float* w2   = (const float*)d_in[6];
  const float* gb   = (const float*)d_in[7];
  const float* Wo   = (const float*)d_in[8];
  const float* rmsw = (const float*)d_in[9];
  float* out = (float*)d_out;

  float* ws   = (float*)d_ws;
  float* qb   = ws;                  // [B,H,T,256]  4,194,304
  float* kb   = qb + 4194304;        // 4,194,304
  float* egb  = kb + 4194304;        // 4,194,304
  float* vb   = egb + 4194304;       // [B,H,T,512]  8,388,608
  float* gpre = vb + 8388608;        // [4096,2048]  8,388,608
  float* ob   = gpre + 8388608;      // [4096,2048]  8,388,608
  float* tmp  = ob + 8388608;        // [4096,16]    65,536

  // projections (x is [4096,1024] row-major)
  hipLaunchKernelGGL(gemm_f32, dim3(8, 32), dim3(256), 0, stream,
                     x, Wq, qb, 4096, 1024, 1024, 1, 8, 0.0625f);  // q * HK^-0.5
  hipLaunchKernelGGL(gemm_f32, dim3(8, 32), dim3(256), 0, stream,
                     x, Wk, kb, 4096, 1024, 1024, 1, 8, 1.f);
  hipLaunchKernelGGL(gemm_f32, dim3(16, 32), dim3(256), 0, stream,
                     x, Wv, vb, 4096, 2048, 1024, 1, 9, 1.f);
  hipLaunchKernelGGL(gemm_f32, dim3(16, 32), dim3(256), 0, stream,
                     x, Wg, gpre, 4096, 2048, 1024, 0, 0, 1.f);
  // low-rank forget gate
  hipLaunchKernelGGL(lowrank1, dim3(256), dim3(256), 0, stream, x, w1, tmp);
  hipLaunchKernelGGL(gatek, dim3(16384), dim3(256), 0, stream, tmp, w2, gb, egb);
  // sequential linear-attention scan
  hipLaunchKernelGGL(scan_kernel, dim3(256), dim3(256), 0, stream, qb, kb, egb, vb, ob);
  // group RMSNorm + SiLU gate (in place on ob)
  hipLaunchKernelGGL(rms_silu, dim3(4096), dim3(256), 0, stream, ob, gpre, rmsw);
  // output projection
  hipLaunchKernelGGL(gemm_f32, dim3(8, 32), dim3(256), 0, stream,
                     ob, Wo, out, 4096, 1024, 2048, 0, 0, 1.f);
}

// Round 2
// 1863.860 us; speedup vs baseline: 1.5080x; 1.5080x over previous
//
#include <hip/hip_runtime.h>
#include <hip/hip_bf16.h>
#include <cstdint>
#include <cstddef>

// GLA forward, fp32, chunked scan (C=128).
// B=2, T=2048, D=1024, H=4, HK=256, HV=512, DK=1024, DV=2048, LR=16

#define NH 4
#define TSEQ 2048
#define CHUNK 128
#define NCHUNK 16

// ---------------- fp32 tiled GEMM: C = A[MxK] @ B[KxN] (row-major) --------
// mode 0: plain row-major C[m*N+n]
// mode 1: head-major remap: b=m>>11, t=m&2047, h=n>>hdshift, hd=n&(HD-1)
__global__ __launch_bounds__(256) void gemm_f32(
    const float* __restrict__ A, const float* __restrict__ B, float* __restrict__ C,
    int M, int N, int K, int mode, int hdshift, float scale)
{
  __shared__ float As[8][132];
  __shared__ float Bs[8][128];
  const int tid = threadIdx.x;
  const int tx = tid & 15, ty = tid >> 4;
  const int arow = tid >> 1, acol = (tid & 1) * 4;
  const int brow = tid >> 5, bcol = (tid & 31) * 4;
  const int m0 = blockIdx.y * 128, n0 = blockIdx.x * 128;
  const float* Ap = A + (size_t)(m0 + arow) * K + acol;
  const float* Bp = B + (size_t)brow * N + n0 + bcol;

  float acc[8][8];
#pragma unroll
  for (int i = 0; i < 8; ++i)
#pragma unroll
    for (int j = 0; j < 8; ++j) acc[i][j] = 0.f;

  for (int k0 = 0; k0 < K; k0 += 8) {
    const float4 av = *(const float4*)(Ap + k0);
    const float4 bv = *(const float4*)(Bp + (size_t)k0 * N);
    __syncthreads();
    As[acol + 0][arow] = av.x;
    As[acol + 1][arow] = av.y;
    As[acol + 2][arow] = av.z;
    As[acol + 3][arow] = av.w;
    *(float4*)&Bs[brow][bcol] = bv;
    __syncthreads();
#pragma unroll
    for (int kk = 0; kk < 8; ++kk) {
      const float4 a0 = *(const float4*)&As[kk][ty * 8];
      const float4 a1 = *(const float4*)&As[kk][ty * 8 + 4];
      const float4 b0 = *(const float4*)&Bs[kk][tx * 8];
      const float4 b1 = *(const float4*)&Bs[kk][tx * 8 + 4];
      const float ar[8] = {a0.x, a0.y, a0.z, a0.w, a1.x, a1.y, a1.z, a1.w};
      const float br[8] = {b0.x, b0.y, b0.z, b0.w, b1.x, b1.y, b1.z, b1.w};
#pragma unroll
      for (int i = 0; i < 8; ++i)
#pragma unroll
        for (int j = 0; j < 8; ++j) acc[i][j] = fmaf(ar[i], br[j], acc[i][j]);
    }
  }

#pragma unroll
  for (int i = 0; i < 8; ++i) {
    const int m = m0 + ty * 8 + i;
    const int n = n0 + tx * 8;
    const float4 lo = make_float4(acc[i][0] * scale, acc[i][1] * scale,
                                  acc[i][2] * scale, acc[i][3] * scale);
    const float4 hi = make_float4(acc[i][4] * scale, acc[i][5] * scale,
                                  acc[i][6] * scale, acc[i][7] * scale);
    if (mode == 0) {
      float* p = C + (size_t)m * N + n;
      *(float4*)p = lo;
      *(float4*)(p + 4) = hi;
    } else {
      const int bb = m >> 11, tt = m & 2047;
      const int HD = 1 << hdshift;
      const int h = n >> hdshift, hd = n & (HD - 1);
      float* p = C + (((size_t)(bb * NH + h)) * TSEQ + tt) * HD + hd;
      *(float4*)p = lo;
      *(float4*)(p + 4) = hi;
    }
  }
}

// ---------------- low-rank gate part 1: tmp[4096,16] = x @ w1[1024,16] ----
__global__ __launch_bounds__(256) void lowrank1(
    const float* __restrict__ x, const float* __restrict__ w1, float* __restrict__ tmp)
{
  const int idx = blockIdx.x * 256 + threadIdx.x;
  const int m = idx >> 4, i = idx & 15;
  const float* xr = x + (size_t)m * 1024;
  float acc = 0.f;
#pragma unroll 4
  for (int kk = 0; kk < 1024; kk += 4) {
    const float4 xv = *(const float4*)(xr + kk);
    acc = fmaf(xv.x, w1[(kk + 0) * 16 + i], acc);
    acc = fmaf(xv.y, w1[(kk + 1) * 16 + i], acc);
    acc = fmaf(xv.z, w1[(kk + 2) * 16 + i], acc);
    acc = fmaf(xv.w, w1[(kk + 3) * 16 + i], acc);
  }
  tmp[idx] = acc;
}

// --------- gate + chunk cumsum: in-place q *= e^B, k *= e^-B; Dc = e^B_last
// grid 128 = (bh, c); block 256 = i (key-dim lane)
__global__ __launch_bounds__(256) void gate_chunk(
    const float* __restrict__ tmp, const float* __restrict__ w2,
    const float* __restrict__ bias, float* __restrict__ q, float* __restrict__ k,
    float* __restrict__ Dc)
{
  const int bh = blockIdx.x >> 4;
  const int c = blockIdx.x & 15;
  const int i = threadIdx.x;
  const int b = bh >> 2, h = bh & 3;
  const int n = h * 256 + i;
  float w2c[16];
#pragma unroll
  for (int r = 0; r < 16; ++r) w2c[r] = w2[r * 1024 + n];
  const float bn = bias[n];
  const int t0 = c * CHUNK;
  const float* tmpp = tmp + ((size_t)(b * TSEQ + t0)) * 16;
  float* qp = q + ((size_t)bh * TSEQ + t0) * 256 + i;
  float* kp = k + ((size_t)bh * TSEQ + t0) * 256 + i;
  float B = 0.f, eB = 1.f;
  for (int t = 0; t < CHUNK; ++t) {
    float acc = bn;
    const float* tr = tmpp + t * 16;
#pragma unroll
    for (int r = 0; r < 16; ++r) acc = fmaf(tr[r], w2c[r], acc);
    const float ls = fminf(acc, 0.f) - log1pf(expf(-fabsf(acc)));
    B += ls * (1.f / 16.f);
    eB = expf(B);
    qp[t * 256] *= eB;
    kp[t * 256] *= (1.f / eB);
  }
  Dc[(bh * NCHUNK + c) * 256 + i] = eB;
}

// ---------------- U_c[i][j] = sum_s kt[s][i] * v[s][j]  (per bh,chunk) ----
// grid: x = it*4+jt (8), y = bh*16+c (128); block 256
__global__ __launch_bounds__(256) void chunk_state(
    const float* __restrict__ kt, const float* __restrict__ v, float* __restrict__ U)
{
  const int bhc = blockIdx.y;
  const int bh = bhc >> 4, c = bhc & 15;
  const int it = blockIdx.x >> 2, jt = blockIdx.x & 3;
  const int i0 = it * 128, j0 = jt * 128;
  const int tid = threadIdx.x;
  const int tx = tid & 15, ty = tid >> 4;
  const int lr = tid >> 5, lc = (tid & 31) * 4;
  __shared__ float As[8][132];   // As[s][i]
  __shared__ float Bs[8][128];   // Bs[s][j]
  const int sbase = c * CHUNK;
  const float* ktp = kt + ((size_t)bh * TSEQ + sbase) * 256 + i0;
  const float* vp = v + ((size_t)bh * TSEQ + sbase) * 512 + j0;

  float acc[8][8];
#pragma unroll
  for (int i = 0; i < 8; ++i)
#pragma unroll
    for (int j = 0; j < 8; ++j) acc[i][j] = 0.f;

  for (int s0 = 0; s0 < CHUNK; s0 += 8) {
    const float4 av = *(const float4*)(ktp + (size_t)(s0 + lr) * 256 + lc);
    const float4 bv = *(const float4*)(vp + (size_t)(s0 + lr) * 512 + lc);
    __syncthreads();
    *(float4*)&As[lr][lc] = av;
    *(float4*)&Bs[lr][lc] = bv;
    __syncthreads();
#pragma unroll
    for (int ss = 0; ss < 8; ++ss) {
      const float4 a0 = *(const float4*)&As[ss][ty * 8];
      const float4 a1 = *(const float4*)&As[ss][ty * 8 + 4];
      const float4 b0 = *(const float4*)&Bs[ss][tx * 8];
      const float4 b1 = *(const float4*)&Bs[ss][tx * 8 + 4];
      const float ar[8] = {a0.x, a0.y, a0.z, a0.w, a1.x, a1.y, a1.z, a1.w};
      const float br[8] = {b0.x, b0.y, b0.z, b0.w, b1.x, b1.y, b1.z, b1.w};
#pragma unroll
      for (int i = 0; i < 8; ++i)
#pragma unroll
        for (int j = 0; j < 8; ++j) acc[i][j] = fmaf(ar[i], br[j], acc[i][j]);
    }
  }
  float* Up = U + (((size_t)bhc * 256) + i0 + ty * 8) * 512 + j0 + tx * 8;
#pragma unroll
  for (int i = 0; i < 8; ++i) {
    *(float4*)(Up + (size_t)i * 512) = make_float4(acc[i][0], acc[i][1], acc[i][2], acc[i][3]);
    *(float4*)(Up + (size_t)i * 512 + 4) = make_float4(acc[i][4], acc[i][5], acc[i][6], acc[i][7]);
  }
}

// ------------- serial inter-chunk state scan, IN PLACE on U --------------
// After this kernel U[bh][c] holds S_c (state at chunk start).
__global__ __launch_bounds__(256) void state_scan(
    float* __restrict__ U, const float* __restrict__ Dc)
{
  const size_t idx = (size_t)blockIdx.x * 256 + threadIdx.x;  // bh*131072 + i*512 + j
  const int bh = (int)(idx >> 17);
  const int ij = (int)(idx & 131071);
  const int i = ij >> 9;
  float S = 0.f;
  float* Up = U + (size_t)bh * NCHUNK * 131072 + ij;
  const float* Dp = Dc + bh * NCHUNK * 256 + i;
  for (int c = 0; c < NCHUNK; ++c) {
    const float u = Up[(size_t)c * 131072];
    Up[(size_t)c * 131072] = S;
    S = Dp[c * 256] * (S + u);
  }
}

// ------------- A = causal(qt @ kt^T) per (bh, c): [128x128], K=256 --------
__global__ __launch_bounds__(256) void qk_chunk(
    const float* __restrict__ qt, const float* __restrict__ kt, float* __restrict__ Aw)
{
  const int bhc = blockIdx.x;
  const int bh = bhc >> 4, c = bhc & 15;
  const int tid = threadIdx.x;
  const int tx = tid & 15, ty = tid >> 4;
  const int arow = tid >> 1, acol = (tid & 1) * 4;
  __shared__ float Qs[8][132];   // Qs[kk][t]
  __shared__ float Ks[8][132];   // Ks[kk][s]
  const float* qp = qt + ((size_t)bh * TSEQ + c * CHUNK) * 256;
  const float* kp = kt + ((size_t)bh * TSEQ + c * CHUNK) * 256;

  float acc[8][8];
#pragma unroll
  for (int i = 0; i < 8; ++i)
#pragma unroll
    for (int j = 0; j < 8; ++j) acc[i][j] = 0.f;

  for (int k0 = 0; k0 < 256; k0 += 8) {
    const float4 av = *(const float4*)(qp + (size_t)arow * 256 + k0 + acol);
    const float4 bv = *(const float4*)(kp + (size_t)arow * 256 + k0 + acol);
    __syncthreads();
    Qs[acol + 0][arow] = av.x; Qs[acol + 1][arow] = av.y;
    Qs[acol + 2][arow] = av.z; Qs[acol + 3][arow] = av.w;
    Ks[acol + 0][arow] = bv.x; Ks[acol + 1][arow] = bv.y;
    Ks[acol + 2][arow] = bv.z; Ks[acol + 3][arow] = bv.w;
    __syncthreads();
#pragma unroll
    for (int kk = 0; kk < 8; ++kk) {
      const float4 a0 = *(const float4*)&Qs[kk][ty * 8];
      const float4 a1 = *(const float4*)&Qs[kk][ty * 8 + 4];
      const float4 b0 = *(const float4*)&Ks[kk][tx * 8];
      const float4 b1 = *(const float4*)&Ks[kk][tx * 8 + 4];
      const float ar[8] = {a0.x, a0.y, a0.z, a0.w, a1.x, a1.y, a1.z, a1.w};
      const float br[8] = {b0.x, b0.y, b0.z, b0.w, b1.x, b1.y, b1.z, b1.w};
#pragma unroll
      for (int i = 0; i < 8; ++i)
#pragma unroll
        for (int j = 0; j < 8; ++j) acc[i][j] = fmaf(ar[i], br[j], acc[i][j]);
    }
  }
  float* Ap = Aw + (size_t)bhc * (CHUNK * CHUNK);
#pragma unroll
  for (int i = 0; i < 8; ++i) {
    const int t = ty * 8 + i;
#pragma unroll
    for (int j = 0; j < 8; ++j) {
      const int s = tx * 8 + j;
      Ap[t * CHUNK + s] = (s <= t) ? acc[i][j] : 0.f;
    }
  }
}

// -------- o = A @ V + qt @ S_c  (per bh, c, 128-col tile) -----------------
// grid: x = jt (4), y = bh*16+c (128); block 256
__global__ __launch_bounds__(256) void intra(
    const float* __restrict__ Aw, const float* __restrict__ qt,
    const float* __restrict__ v, const float* __restrict__ S, float* __restrict__ o)
{
  const int bhc = blockIdx.y;
  const int bh = bhc >> 4, c = bhc & 15;
  const int j0 = blockIdx.x * 128;
  const int tid = threadIdx.x;
  const int tx = tid & 15, ty = tid >> 4;
  const int arow = tid >> 1, acol = (tid & 1) * 4;
  const int lr = tid >> 5, lc = (tid & 31) * 4;
  __shared__ float As[8][132];
  __shared__ float Bs[8][128];

  float acc[8][8];
#pragma unroll
  for (int i = 0; i < 8; ++i)
#pragma unroll
    for (int j = 0; j < 8; ++j) acc[i][j] = 0.f;

  // phase 1: A[128x128] @ V[128x128 tile]
  const float* Ap = Aw + (size_t)bhc * (CHUNK * CHUNK);
  const float* vp = v + ((size_t)bh * TSEQ + c * CHUNK) * 512 + j0;
  for (int k0 = 0; k0 < CHUNK; k0 += 8) {
    const float4 av = *(const float4*)(Ap + (size_t)arow * CHUNK + k0 + acol);
    const float4 bv = *(const float4*)(vp + (size_t)(k0 + lr) * 512 + lc);
    __syncthreads();
    As[acol + 0][arow] = av.x; As[acol + 1][arow] = av.y;
    As[acol + 2][arow] = av.z; As[acol + 3][arow] = av.w;
    *(float4*)&Bs[lr][lc] = bv;
    __syncthreads();
#pragma unroll
    for (int kk = 0; kk < 8; ++kk) {
      const float4 a0 = *(const float4*)&As[kk][ty * 8];
      const float4 a1 = *(const float4*)&As[kk][ty * 8 + 4];
      const float4 b0 = *(const float4*)&Bs[kk][tx * 8];
      const float4 b1 = *(const float4*)&Bs[kk][tx * 8 + 4];
      const float ar[8] = {a0.x, a0.y, a0.z, a0.w, a1.x, a1.y, a1.z, a1.w};
      const float br[8] = {b0.x, b0.y, b0.z, b0.w, b1.x, b1.y, b1.z, b1.w};
#pragma unroll
      for (int i = 0; i < 8; ++i)
#pragma unroll
        for (int j = 0; j < 8; ++j) acc[i][j] = fmaf(ar[i], br[j], acc[i][j]);
    }
  }
  // phase 2: qt[128x256] @ S[256x128 tile]
  const float* qp = qt + ((size_t)bh * TSEQ + c * CHUNK) * 256;
  const float* Sp = S + ((size_t)bhc * 256) * 512 + j0;
  for (int k0 = 0; k0 < 256; k0 += 8) {
    const float4 av = *(const float4*)(qp + (size_t)arow * 256 + k0 + acol);
    const float4 bv = *(const float4*)(Sp + (size_t)(k0 + lr) * 512 + lc);
    __syncthreads();
    As[acol + 0][arow] = av.x; As[acol + 1][arow] = av.y;
    As[acol + 2][arow] = av.z; As[acol + 3][arow] = av.w;
    *(float4*)&Bs[lr][lc] = bv;
    __syncthreads();
#pragma unroll
    for (int kk = 0; kk < 8; ++kk) {
      const float4 a0 = *(const float4*)&As[kk][ty * 8];
      const float4 a1 = *(const float4*)&As[kk][ty * 8 + 4];
      const float4 b0 = *(const float4*)&Bs[kk][tx * 8];
      const float4 b1 = *(const float4*)&Bs[kk][tx * 8 + 4];
      const float ar[8] = {a0.x, a0.y, a0.z, a0.w, a1.x, a1.y, a1.z, a1.w};
      const float br[8] = {b0.x, b0.y, b0.z, b0.w, b1.x, b1.y, b1.z, b1.w};
#pragma unroll
      for (int i = 0; i < 8; ++i)
#pragma unroll
        for (int j = 0; j < 8; ++j) acc[i][j] = fmaf(ar[i], br[j], acc[i][j]);
    }
  }
  // epilogue: o[b][t][h*512 + j0 + col]
  const int b = bh >> 2, h = bh & 3;
  float* op = o + ((size_t)(b * TSEQ + c * CHUNK + ty * 8)) * 2048 + h * 512 + j0 + tx * 8;
#pragma unroll
  for (int i = 0; i < 8; ++i) {
    *(float4*)(op + (size_t)i * 2048) = make_float4(acc[i][0], acc[i][1], acc[i][2], acc[i][3]);
    *(float4*)(op + (size_t)i * 2048 + 4) = make_float4(acc[i][4], acc[i][5], acc[i][6], acc[i][7]);
  }
}

// ---------------- group RMSNorm (512) + SiLU output gate, in-place on o ---
__global__ __launch_bounds__(256) void rms_silu(
    float* __restrict__ o, const float* __restrict__ gpre, const float* __restrict__ w)
{
  const int grp = blockIdx.x * 4 + (threadIdx.x >> 6);
  const int lane = threadIdx.x & 63;
  const size_t base = (size_t)(grp >> 2) * 2048 + (grp & 3) * 512;
  float xv[8];
  float ss = 0.f;
#pragma unroll
  for (int i = 0; i < 8; ++i) {
    xv[i] = o[base + i * 64 + lane];
    ss = fmaf(xv[i], xv[i], ss);
  }
#pragma unroll
  for (int off = 1; off < 64; off <<= 1) ss += __shfl_xor(ss, off, 64);
  const float r = rsqrtf(ss * (1.f / 512.f) + 1e-5f);
#pragma unroll
  for (int i = 0; i < 8; ++i) {
    const int c = i * 64 + lane;
    const float gp = gpre[base + c];
    const float sig = 1.f / (1.f + expf(-gp));
    o[base + c] = xv[i] * r * w[c] * gp * sig;
  }
}

extern "C" void kernel_launch(void* const* d_in, const int* in_sizes, int n_in,
                              void* d_out, int out_size, void* d_ws, size_t ws_size,
                              hipStream_t stream) {
  const float* x    = (const float*)d_in[0];
  const float* Wq   = (const float*)d_in[1];
  const float* Wk   = (const float*)d_in[2];
  const float* Wv   = (const float*)d_in[3];
  const float* Wg   = (const float*)d_in[4];
  const float* w1   = (const float*)d_in[5];
  const float* w2   = (const float*)d_in[6];
  const float* gb   = (const float*)d_in[7];
  const float* Wo   = (const float*)d_in[8];
  const float* rmsw = (const float*)d_in[9];
  float* out = (float*)d_out;

  float* ws   = (float*)d_ws;
  float* qb   = ws;                  // [8][2048][256]   4,194,304
  float* kb   = qb + 4194304;        //                  4,194,304
  float* vb   = kb + 4194304;        // [8][2048][512]   8,388,608
  float* gpre = vb + 8388608;        // [4096][2048]     8,388,608
  float* ob   = gpre + 8388608;      // [4096][2048]     8,388,608
  float* tmp  = ob + 8388608;        // [4096][16]       65,536
  float* Dc   = tmp + 65536;         // [8][16][256]     32,768
  float* Aw   = Dc + 32768;          // [8][16][128][128] 2,097,152
  float* Uw   = Aw + 2097152;        // [8][16][256][512] 16,777,216
  // total ~52.5M floats = 210 MB

  // projections
  hipLaunchKernelGGL(gemm_f32, dim3(8, 32), dim3(256), 0, stream,
                     x, Wq, qb, 4096, 1024, 1024, 1, 8, 0.0625f);
  hipLaunchKernelGGL(gemm_f32, dim3(8, 32), dim3(256), 0, stream,
                     x, Wk, kb, 4096, 1024, 1024, 1, 8, 1.f);
  hipLaunchKernelGGL(gemm_f32, dim3(16, 32), dim3(256), 0, stream,
                     x, Wv, vb, 4096, 2048, 1024, 1, 9, 1.f);
  hipLaunchKernelGGL(gemm_f32, dim3(16, 32), dim3(256), 0, stream,
                     x, Wg, gpre, 4096, 2048, 1024, 0, 0, 1.f);
  // low-rank forget gate -> in-place q *= e^B, k *= e^-B, chunk decays Dc
  hipLaunchKernelGGL(lowrank1, dim3(256), dim3(256), 0, stream, x, w1, tmp);
  hipLaunchKernelGGL(gate_chunk, dim3(128), dim3(256), 0, stream,
                     tmp, w2, gb, qb, kb, Dc);
  // chunked scan
  hipLaunchKernelGGL(chunk_state, dim3(8, 128), dim3(256), 0, stream, kb, vb, Uw);
  hipLaunchKernelGGL(state_scan, dim3(4096), dim3(256), 0, stream, Uw, Dc);
  hipLaunchKernelGGL(qk_chunk, dim3(128), dim3(256), 0, stream, qb, kb, Aw);
  hipLaunchKernelGGL(intra, dim3(4, 128), dim3(256), 0, stream, Aw, qb, vb, Uw, ob);
  // group RMSNorm + SiLU gate (in place on ob)
  hipLaunchKernelGGL(rms_silu, dim3(4096), dim3(256), 0, stream, ob, gpre, rmsw);
  // output projection
  hipLaunchKernelGGL(gemm_f32, dim3(8, 32), dim3(256), 0, stream,
                     ob, Wo, out, 4096, 1024, 2048, 0, 0, 1.f);
}

// Round 3
// 359.381 us; speedup vs baseline: 7.8209x; 5.1863x over previous
//
#include <hip/hip_runtime.h>
#include <cstdint>
#include <cstddef>

// GLA forward, bf16 MFMA pipeline.
// B=2, T=2048, D=1024, H=4, HK=256, HV=512, DK=1024, DV=2048, LR=16, CHUNK=128

typedef unsigned short u16;
typedef __attribute__((ext_vector_type(8))) short s8v;   // 8 x bf16 (4 VGPR)
typedef __attribute__((ext_vector_type(4))) float f4v;   // MFMA accumulator

__device__ __forceinline__ u16 f2b(float f) {
  unsigned u = __builtin_bit_cast(unsigned, f);
  unsigned r = u + 0x7FFFu + ((u >> 16) & 1u);   // RNE
  return (u16)(r >> 16);
}
__device__ __forceinline__ float b2f(u16 h) {
  unsigned u = ((unsigned)h) << 16;
  return __builtin_bit_cast(float, u);
}

// async global->LDS, 16B per lane; LDS dest is wave-uniform base + lane*16
__device__ __forceinline__ void cp16(const void* g, void* l) {
  __builtin_amdgcn_global_load_lds(
      (const __attribute__((address_space(1))) unsigned int*)g,
      (__attribute__((address_space(3))) unsigned int*)l, 16, 0, 0);
}

// ---- shared MFMA core: C[128x128] += A[128xK] * BT[128xK]^T, bf16, BK=32 ----
// A, BT pre-offset to tile start. lda/ldb in elements. As/Bs: 4096 u16 each.
__device__ __forceinline__ void stage_tile(const u16* g, int ld, u16* lds,
                                           int wv, int ln) {
#pragma unroll
  for (int i = 0; i < 2; ++i) {
    const int c = wv * 2 + i;                       // 1KB chunk id 0..7
    const u16* src = g + (size_t)(c * 16 + (ln >> 2)) * ld + (ln & 3) * 8;
    cp16(src, lds + c * 512);                       // base uniform per wave
  }
}

__device__ __forceinline__ void gemm_core(
    const u16* __restrict__ A, int lda, const u16* __restrict__ BT, int ldb,
    int K, u16* As, u16* Bs, f4v acc[4][4])
{
  const int tid = threadIdx.x;
  const int ln = tid & 63, wv = tid >> 6;
  const int wr = wv >> 1, wc = wv & 1;
  const int arow = wr * 64 + (ln & 15);
  const int brow = wc * 64 + (ln & 15);
  const int kq = (ln >> 4) * 8;
  for (int k0 = 0; k0 < K; k0 += 32) {
    stage_tile(A + k0, lda, As, wv, ln);
    stage_tile(BT + k0, ldb, Bs, wv, ln);
    __syncthreads();                 // drains vmcnt -> staged data visible
    s8v af[4], bf[4];
#pragma unroll
    for (int f = 0; f < 4; ++f)
      af[f] = *(const s8v*)(As + (arow + f * 16) * 32 + kq);
#pragma unroll
    for (int f = 0; f < 4; ++f)
      bf[f] = *(const s8v*)(Bs + (brow + f * 16) * 32 + kq);
#pragma unroll
    for (int mf = 0; mf < 4; ++mf)
#pragma unroll
      for (int nf = 0; nf < 4; ++nf)
        acc[mf][nf] = __builtin_amdgcn_mfma_f32_16x16x32_bf16(
            af[mf], bf[nf], acc[mf][nf], 0, 0, 0);
    __syncthreads();                 // reads done before next stage
  }
}

#define EPI_SETUP                                            \
  const int tid = threadIdx.x;                               \
  const int ln = tid & 63, wv = tid >> 6;                    \
  const int wr = wv >> 1, wc = wv & 1;

#define ZERO_ACC(acc)                                        \
  _Pragma("unroll")                                          \
  for (int zi = 0; zi < 4; ++zi)                             \
    _Pragma("unroll")                                        \
    for (int zj = 0; zj < 4; ++zj)                           \
      acc[zi][zj] = (f4v){0.f, 0.f, 0.f, 0.f};

// ---------------- elementwise / transpose helpers ----------------
__global__ __launch_bounds__(256) void cast_b(const float* __restrict__ in,
                                              u16* __restrict__ out) {
  const int i = blockIdx.x * 256 + threadIdx.x;   // one float4 per thread
  const float4 v = ((const float4*)in)[i];
  u16* p = out + i * 4;
  p[0] = f2b(v.x); p[1] = f2b(v.y); p[2] = f2b(v.z); p[3] = f2b(v.w);
}

// W [R][C] f32 -> WT [C][R] bf16
__global__ __launch_bounds__(256) void wtrans(const float* __restrict__ in,
                                              u16* __restrict__ out, int R, int C) {
  __shared__ float t[32][33];
  const int c0 = blockIdx.x * 32, r0 = blockIdx.y * 32;
  const int lx = threadIdx.x & 31, ly = threadIdx.x >> 5;
#pragma unroll
  for (int i = 0; i < 32; i += 8)
    t[ly + i][lx] = in[(size_t)(r0 + ly + i) * C + c0 + lx];
  __syncthreads();
#pragma unroll
  for (int i = 0; i < 32; i += 8)
    out[(size_t)(c0 + ly + i) * R + r0 + lx] = f2b(t[lx][ly + i]);
}

// bf16 [z][R][C] -> [z][C][R]
__global__ __launch_bounds__(256) void trans_b16(const u16* __restrict__ in,
                                                 u16* __restrict__ out, int R, int C) {
  __shared__ u16 t[32][33];
  const size_t boff = (size_t)blockIdx.z * R * C;
  const int c0 = blockIdx.x * 32, r0 = blockIdx.y * 32;
  const int lx = threadIdx.x & 31, ly = threadIdx.x >> 5;
#pragma unroll
  for (int i = 0; i < 32; i += 8)
    t[ly + i][lx] = in[boff + (size_t)(r0 + ly + i) * C + c0 + lx];
  __syncthreads();
#pragma unroll
  for (int i = 0; i < 32; i += 8)
    out[boff + (size_t)(c0 + ly + i) * R + r0 + lx] = t[lx][ly + i];
}

// ---------------- fused projections: xb[4096,1024] @ [Wq|Wk|Wv|Wg] ----------
// WT rows: 0..1023 WqT, 1024..2047 WkT, 2048..4095 WvT, 4096..6143 WgT
__global__ __launch_bounds__(256) void proj_all(
    const u16* __restrict__ xb, const u16* __restrict__ WT,
    u16* __restrict__ qh, u16* __restrict__ kh, u16* __restrict__ vT,
    u16* __restrict__ gpre)
{
  __shared__ __align__(16) u16 As[4096], Bs[4096];
  const int m0 = blockIdx.y * 128, n0 = blockIdx.x * 128;
  f4v acc[4][4];
  ZERO_ACC(acc)
  gemm_core(xb + (size_t)m0 * 1024, 1024, WT + (size_t)n0 * 1024, 1024, 1024,
            As, Bs, acc);
  EPI_SETUP
#pragma unroll
  for (int mf = 0; mf < 4; ++mf)
#pragma unroll
    for (int nf = 0; nf < 4; ++nf)
#pragma unroll
      for (int r = 0; r < 4; ++r) {
        const int m = m0 + wr * 64 + mf * 16 + ((ln >> 4) << 2) + r;
        const int n = n0 + wc * 64 + nf * 16 + (ln & 15);
        const float val = acc[mf][nf][r];
        const int b = m >> 11, t = m & 2047;
        if (n0 < 1024) {
          qh[(((size_t)(b * 4 + (n >> 8))) * 2048 + t) * 256 + (n & 255)] =
              f2b(val * 0.0625f);
        } else if (n0 < 2048) {
          const int nn = n - 1024;
          kh[(((size_t)(b * 4 + (nn >> 8))) * 2048 + t) * 256 + (nn & 255)] =
              f2b(val);
        } else if (n0 < 4096) {
          const int nn = n - 2048;
          vT[(((size_t)(b * 4 + (nn >> 9))) * 512 + (nn & 511)) * 2048 + t] =
              f2b(val);
        } else {
          gpre[(size_t)m * 2048 + (n - 4096)] = f2b(val);
        }
      }
}

// ---------------- final: out[4096,1024] = ob[4096,2048] @ Wo ----------------
__global__ __launch_bounds__(256) void gemm_out(
    const u16* __restrict__ ob, const u16* __restrict__ WoT,
    float* __restrict__ out)
{
  __shared__ __align__(16) u16 As[4096], Bs[4096];
  const int m0 = blockIdx.y * 128, n0 = blockIdx.x * 128;
  f4v acc[4][4];
  ZERO_ACC(acc)
  gemm_core(ob + (size_t)m0 * 2048, 2048, WoT + (size_t)n0 * 2048, 2048, 2048,
            As, Bs, acc);
  EPI_SETUP
#pragma unroll
  for (int mf = 0; mf < 4; ++mf)
#pragma unroll
    for (int nf = 0; nf < 4; ++nf)
#pragma unroll
      for (int r = 0; r < 4; ++r) {
        const int m = m0 + wr * 64 + mf * 16 + ((ln >> 4) << 2) + r;
        const int n = n0 + wc * 64 + nf * 16 + (ln & 15);
        out[(size_t)m * 1024 + n] = acc[mf][nf][r];
      }
}

// ---------------- low-rank gate part 1: tmp[4096,16] = x @ w1 ----------------
__global__ __launch_bounds__(256) void lowrank1(
    const float* __restrict__ x, const float* __restrict__ w1,
    float* __restrict__ tmp)
{
  const int idx = blockIdx.x * 256 + threadIdx.x;
  const int m = idx >> 4, i = idx & 15;
  const float* xr = x + (size_t)m * 1024;
  float acc = 0.f;
#pragma unroll 4
  for (int kk = 0; kk < 1024; kk += 4) {
    const float4 xv = *(const float4*)(xr + kk);
    acc = fmaf(xv.x, w1[(kk + 0) * 16 + i], acc);
    acc = fmaf(xv.y, w1[(kk + 1) * 16 + i], acc);
    acc = fmaf(xv.z, w1[(kk + 2) * 16 + i], acc);
    acc = fmaf(xv.w, w1[(kk + 3) * 16 + i], acc);
  }
  tmp[idx] = acc;
}

// --------- gate + chunk cumsum: qt = q*e^B, kt = k*e^-B (bf16); Dc = e^B_last
__global__ __launch_bounds__(256) void gate_chunk(
    const float* __restrict__ tmp, const float* __restrict__ w2,
    const float* __restrict__ bias, const u16* __restrict__ qh,
    const u16* __restrict__ kh, u16* __restrict__ qt, u16* __restrict__ kt,
    float* __restrict__ Dc)
{
  const int bh = blockIdx.x >> 4;
  const int c = blockIdx.x & 15;
  const int i = threadIdx.x;
  const int b = bh >> 2, h = bh & 3;
  const int n = h * 256 + i;
  float w2c[16];
#pragma unroll
  for (int r = 0; r < 16; ++r) w2c[r] = w2[r * 1024 + n];
  const float bn = bias[n];
  const int t0 = c * 128;
  const float* tmpp = tmp + ((size_t)(b * 2048 + t0)) * 16;
  const size_t off0 = ((size_t)bh * 2048 + t0) * 256 + i;
  float B = 0.f, eB = 1.f;
  for (int t = 0; t < 128; ++t) {
    float acc = bn;
    const float* tr = tmpp + t * 16;
#pragma unroll
    for (int r = 0; r < 16; ++r) acc = fmaf(tr[r], w2c[r], acc);
    const float ls = fminf(acc, 0.f) - log1pf(expf(-fabsf(acc)));
    B += ls * 0.0625f;
    eB = expf(B);
    const size_t off = off0 + (size_t)t * 256;
    qt[off] = f2b(b2f(qh[off]) * eB);
    kt[off] = f2b(b2f(kh[off]) / eB);
  }
  Dc[(bh * 16 + c) * 256 + i] = eB;
}

// ---------------- UT[bhc][j][i] = sum_s vT[j][s] * ktT[i][s] ----------------
__global__ __launch_bounds__(256) void chunk_state_k(
    const u16* __restrict__ vT, const u16* __restrict__ ktT, u16* __restrict__ UT)
{
  __shared__ __align__(16) u16 As[4096], Bs[4096];
  const int bhc = blockIdx.y, bh = bhc >> 4, c = bhc & 15;
  const int mt = blockIdx.x >> 1, nt = blockIdx.x & 1;
  f4v acc[4][4];
  ZERO_ACC(acc)
  gemm_core(vT + ((size_t)bh * 512 + mt * 128) * 2048 + c * 128, 2048,
            ktT + ((size_t)bh * 256 + nt * 128) * 2048 + c * 128, 2048, 128,
            As, Bs, acc);
  EPI_SETUP
  u16* Up = UT + (size_t)bhc * 131072;
#pragma unroll
  for (int mf = 0; mf < 4; ++mf)
#pragma unroll
    for (int nf = 0; nf < 4; ++nf)
#pragma unroll
      for (int r = 0; r < 4; ++r) {
        const int ml = mt * 128 + wr * 64 + mf * 16 + ((ln >> 4) << 2) + r;
        const int nl = nt * 128 + wc * 64 + nf * 16 + (ln & 15);
        Up[(size_t)ml * 256 + nl] = f2b(acc[mf][nf][r]);
      }
}

// ------ serial inter-chunk scan, in place on UT (bf16, fp32 accum) ----------
__global__ __launch_bounds__(256) void state_scan(
    u16* __restrict__ UT, const float* __restrict__ Dc)
{
  const size_t idx = (size_t)blockIdx.x * 256 + threadIdx.x;  // bh*131072+j*256+i
  const int bh = (int)(idx >> 17);
  const int ji = (int)(idx & 131071);
  const int i = ji & 255;
  u16* Up = UT + (size_t)bh * 16 * 131072 + ji;
  const float* Dp = Dc + bh * 16 * 256 + i;
  float S = 0.f;
  for (int c = 0; c < 16; ++c) {
    const float u = b2f(Up[(size_t)c * 131072]);
    Up[(size_t)c * 131072] = f2b(S);
    S = Dp[c * 256] * (S + u);
  }
}

// ---------------- Aw[bhc][t][s] = causal(qt @ kt^T), bf16 -------------------
__global__ __launch_bounds__(256) void qk_causal_k(
    const u16* __restrict__ qt, const u16* __restrict__ kt, u16* __restrict__ Aw)
{
  __shared__ __align__(16) u16 As[4096], Bs[4096];
  const int bhc = blockIdx.x, bh = bhc >> 4, c = bhc & 15;
  f4v acc[4][4];
  ZERO_ACC(acc)
  const size_t base = ((size_t)bh * 2048 + c * 128) * 256;
  gemm_core(qt + base, 256, kt + base, 256, 256, As, Bs, acc);
  EPI_SETUP
  u16* Ap = Aw + (size_t)bhc * 16384;
#pragma unroll
  for (int mf = 0; mf < 4; ++mf)
#pragma unroll
    for (int nf = 0; nf < 4; ++nf)
#pragma unroll
      for (int r = 0; r < 4; ++r) {
        const int t = wr * 64 + mf * 16 + ((ln >> 4) << 2) + r;
        const int s = wc * 64 + nf * 16 + (ln & 15);
        Ap[t * 128 + s] = (s <= t) ? f2b(acc[mf][nf][r]) : (u16)0;
      }
}

// -------- ob = Aw @ V + qt @ S  (per bhc, 128-col tile of HV) ---------------
__global__ __launch_bounds__(256) void intra_k(
    const u16* __restrict__ Aw, const u16* __restrict__ qt,
    const u16* __restrict__ vT, const u16* __restrict__ UT, u16* __restrict__ ob)
{
  __shared__ __align__(16) u16 As[4096], Bs[4096];
  const int jt = blockIdx.x;
  const int bhc = blockIdx.y, bh = bhc >> 4, c = bhc & 15;
  f4v acc[4][4];
  ZERO_ACC(acc)
  // phase 1: Aw[t][s] * vT[j][s]^T
  gemm_core(Aw + (size_t)bhc * 16384, 128,
            vT + ((size_t)bh * 512 + jt * 128) * 2048 + c * 128, 2048, 128,
            As, Bs, acc);
  // phase 2: qt[t][i] * S^T[j][i]^T  (UT holds S in [j][i] layout)
  gemm_core(qt + ((size_t)bh * 2048 + c * 128) * 256, 256,
            UT + (size_t)bhc * 131072 + (size_t)jt * 128 * 256, 256, 256,
            As, Bs, acc);
  EPI_SETUP
  const int b = bh >> 2, h = bh & 3;
#pragma unroll
  for (int mf = 0; mf < 4; ++mf)
#pragma unroll
    for (int nf = 0; nf < 4; ++nf)
#pragma unroll
      for (int r = 0; r < 4; ++r) {
        const int t = c * 128 + wr * 64 + mf * 16 + ((ln >> 4) << 2) + r;
        const int j = jt * 128 + wc * 64 + nf * 16 + (ln & 15);
        ob[((size_t)(b * 2048 + t)) * 2048 + h * 512 + j] = f2b(acc[mf][nf][r]);
      }
}

// ---------------- group RMSNorm (512) + SiLU gate, in place on ob -----------
__global__ __launch_bounds__(256) void rms_silu(
    u16* __restrict__ o, const u16* __restrict__ gpre, const float* __restrict__ w)
{
  const int grp = blockIdx.x * 4 + (threadIdx.x >> 6);
  const int lane = threadIdx.x & 63;
  const size_t base = (size_t)(grp >> 2) * 2048 + (grp & 3) * 512;
  float xv[8];
  float ss = 0.f;
#pragma unroll
  for (int i = 0; i < 8; ++i) {
    xv[i] = b2f(o[base + i * 64 + lane]);
    ss = fmaf(xv[i], xv[i], ss);
  }
#pragma unroll
  for (int off = 1; off < 64; off <<= 1) ss += __shfl_xor(ss, off, 64);
  const float r = rsqrtf(ss * (1.f / 512.f) + 1e-5f);
#pragma unroll
  for (int i = 0; i < 8; ++i) {
    const int cidx = i * 64 + lane;
    const float gp = b2f(gpre[base + cidx]);
    const float sig = 1.f / (1.f + expf(-gp));
    o[base + cidx] = f2b(xv[i] * r * w[cidx] * gp * sig);
  }
}

extern "C" void kernel_launch(void* const* d_in, const int* in_sizes, int n_in,
                              void* d_out, int out_size, void* d_ws, size_t ws_size,
                              hipStream_t stream) {
  const float* x    = (const float*)d_in[0];
  const float* Wq   = (const float*)d_in[1];
  const float* Wk   = (const float*)d_in[2];
  const float* Wv   = (const float*)d_in[3];
  const float* Wg   = (const float*)d_in[4];
  const float* w1   = (const float*)d_in[5];
  const float* w2   = (const float*)d_in[6];
  const float* gb   = (const float*)d_in[7];
  const float* Wo   = (const float*)d_in[8];
  const float* rmsw = (const float*)d_in[9];
  float* out = (float*)d_out;

  char* W = (char*)d_ws;
  u16*   xb   = (u16*)W;   W += (size_t)8  << 20;   // [4096][1024]
  u16*   WTa  = (u16*)W;   W += (size_t)12 << 20;   // [6144][1024]
  u16*   WoT  = (u16*)W;   W += (size_t)4  << 20;   // [1024][2048]
  u16*   qh   = (u16*)W;   W += (size_t)8  << 20;   // [8][2048][256]
  u16*   kh   = (u16*)W;   W += (size_t)8  << 20;
  u16*   vT   = (u16*)W;   W += (size_t)16 << 20;   // [8][512][2048]
  u16*   gpre = (u16*)W;   W += (size_t)16 << 20;   // [4096][2048]
  float* tmp  = (float*)W; W += (size_t)256 << 10;  // [4096][16]
  float* Dc   = (float*)W; W += (size_t)128 << 10;  // [8][16][256]
  u16*   qt   = (u16*)W;   W += (size_t)8  << 20;   // [8][2048][256]
  u16*   kt   = (u16*)W;   W += (size_t)8  << 20;
  u16*   ktT  = (u16*)W;   W += (size_t)8  << 20;   // [8][256][2048]
  u16*   UT   = (u16*)W;   W += (size_t)32 << 20;   // [128][512][256]
  u16*   Aw   = (u16*)W;   W += (size_t)4  << 20;   // [128][128][128]
  u16*   ob   = (u16*)W;   W += (size_t)16 << 20;   // [4096][2048]

  // bf16 conversions / weight transposes
  hipLaunchKernelGGL(cast_b, dim3(4096), dim3(256), 0, stream, x, xb);
  hipLaunchKernelGGL(wtrans, dim3(32, 32), dim3(256), 0, stream, Wq, WTa, 1024, 1024);
  hipLaunchKernelGGL(wtrans, dim3(32, 32), dim3(256), 0, stream, Wk, WTa + 1048576, 1024, 1024);
  hipLaunchKernelGGL(wtrans, dim3(64, 32), dim3(256), 0, stream, Wv, WTa + 2097152, 1024, 2048);
  hipLaunchKernelGGL(wtrans, dim3(64, 32), dim3(256), 0, stream, Wg, WTa + 4194304, 1024, 2048);
  hipLaunchKernelGGL(wtrans, dim3(32, 64), dim3(256), 0, stream, Wo, WoT, 2048, 1024);

  // fused q/k/v/g projections (MFMA)
  hipLaunchKernelGGL(proj_all, dim3(48, 32), dim3(256), 0, stream,
                     xb, WTa, qh, kh, vT, gpre);

  // low-rank forget gate, apply decay to q/k (bf16)
  hipLaunchKernelGGL(lowrank1, dim3(256), dim3(256), 0, stream, x, w1, tmp);
  hipLaunchKernelGGL(gate_chunk, dim3(128), dim3(256), 0, stream,
                     tmp, w2, gb, qh, kh, qt, kt, Dc);
  hipLaunchKernelGGL(trans_b16, dim3(8, 64, 8), dim3(256), 0, stream,
                     kt, ktT, 2048, 256);

  // chunked scan (all MFMA except the tiny serial pass)
  hipLaunchKernelGGL(chunk_state_k, dim3(8, 128), dim3(256), 0, stream, vT, ktT, UT);
  hipLaunchKernelGGL(state_scan, dim3(4096), dim3(256), 0, stream, UT, Dc);
  hipLaunchKernelGGL(qk_causal_k, dim3(128), dim3(256), 0, stream, qt, kt, Aw);
  hipLaunchKernelGGL(intra_k, dim3(4, 128), dim3(256), 0, stream, Aw, qt, vT, UT, ob);

  // group RMSNorm + SiLU gate (in place), then output projection (MFMA)
  hipLaunchKernelGGL(rms_silu, dim3(4096), dim3(256), 0, stream, ob, gpre, rmsw);
  hipLaunchKernelGGL(gemm_out, dim3(8, 32), dim3(256), 0, stream, ob, WoT, out);
}

// Round 4
// 336.160 us; speedup vs baseline: 8.3611x; 1.0691x over previous
//
#include <hip/hip_runtime.h>
#include <cstdint>
#include <cstddef>

// GLA forward, bf16 MFMA pipeline, fused gate decay + swizzled grids.
// B=2, T=2048, D=1024, H=4, HK=256, HV=512, DK=1024, DV=2048, LR=16, CHUNK=128

typedef unsigned short u16;
typedef __attribute__((ext_vector_type(8))) short s8v;   // 8 x bf16 (4 VGPR)
typedef __attribute__((ext_vector_type(4))) float f4v;   // MFMA accumulator

__device__ __forceinline__ u16 f2b(float f) {
  unsigned u = __builtin_bit_cast(unsigned, f);
  unsigned r = u + 0x7FFFu + ((u >> 16) & 1u);   // RNE
  return (u16)(r >> 16);
}
__device__ __forceinline__ float b2f(u16 h) {
  unsigned u = ((unsigned)h) << 16;
  return __builtin_bit_cast(float, u);
}

// async global->LDS, 16B per lane; LDS dest is wave-uniform base + lane*16
__device__ __forceinline__ void cp16(const void* g, void* l) {
  __builtin_amdgcn_global_load_lds(
      (const __attribute__((address_space(1))) unsigned int*)g,
      (__attribute__((address_space(3))) unsigned int*)l, 16, 0, 0);
}

// ---- shared MFMA core: C[128x128] += A[128xK] * BT[128xK]^T, bf16, BK=32 ----
__device__ __forceinline__ void stage_tile(const u16* g, int ld, u16* lds,
                                           int wv, int ln) {
#pragma unroll
  for (int i = 0; i < 2; ++i) {
    const int c = wv * 2 + i;                       // 1KB chunk id 0..7
    const u16* src = g + (size_t)(c * 16 + (ln >> 2)) * ld + (ln & 3) * 8;
    cp16(src, lds + c * 512);
  }
}

__device__ __forceinline__ void gemm_core(
    const u16* __restrict__ A, int lda, const u16* __restrict__ BT, int ldb,
    int K, u16* As, u16* Bs, f4v acc[4][4])
{
  const int tid = threadIdx.x;
  const int ln = tid & 63, wv = tid >> 6;
  const int wr = wv >> 1, wc = wv & 1;
  const int arow = wr * 64 + (ln & 15);
  const int brow = wc * 64 + (ln & 15);
  const int kq = (ln >> 4) * 8;
  for (int k0 = 0; k0 < K; k0 += 32) {
    stage_tile(A + k0, lda, As, wv, ln);
    stage_tile(BT + k0, ldb, Bs, wv, ln);
    __syncthreads();
    s8v af[4], bf[4];
#pragma unroll
    for (int f = 0; f < 4; ++f)
      af[f] = *(const s8v*)(As + (arow + f * 16) * 32 + kq);
#pragma unroll
    for (int f = 0; f < 4; ++f)
      bf[f] = *(const s8v*)(Bs + (brow + f * 16) * 32 + kq);
#pragma unroll
    for (int mf = 0; mf < 4; ++mf)
#pragma unroll
      for (int nf = 0; nf < 4; ++nf)
        acc[mf][nf] = __builtin_amdgcn_mfma_f32_16x16x32_bf16(
            af[mf], bf[nf], acc[mf][nf], 0, 0, 0);
    __syncthreads();
  }
}

#define EPI_SETUP                                            \
  const int tid = threadIdx.x;                               \
  const int ln = tid & 63, wv = tid >> 6;                    \
  const int wr = wv >> 1, wc = wv & 1;

#define ZERO_ACC(acc)                                        \
  _Pragma("unroll")                                          \
  for (int zi = 0; zi < 4; ++zi)                             \
    _Pragma("unroll")                                        \
    for (int zj = 0; zj < 4; ++zj)                           \
      acc[zi][zj] = (f4v){0.f, 0.f, 0.f, 0.f};

// ---------------- elementwise / transpose helpers ----------------
__global__ __launch_bounds__(256) void cast_b(const float* __restrict__ in,
                                              u16* __restrict__ out) {
  const int i = blockIdx.x * 256 + threadIdx.x;
  const float4 v = ((const float4*)in)[i];
  u16* p = out + i * 4;
  p[0] = f2b(v.x); p[1] = f2b(v.y); p[2] = f2b(v.z); p[3] = f2b(v.w);
}

// W [R][C] f32 -> WT [C][R] bf16
__global__ __launch_bounds__(256) void wtrans(const float* __restrict__ in,
                                              u16* __restrict__ out, int R, int C) {
  __shared__ float t[32][33];
  const int c0 = blockIdx.x * 32, r0 = blockIdx.y * 32;
  const int lx = threadIdx.x & 31, ly = threadIdx.x >> 5;
#pragma unroll
  for (int i = 0; i < 32; i += 8)
    t[ly + i][lx] = in[(size_t)(r0 + ly + i) * C + c0 + lx];
  __syncthreads();
#pragma unroll
  for (int i = 0; i < 32; i += 8)
    out[(size_t)(c0 + ly + i) * R + r0 + lx] = f2b(t[lx][ly + i]);
}

// bf16 [z][R][C] -> [z][C][R]
__global__ __launch_bounds__(256) void trans_b16(const u16* __restrict__ in,
                                                 u16* __restrict__ out, int R, int C) {
  __shared__ u16 t[32][33];
  const size_t boff = (size_t)blockIdx.z * R * C;
  const int c0 = blockIdx.x * 32, r0 = blockIdx.y * 32;
  const int lx = threadIdx.x & 31, ly = threadIdx.x >> 5;
#pragma unroll
  for (int i = 0; i < 32; i += 8)
    t[ly + i][lx] = in[boff + (size_t)(r0 + ly + i) * C + c0 + lx];
  __syncthreads();
#pragma unroll
  for (int i = 0; i < 32; i += 8)
    out[boff + (size_t)(c0 + ly + i) * R + r0 + lx] = t[lx][ly + i];
}

// ---------------- low-rank gate part 1: tmp[4096,16] = x @ w1 ----------------
__global__ __launch_bounds__(256) void lowrank1(
    const float* __restrict__ x, const float* __restrict__ w1,
    float* __restrict__ tmp)
{
  const int idx = blockIdx.x * 256 + threadIdx.x;
  const int m = idx >> 4, i = idx & 15;
  const float* xr = x + (size_t)m * 1024;
  float acc = 0.f;
#pragma unroll 4
  for (int kk = 0; kk < 1024; kk += 4) {
    const float4 xv = *(const float4*)(xr + kk);
    acc = fmaf(xv.x, w1[(kk + 0) * 16 + i], acc);
    acc = fmaf(xv.y, w1[(kk + 1) * 16 + i], acc);
    acc = fmaf(xv.z, w1[(kk + 2) * 16 + i], acc);
    acc = fmaf(xv.w, w1[(kk + 3) * 16 + i], acc);
  }
  tmp[idx] = acc;
}

// -------- gate cumsum: Bcum[bh][t][i] (fp32 log-decay prefix), Dc = e^B_end --
// grid (4, 32): x = h (n-quad), y = b*16+c. 256 threads over i.
__global__ __launch_bounds__(256) void gate_cum(
    const float* __restrict__ tmp, const float* __restrict__ w2,
    const float* __restrict__ bias, float* __restrict__ Bcum,
    float* __restrict__ Dc)
{
  __shared__ float ls_t[2048];   // tmp slice for this (b, c): 128 t x 16
  const int b = blockIdx.y >> 4, c = blockIdx.y & 15;
  const int h = blockIdx.x;
  const int i = threadIdx.x;
  const int n = h * 256 + i;
  const int bh = b * 4 + h;
  const float* tp = tmp + ((size_t)(b * 2048 + c * 128)) * 16;
#pragma unroll
  for (int r = 0; r < 8; ++r) ls_t[r * 256 + threadIdx.x] = tp[r * 256 + threadIdx.x];
  __syncthreads();
  float w2c[16];
#pragma unroll
  for (int r = 0; r < 16; ++r) w2c[r] = w2[r * 1024 + n];
  const float bn = bias[n];
  float* Bp = Bcum + ((size_t)bh * 2048 + c * 128) * 256 + i;
  float B = 0.f;
  for (int t = 0; t < 128; ++t) {
    float gl = bn;
    const float* tr = ls_t + t * 16;
#pragma unroll
    for (int r = 0; r < 16; ++r) gl = fmaf(tr[r], w2c[r], gl);
    const float ls = fminf(gl, 0.f) - log1pf(expf(-fabsf(gl)));
    B += ls * 0.0625f;
    Bp[(size_t)t * 256] = B;
  }
  Dc[(bh * 16 + c) * 256 + i] = expf(B);
}

// ---------------- fused projections: xb[4096,1024] @ [Wq|Wk|Wv|Wg] ----------
// decay fused: qt = q*scale*e^B, kt = k*e^-B. v row-major, gpre plain.
__global__ __launch_bounds__(256) void proj_all(
    const u16* __restrict__ xb, const u16* __restrict__ WT,
    const float* __restrict__ Bcum, u16* __restrict__ qt, u16* __restrict__ kt,
    u16* __restrict__ vr, u16* __restrict__ gpre)
{
  __shared__ __align__(16) u16 As[4096], Bs[4096];
  // bijective XCD-chunked swizzle: 1536 blocks, 192 per XCD, x-major panels
  const int id = blockIdx.x;
  const int wg = (id & 7) * 192 + (id >> 3);
  const int m0 = (wg & 31) * 128, n0 = (wg >> 5) * 128;
  f4v acc[4][4];
  ZERO_ACC(acc)
  gemm_core(xb + (size_t)m0 * 1024, 1024, WT + (size_t)n0 * 1024, 1024, 1024,
            As, Bs, acc);
  EPI_SETUP
#pragma unroll
  for (int mf = 0; mf < 4; ++mf)
#pragma unroll
    for (int nf = 0; nf < 4; ++nf)
#pragma unroll
      for (int r = 0; r < 4; ++r) {
        const int m = m0 + wr * 64 + mf * 16 + ((ln >> 4) << 2) + r;
        const int n = n0 + wc * 64 + nf * 16 + (ln & 15);
        const float val = acc[mf][nf][r];
        const int b = m >> 11, t = m & 2047;
        if (n0 < 1024) {
          const int bh = b * 4 + (n >> 8), i = n & 255;
          const size_t off = ((size_t)bh * 2048 + t) * 256 + i;
          qt[off] = f2b(val * 0.0625f * expf(Bcum[off]));
        } else if (n0 < 2048) {
          const int nn = n - 1024;
          const int bh = b * 4 + (nn >> 8), i = nn & 255;
          const size_t off = ((size_t)bh * 2048 + t) * 256 + i;
          kt[off] = f2b(val * expf(-Bcum[off]));
        } else if (n0 < 4096) {
          const int nn = n - 2048;
          const int bh = b * 4 + (nn >> 9), j = nn & 511;
          vr[((size_t)bh * 2048 + t) * 512 + j] = f2b(val);
        } else {
          gpre[(size_t)m * 2048 + (n - 4096)] = f2b(val);
        }
      }
}

// ---------------- final: out[4096,1024] = ob[4096,2048] @ Wo ----------------
__global__ __launch_bounds__(256) void gemm_out(
    const u16* __restrict__ ob, const u16* __restrict__ WoT,
    float* __restrict__ out)
{
  __shared__ __align__(16) u16 As[4096], Bs[4096];
  const int id = blockIdx.x;                 // 256 blocks, 32 per XCD
  const int wg = (id & 7) * 32 + (id >> 3);
  const int n0 = (wg >> 5) * 128, m0 = (wg & 31) * 128;
  f4v acc[4][4];
  ZERO_ACC(acc)
  gemm_core(ob + (size_t)m0 * 2048, 2048, WoT + (size_t)n0 * 2048, 2048, 2048,
            As, Bs, acc);
  EPI_SETUP
#pragma unroll
  for (int mf = 0; mf < 4; ++mf)
#pragma unroll
    for (int nf = 0; nf < 4; ++nf)
#pragma unroll
      for (int r = 0; r < 4; ++r) {
        const int m = m0 + wr * 64 + mf * 16 + ((ln >> 4) << 2) + r;
        const int n = n0 + wc * 64 + nf * 16 + (ln & 15);
        out[(size_t)m * 1024 + n] = acc[mf][nf][r];
      }
}

// ---------------- UT[bhc][j][i] = sum_s vT[j][s] * ktT[i][s] ----------------
__global__ __launch_bounds__(256) void chunk_state_k(
    const u16* __restrict__ vT, const u16* __restrict__ ktT, u16* __restrict__ UT)
{
  __shared__ __align__(16) u16 As[4096], Bs[4096];
  const int bhc = blockIdx.y, bh = bhc >> 4, c = bhc & 15;
  const int mt = blockIdx.x >> 1, nt = blockIdx.x & 1;
  f4v acc[4][4];
  ZERO_ACC(acc)
  gemm_core(vT + ((size_t)bh * 512 + mt * 128) * 2048 + c * 128, 2048,
            ktT + ((size_t)bh * 256 + nt * 128) * 2048 + c * 128, 2048, 128,
            As, Bs, acc);
  EPI_SETUP
  u16* Up = UT + (size_t)bhc * 131072;
#pragma unroll
  for (int mf = 0; mf < 4; ++mf)
#pragma unroll
    for (int nf = 0; nf < 4; ++nf)
#pragma unroll
      for (int r = 0; r < 4; ++r) {
        const int ml = mt * 128 + wr * 64 + mf * 16 + ((ln >> 4) << 2) + r;
        const int nl = nt * 128 + wc * 64 + nf * 16 + (ln & 15);
        Up[(size_t)ml * 256 + nl] = f2b(acc[mf][nf][r]);
      }
}

// ------ serial inter-chunk scan, in place on UT (bf16, fp32 accum) ----------
__global__ __launch_bounds__(256) void state_scan(
    u16* __restrict__ UT, const float* __restrict__ Dc)
{
  const size_t idx = (size_t)blockIdx.x * 256 + threadIdx.x;
  const int bh = (int)(idx >> 17);
  const int ji = (int)(idx & 131071);
  const int i = ji & 255;
  u16* Up = UT + (size_t)bh * 16 * 131072 + ji;
  const float* Dp = Dc + bh * 16 * 256 + i;
  float S = 0.f;
  for (int c = 0; c < 16; ++c) {
    const float u = b2f(Up[(size_t)c * 131072]);
    Up[(size_t)c * 131072] = f2b(S);
    S = Dp[c * 256] * (S + u);
  }
}

// ---------------- Aw[bhc][t][s] = causal(qt @ kt^T), bf16 -------------------
__global__ __launch_bounds__(256) void qk_causal_k(
    const u16* __restrict__ qt, const u16* __restrict__ kt, u16* __restrict__ Aw)
{
  __shared__ __align__(16) u16 As[4096], Bs[4096];
  const int bhc = blockIdx.x, bh = bhc >> 4, c = bhc & 15;
  f4v acc[4][4];
  ZERO_ACC(acc)
  const size_t base = ((size_t)bh * 2048 + c * 128) * 256;
  gemm_core(qt + base, 256, kt + base, 256, 256, As, Bs, acc);
  EPI_SETUP
  u16* Ap = Aw + (size_t)bhc * 16384;
#pragma unroll
  for (int mf = 0; mf < 4; ++mf)
#pragma unroll
    for (int nf = 0; nf < 4; ++nf)
#pragma unroll
      for (int r = 0; r < 4; ++r) {
        const int t = wr * 64 + mf * 16 + ((ln >> 4) << 2) + r;
        const int s = wc * 64 + nf * 16 + (ln & 15);
        Ap[t * 128 + s] = (s <= t) ? f2b(acc[mf][nf][r]) : (u16)0;
      }
}

// -------- ob = Aw @ V + qt @ S  (per bhc, 128-col tile of HV) ---------------
__global__ __launch_bounds__(256) void intra_k(
    const u16* __restrict__ Aw, const u16* __restrict__ qt,
    const u16* __restrict__ vT, const u16* __restrict__ UT, u16* __restrict__ ob)
{
  __shared__ __align__(16) u16 As[4096], Bs[4096];
  const int jt = blockIdx.x;
  const int bhc = blockIdx.y, bh = bhc >> 4, c = bhc & 15;
  f4v acc[4][4];
  ZERO_ACC(acc)
  gemm_core(Aw + (size_t)bhc * 16384, 128,
            vT + ((size_t)bh * 512 + jt * 128) * 2048 + c * 128, 2048, 128,
            As, Bs, acc);
  gemm_core(qt + ((size_t)bh * 2048 + c * 128) * 256, 256,
            UT + (size_t)bhc * 131072 + (size_t)jt * 128 * 256, 256, 256,
            As, Bs, acc);
  EPI_SETUP
  const int b = bh >> 2, h = bh & 3;
#pragma unroll
  for (int mf = 0; mf < 4; ++mf)
#pragma unroll
    for (int nf = 0; nf < 4; ++nf)
#pragma unroll
      for (int r = 0; r < 4; ++r) {
        const int t = c * 128 + wr * 64 + mf * 16 + ((ln >> 4) << 2) + r;
        const int j = jt * 128 + wc * 64 + nf * 16 + (ln & 15);
        ob[((size_t)(b * 2048 + t)) * 2048 + h * 512 + j] = f2b(acc[mf][nf][r]);
      }
}

// ---------------- group RMSNorm (512) + SiLU gate, in place on ob -----------
__global__ __launch_bounds__(256) void rms_silu(
    u16* __restrict__ o, const u16* __restrict__ gpre, const float* __restrict__ w)
{
  const int grp = blockIdx.x * 4 + (threadIdx.x >> 6);
  const int lane = threadIdx.x & 63;
  const size_t base = (size_t)(grp >> 2) * 2048 + (grp & 3) * 512;
  float xv[8];
  float ss = 0.f;
#pragma unroll
  for (int i = 0; i < 8; ++i) {
    xv[i] = b2f(o[base + i * 64 + lane]);
    ss = fmaf(xv[i], xv[i], ss);
  }
#pragma unroll
  for (int off = 1; off < 64; off <<= 1) ss += __shfl_xor(ss, off, 64);
  const float r = rsqrtf(ss * (1.f / 512.f) + 1e-5f);
#pragma unroll
  for (int i = 0; i < 8; ++i) {
    const int cidx = i * 64 + lane;
    const float gp = b2f(gpre[base + cidx]);
    const float sig = 1.f / (1.f + expf(-gp));
    o[base + cidx] = f2b(xv[i] * r * w[cidx] * gp * sig);
  }
}

extern "C" void kernel_launch(void* const* d_in, const int* in_sizes, int n_in,
                              void* d_out, int out_size, void* d_ws, size_t ws_size,
                              hipStream_t stream) {
  const float* x    = (const float*)d_in[0];
  const float* Wq   = (const float*)d_in[1];
  const float* Wk   = (const float*)d_in[2];
  const float* Wv   = (const float*)d_in[3];
  const float* Wg   = (const float*)d_in[4];
  const float* w1   = (const float*)d_in[5];
  const float* w2   = (const float*)d_in[6];
  const float* gb   = (const float*)d_in[7];
  const float* Wo   = (const float*)d_in[8];
  const float* rmsw = (const float*)d_in[9];
  float* out = (float*)d_out;

  char* W = (char*)d_ws;
  u16*   xb   = (u16*)W;   W += (size_t)8  << 20;   // [4096][1024]
  u16*   WTa  = (u16*)W;   W += (size_t)12 << 20;   // [6144][1024]
  u16*   WoT  = (u16*)W;   W += (size_t)4  << 20;   // [1024][2048]
  u16*   qt   = (u16*)W;   W += (size_t)8  << 20;   // [8][2048][256]
  u16*   kt   = (u16*)W;   W += (size_t)8  << 20;
  u16*   vr   = (u16*)W;   W += (size_t)16 << 20;   // [8][2048][512]
  u16*   vT   = (u16*)W;   W += (size_t)16 << 20;   // [8][512][2048]
  u16*   ktT  = (u16*)W;   W += (size_t)8  << 20;   // [8][256][2048]
  u16*   gpre = (u16*)W;   W += (size_t)16 << 20;   // [4096][2048]
  float* tmp  = (float*)W; W += (size_t)256 << 10;  // [4096][16]
  float* Dc   = (float*)W; W += (size_t)128 << 10;  // [8][16][256]
  float* Bcum = (float*)W; W += (size_t)16 << 20;   // [8][2048][256] fp32
  u16*   UT   = (u16*)W;   W += (size_t)32 << 20;   // [128][512][256]
  u16*   Aw   = (u16*)W;   W += (size_t)4  << 20;   // [128][128][128]
  u16*   ob   = (u16*)W;   W += (size_t)16 << 20;   // [4096][2048]

  // gate pipeline first (Bcum needed by proj_all)
  hipLaunchKernelGGL(lowrank1, dim3(256), dim3(256), 0, stream, x, w1, tmp);
  hipLaunchKernelGGL(gate_cum, dim3(4, 32), dim3(256), 0, stream,
                     tmp, w2, gb, Bcum, Dc);

  // bf16 conversions / weight transposes
  hipLaunchKernelGGL(cast_b, dim3(4096), dim3(256), 0, stream, x, xb);
  hipLaunchKernelGGL(wtrans, dim3(32, 32), dim3(256), 0, stream, Wq, WTa, 1024, 1024);
  hipLaunchKernelGGL(wtrans, dim3(32, 32), dim3(256), 0, stream, Wk, WTa + 1048576, 1024, 1024);
  hipLaunchKernelGGL(wtrans, dim3(64, 32), dim3(256), 0, stream, Wv, WTa + 2097152, 1024, 2048);
  hipLaunchKernelGGL(wtrans, dim3(64, 32), dim3(256), 0, stream, Wg, WTa + 4194304, 1024, 2048);
  hipLaunchKernelGGL(wtrans, dim3(32, 64), dim3(256), 0, stream, Wo, WoT, 2048, 1024);

  // fused q/k/v/g projections with decay applied in epilogue
  hipLaunchKernelGGL(proj_all, dim3(1536), dim3(256), 0, stream,
                     xb, WTa, Bcum, qt, kt, vr, gpre);

  // layout transposes for the scan GEMMs
  hipLaunchKernelGGL(trans_b16, dim3(8, 64, 8), dim3(256), 0, stream,
                     kt, ktT, 2048, 256);
  hipLaunchKernelGGL(trans_b16, dim3(16, 64, 8), dim3(256), 0, stream,
                     vr, vT, 2048, 512);

  // chunked scan
  hipLaunchKernelGGL(chunk_state_k, dim3(8, 128), dim3(256), 0, stream, vT, ktT, UT);
  hipLaunchKernelGGL(state_scan, dim3(4096), dim3(256), 0, stream, UT, Dc);
  hipLaunchKernelGGL(qk_causal_k, dim3(128), dim3(256), 0, stream, qt, kt, Aw);
  hipLaunchKernelGGL(intra_k, dim3(4, 128), dim3(256), 0, stream, Aw, qt, vT, UT, ob);

  // group RMSNorm + SiLU gate (in place), then output projection
  hipLaunchKernelGGL(rms_silu, dim3(4096), dim3(256), 0, stream, ob, gpre, rmsw);
  hipLaunchKernelGGL(gemm_out, dim3(256), dim3(256), 0, stream, ob, WoT, out);
}

// Round 5
// 321.932 us; speedup vs baseline: 8.7306x; 1.0442x over previous
//
#include <hip/hip_runtime.h>
#include <cstdint>
#include <cstddef>

// GLA forward, bf16 MFMA pipeline, 2-phase double-buffered LDS core.
// B=2, T=2048, D=1024, H=4, HK=256, HV=512, DK=1024, DV=2048, LR=16, CHUNK=128

typedef unsigned short u16;
typedef __attribute__((ext_vector_type(8))) short s8v;   // 8 x bf16 (4 VGPR)
typedef __attribute__((ext_vector_type(4))) float f4v;   // MFMA accumulator

__device__ __forceinline__ u16 f2b(float f) {
  unsigned u = __builtin_bit_cast(unsigned, f);
  unsigned r = u + 0x7FFFu + ((u >> 16) & 1u);   // RNE
  return (u16)(r >> 16);
}
__device__ __forceinline__ float b2f(u16 h) {
  unsigned u = ((unsigned)h) << 16;
  return __builtin_bit_cast(float, u);
}

// async global->LDS, 16B per lane; LDS dest is wave-uniform base + lane*16
__device__ __forceinline__ void cp16(const void* g, void* l) {
  __builtin_amdgcn_global_load_lds(
      (const __attribute__((address_space(1))) unsigned int*)g,
      (__attribute__((address_space(3))) unsigned int*)l, 16, 0, 0);
}

// ---- shared MFMA core: C[128x128] += A[128xK] * BT[128xK]^T, bf16, BK=32 ----
// 2-phase double-buffered: stage tile k+1 while computing tile k.
__device__ __forceinline__ void stage_tile(const u16* g, int ld, u16* lds,
                                           int wv, int ln) {
#pragma unroll
  for (int i = 0; i < 2; ++i) {
    const int c = wv * 2 + i;                       // 1KB chunk id 0..7
    const u16* src = g + (size_t)(c * 16 + (ln >> 2)) * ld + (ln & 3) * 8;
    cp16(src, lds + c * 512);
  }
}

__device__ __forceinline__ void gemm_core(
    const u16* __restrict__ A, int lda, const u16* __restrict__ BT, int ldb,
    int K, u16* As, u16* Bs, f4v acc[4][4])
{
  const int tid = threadIdx.x;
  const int ln = tid & 63, wv = tid >> 6;
  const int wr = wv >> 1, wc = wv & 1;
  const int arow = wr * 64 + (ln & 15);
  const int brow = wc * 64 + (ln & 15);
  const int kq = (ln >> 4) * 8;
  // prologue: stage tile 0 into buffer 0
  stage_tile(A, lda, As, wv, ln);
  stage_tile(BT, ldb, Bs, wv, ln);
  __syncthreads();
  int cur = 0;
  for (int k0 = 0; k0 < K; k0 += 32) {
    const int nxt = cur ^ 1;
    if (k0 + 32 < K) {                       // issue next-tile loads early
      stage_tile(A + k0 + 32, lda, As + nxt * 4096, wv, ln);
      stage_tile(BT + k0 + 32, ldb, Bs + nxt * 4096, wv, ln);
    }
    const u16* Ab = As + cur * 4096;
    const u16* Bb = Bs + cur * 4096;
    s8v af[4], bf[4];
#pragma unroll
    for (int f = 0; f < 4; ++f)
      af[f] = *(const s8v*)(Ab + (arow + f * 16) * 32 + kq);
#pragma unroll
    for (int f = 0; f < 4; ++f)
      bf[f] = *(const s8v*)(Bb + (brow + f * 16) * 32 + kq);
#pragma unroll
    for (int mf = 0; mf < 4; ++mf)
#pragma unroll
      for (int nf = 0; nf < 4; ++nf)
        acc[mf][nf] = __builtin_amdgcn_mfma_f32_16x16x32_bf16(
            af[mf], bf[nf], acc[mf][nf], 0, 0, 0);
    __syncthreads();   // drains vmcnt(0): next buffer staged, reads of cur done
    cur = nxt;
  }
}

#define EPI_SETUP                                            \
  const int tid = threadIdx.x;                               \
  const int ln = tid & 63, wv = tid >> 6;                    \
  const int wr = wv >> 1, wc = wv & 1;

#define ZERO_ACC(acc)                                        \
  _Pragma("unroll")                                          \
  for (int zi = 0; zi < 4; ++zi)                             \
    _Pragma("unroll")                                        \
    for (int zj = 0; zj < 4; ++zj)                           \
      acc[zi][zj] = (f4v){0.f, 0.f, 0.f, 0.f};

// ---------------- elementwise / transpose helpers ----------------
__global__ __launch_bounds__(256) void cast_b(const float* __restrict__ in,
                                              u16* __restrict__ out) {
  const int i = blockIdx.x * 256 + threadIdx.x;
  const float4 v = ((const float4*)in)[i];
  u16* p = out + i * 4;
  p[0] = f2b(v.x); p[1] = f2b(v.y); p[2] = f2b(v.z); p[3] = f2b(v.w);
}

// W [R][C] f32 -> WT [C][R] bf16
__global__ __launch_bounds__(256) void wtrans(const float* __restrict__ in,
                                              u16* __restrict__ out, int R, int C) {
  __shared__ float t[32][33];
  const int c0 = blockIdx.x * 32, r0 = blockIdx.y * 32;
  const int lx = threadIdx.x & 31, ly = threadIdx.x >> 5;
#pragma unroll
  for (int i = 0; i < 32; i += 8)
    t[ly + i][lx] = in[(size_t)(r0 + ly + i) * C + c0 + lx];
  __syncthreads();
#pragma unroll
  for (int i = 0; i < 32; i += 8)
    out[(size_t)(c0 + ly + i) * R + r0 + lx] = f2b(t[lx][ly + i]);
}

// bf16 [z][R][C] -> [z][C][R]
__global__ __launch_bounds__(256) void trans_b16(const u16* __restrict__ in,
                                                 u16* __restrict__ out, int R, int C) {
  __shared__ u16 t[32][33];
  const size_t boff = (size_t)blockIdx.z * R * C;
  const int c0 = blockIdx.x * 32, r0 = blockIdx.y * 32;
  const int lx = threadIdx.x & 31, ly = threadIdx.x >> 5;
#pragma unroll
  for (int i = 0; i < 32; i += 8)
    t[ly + i][lx] = in[boff + (size_t)(r0 + ly + i) * C + c0 + lx];
  __syncthreads();
#pragma unroll
  for (int i = 0; i < 32; i += 8)
    out[boff + (size_t)(c0 + ly + i) * R + r0 + lx] = t[lx][ly + i];
}

// ---------------- low-rank gate part 1: tmp[4096,16] = x @ w1 ----------------
__global__ __launch_bounds__(256) void lowrank1(
    const float* __restrict__ x, const float* __restrict__ w1,
    float* __restrict__ tmp)
{
  const int idx = blockIdx.x * 256 + threadIdx.x;
  const int m = idx >> 4, i = idx & 15;
  const float* xr = x + (size_t)m * 1024;
  float acc = 0.f;
#pragma unroll 4
  for (int kk = 0; kk < 1024; kk += 4) {
    const float4 xv = *(const float4*)(xr + kk);
    acc = fmaf(xv.x, w1[(kk + 0) * 16 + i], acc);
    acc = fmaf(xv.y, w1[(kk + 1) * 16 + i], acc);
    acc = fmaf(xv.z, w1[(kk + 2) * 16 + i], acc);
    acc = fmaf(xv.w, w1[(kk + 3) * 16 + i], acc);
  }
  tmp[idx] = acc;
}

// -------- gate cumsum -> bf16 decay factors dq = e^B, dk = e^-B; Dc = e^B_end
// grid (4, 32): x = h, y = b*16+c. 256 threads over i.
__global__ __launch_bounds__(256) void gate_cum(
    const float* __restrict__ tmp, const float* __restrict__ w2,
    const float* __restrict__ bias, u16* __restrict__ dq, u16* __restrict__ dk,
    float* __restrict__ Dc)
{
  __shared__ float ls_t[2048];   // tmp slice for this (b, c): 128 t x 16
  const int b = blockIdx.y >> 4, c = blockIdx.y & 15;
  const int h = blockIdx.x;
  const int i = threadIdx.x;
  const int n = h * 256 + i;
  const int bh = b * 4 + h;
  const float* tp = tmp + ((size_t)(b * 2048 + c * 128)) * 16;
#pragma unroll
  for (int r = 0; r < 8; ++r) ls_t[r * 256 + threadIdx.x] = tp[r * 256 + threadIdx.x];
  __syncthreads();
  float w2c[16];
#pragma unroll
  for (int r = 0; r < 16; ++r) w2c[r] = w2[r * 1024 + n];
  const float bn = bias[n];
  const size_t base = ((size_t)bh * 2048 + c * 128) * 256 + i;
  float B = 0.f;
  for (int t = 0; t < 128; ++t) {
    float gl = bn;
    const float* tr = ls_t + t * 16;
#pragma unroll
    for (int r = 0; r < 16; ++r) gl = fmaf(tr[r], w2c[r], gl);
    const float ls = fminf(gl, 0.f) - log1pf(expf(-fabsf(gl)));
    B += ls * 0.0625f;
    const float eB = expf(B);
    dq[base + (size_t)t * 256] = f2b(eB);
    dk[base + (size_t)t * 256] = f2b(1.f / eB);
  }
  Dc[(bh * 16 + c) * 256 + i] = expf(B);
}

// ---------------- fused projections: xb[4096,1024] @ [Wq|Wk|Wv|Wg] ----------
// decay fused via precomputed bf16 factors. v row-major, gpre plain.
__global__ __launch_bounds__(256) void proj_all(
    const u16* __restrict__ xb, const u16* __restrict__ WT,
    const u16* __restrict__ dq, const u16* __restrict__ dk,
    u16* __restrict__ qt, u16* __restrict__ kt,
    u16* __restrict__ vr, u16* __restrict__ gpre)
{
  __shared__ __align__(16) u16 As[8192], Bs[8192];
  // bijective XCD-chunked swizzle: 1536 blocks, 192 per XCD
  const int id = blockIdx.x;
  const int wg = (id & 7) * 192 + (id >> 3);
  const int m0 = (wg & 31) * 128, n0 = (wg >> 5) * 128;
  f4v acc[4][4];
  ZERO_ACC(acc)
  gemm_core(xb + (size_t)m0 * 1024, 1024, WT + (size_t)n0 * 1024, 1024, 1024,
            As, Bs, acc);
  EPI_SETUP
#pragma unroll
  for (int mf = 0; mf < 4; ++mf)
#pragma unroll
    for (int nf = 0; nf < 4; ++nf)
#pragma unroll
      for (int r = 0; r < 4; ++r) {
        const int m = m0 + wr * 64 + mf * 16 + ((ln >> 4) << 2) + r;
        const int n = n0 + wc * 64 + nf * 16 + (ln & 15);
        const float val = acc[mf][nf][r];
        const int b = m >> 11, t = m & 2047;
        if (n0 < 1024) {
          const int bh = b * 4 + (n >> 8), i = n & 255;
          const size_t off = ((size_t)bh * 2048 + t) * 256 + i;
          qt[off] = f2b(val * 0.0625f * b2f(dq[off]));
        } else if (n0 < 2048) {
          const int nn = n - 1024;
          const int bh = b * 4 + (nn >> 8), i = nn & 255;
          const size_t off = ((size_t)bh * 2048 + t) * 256 + i;
          kt[off] = f2b(val * b2f(dk[off]));
        } else if (n0 < 4096) {
          const int nn = n - 2048;
          const int bh = b * 4 + (nn >> 9), j = nn & 511;
          vr[((size_t)bh * 2048 + t) * 512 + j] = f2b(val);
        } else {
          gpre[(size_t)m * 2048 + (n - 4096)] = f2b(val);
        }
      }
}

// ------- merged scan GEMMs: x<8 -> chunk_state tile, x==8 -> qk_causal ------
// UT layout: [bh][j][c][i]  (c-stride 256 elems -> coalesced state_scan)
__global__ __launch_bounds__(256) void scan_gemms(
    const u16* __restrict__ vT, const u16* __restrict__ ktT,
    const u16* __restrict__ qt, const u16* __restrict__ kt,
    u16* __restrict__ UT, u16* __restrict__ Aw)
{
  __shared__ __align__(16) u16 As[8192], Bs[8192];
  const int bhc = blockIdx.y, bh = bhc >> 4, c = bhc & 15;
  f4v acc[4][4];
  ZERO_ACC(acc)
  if (blockIdx.x < 8) {
    const int mt = blockIdx.x >> 1, nt = blockIdx.x & 1;
    gemm_core(vT + ((size_t)bh * 512 + mt * 128) * 2048 + c * 128, 2048,
              ktT + ((size_t)bh * 256 + nt * 128) * 2048 + c * 128, 2048, 128,
              As, Bs, acc);
    EPI_SETUP
#pragma unroll
    for (int mf = 0; mf < 4; ++mf)
#pragma unroll
      for (int nf = 0; nf < 4; ++nf)
#pragma unroll
        for (int r = 0; r < 4; ++r) {
          const int j = mt * 128 + wr * 64 + mf * 16 + ((ln >> 4) << 2) + r;
          const int i = nt * 128 + wc * 64 + nf * 16 + (ln & 15);
          UT[(((size_t)(bh * 512 + j)) * 16 + c) * 256 + i] = f2b(acc[mf][nf][r]);
        }
  } else {
    const size_t base = ((size_t)bh * 2048 + c * 128) * 256;
    gemm_core(qt + base, 256, kt + base, 256, 256, As, Bs, acc);
    EPI_SETUP
    u16* Ap = Aw + (size_t)bhc * 16384;
#pragma unroll
    for (int mf = 0; mf < 4; ++mf)
#pragma unroll
      for (int nf = 0; nf < 4; ++nf)
#pragma unroll
        for (int r = 0; r < 4; ++r) {
          const int t = wr * 64 + mf * 16 + ((ln >> 4) << 2) + r;
          const int s = wc * 64 + nf * 16 + (ln & 15);
          Ap[t * 128 + s] = (s <= t) ? f2b(acc[mf][nf][r]) : (u16)0;
        }
  }
}

// ------ serial inter-chunk scan, in place on UT (bf16, fp32 accum) ----------
// UT[bh][j][c][i]: 256 threads walk c together -> 512B coalesced per step.
__global__ __launch_bounds__(256) void state_scan(
    u16* __restrict__ UT, const float* __restrict__ Dc)
{
  const int blk = blockIdx.x;               // 4096 = bh*512 + j
  const int bh = blk >> 9, j = blk & 511;
  const int i = threadIdx.x;
  u16* Up = UT + ((size_t)(bh * 512 + j)) * 16 * 256 + i;
  const float* Dp = Dc + bh * 16 * 256 + i;
  float S = 0.f;
  for (int c = 0; c < 16; ++c) {
    const float u = b2f(Up[c * 256]);
    Up[c * 256] = f2b(S);
    S = Dp[c * 256] * (S + u);
  }
}

// -------- ob = Aw @ V + qt @ S  (per bhc, 128-col tile of HV) ---------------
__global__ __launch_bounds__(256) void intra_k(
    const u16* __restrict__ Aw, const u16* __restrict__ qt,
    const u16* __restrict__ vT, const u16* __restrict__ UT, u16* __restrict__ ob)
{
  __shared__ __align__(16) u16 As[8192], Bs[8192];
  const int jt = blockIdx.x;
  const int bhc = blockIdx.y, bh = bhc >> 4, c = bhc & 15;
  f4v acc[4][4];
  ZERO_ACC(acc)
  gemm_core(Aw + (size_t)bhc * 16384, 128,
            vT + ((size_t)bh * 512 + jt * 128) * 2048 + c * 128, 2048, 128,
            As, Bs, acc);
  gemm_core(qt + ((size_t)bh * 2048 + c * 128) * 256, 256,
            UT + ((size_t)(bh * 512 + jt * 128)) * 4096 + (size_t)c * 256, 4096, 256,
            As, Bs, acc);
  EPI_SETUP
  const int b = bh >> 2, h = bh & 3;
#pragma unroll
  for (int mf = 0; mf < 4; ++mf)
#pragma unroll
    for (int nf = 0; nf < 4; ++nf)
#pragma unroll
      for (int r = 0; r < 4; ++r) {
        const int t = c * 128 + wr * 64 + mf * 16 + ((ln >> 4) << 2) + r;
        const int j = jt * 128 + wc * 64 + nf * 16 + (ln & 15);
        ob[((size_t)(b * 2048 + t)) * 2048 + h * 512 + j] = f2b(acc[mf][nf][r]);
      }
}

// ---------------- group RMSNorm (512) + SiLU gate, in place on ob -----------
__global__ __launch_bounds__(256) void rms_silu(
    u16* __restrict__ o, const u16* __restrict__ gpre, const float* __restrict__ w)
{
  const int grp = blockIdx.x * 4 + (threadIdx.x >> 6);
  const int lane = threadIdx.x & 63;
  const size_t base = (size_t)(grp >> 2) * 2048 + (grp & 3) * 512;
  float xv[8];
  float ss = 0.f;
#pragma unroll
  for (int i = 0; i < 8; ++i) {
    xv[i] = b2f(o[base + i * 64 + lane]);
    ss = fmaf(xv[i], xv[i], ss);
  }
#pragma unroll
  for (int off = 1; off < 64; off <<= 1) ss += __shfl_xor(ss, off, 64);
  const float r = rsqrtf(ss * (1.f / 512.f) + 1e-5f);
#pragma unroll
  for (int i = 0; i < 8; ++i) {
    const int cidx = i * 64 + lane;
    const float gp = b2f(gpre[base + cidx]);
    const float sig = 1.f / (1.f + expf(-gp));
    o[base + cidx] = f2b(xv[i] * r * w[cidx] * gp * sig);
  }
}

// ---------------- final: out = ob @ Wo, split-K=2 into pout -----------------
__global__ __launch_bounds__(256) void gemm_out(
    const u16* __restrict__ ob, const u16* __restrict__ WoT,
    float* __restrict__ pout)
{
  __shared__ __align__(16) u16 As[8192], Bs[8192];
  const int id = blockIdx.x;                 // 512 blocks, 64 per XCD
  const int wg = (id & 7) * 64 + (id >> 3);
  const int ks = wg >> 8;                    // K-half
  const int tt = wg & 255;
  const int m0 = (tt & 31) * 128, n0 = (tt >> 5) * 128;
  f4v acc[4][4];
  ZERO_ACC(acc)
  gemm_core(ob + (size_t)m0 * 2048 + ks * 1024, 2048,
            WoT + (size_t)n0 * 2048 + ks * 1024, 2048, 1024, As, Bs, acc);
  EPI_SETUP
  float* po = pout + (size_t)ks * 4194304;
#pragma unroll
  for (int mf = 0; mf < 4; ++mf)
#pragma unroll
    for (int nf = 0; nf < 4; ++nf)
#pragma unroll
      for (int r = 0; r < 4; ++r) {
        const int m = m0 + wr * 64 + mf * 16 + ((ln >> 4) << 2) + r;
        const int n = n0 + wc * 64 + nf * 16 + (ln & 15);
        po[(size_t)m * 1024 + n] = acc[mf][nf][r];
      }
}

__global__ __launch_bounds__(256) void reduce_out(
    const float* __restrict__ p, float* __restrict__ out)
{
  const int i = blockIdx.x * 256 + threadIdx.x;   // float4 granularity
  const float4 a = ((const float4*)p)[i];
  const float4 b = ((const float4*)(p + 4194304))[i];
  ((float4*)out)[i] = make_float4(a.x + b.x, a.y + b.y, a.z + b.z, a.w + b.w);
}

extern "C" void kernel_launch(void* const* d_in, const int* in_sizes, int n_in,
                              void* d_out, int out_size, void* d_ws, size_t ws_size,
                              hipStream_t stream) {
  const float* x    = (const float*)d_in[0];
  const float* Wq   = (const float*)d_in[1];
  const float* Wk   = (const float*)d_in[2];
  const float* Wv   = (const float*)d_in[3];
  const float* Wg   = (const float*)d_in[4];
  const float* w1   = (const float*)d_in[5];
  const float* w2   = (const float*)d_in[6];
  const float* gb   = (const float*)d_in[7];
  const float* Wo   = (const float*)d_in[8];
  const float* rmsw = (const float*)d_in[9];
  float* out = (float*)d_out;

  char* W = (char*)d_ws;
  u16*   xb   = (u16*)W;   W += (size_t)8  << 20;   // [4096][1024]
  u16*   WTa  = (u16*)W;   W += (size_t)12 << 20;   // [6144][1024]
  u16*   WoT  = (u16*)W;   W += (size_t)4  << 20;   // [1024][2048]
  u16*   qt   = (u16*)W;   W += (size_t)8  << 20;   // [8][2048][256]
  u16*   kt   = (u16*)W;   W += (size_t)8  << 20;
  u16*   vr   = (u16*)W;   W += (size_t)16 << 20;   // [8][2048][512]
  u16*   vT   = (u16*)W;   W += (size_t)16 << 20;   // [8][512][2048]
  u16*   ktT  = (u16*)W;   W += (size_t)8  << 20;   // [8][256][2048]
  u16*   gpre = (u16*)W;   W += (size_t)16 << 20;   // [4096][2048]
  float* tmp  = (float*)W; W += (size_t)256 << 10;  // [4096][16]
  float* Dc   = (float*)W; W += (size_t)128 << 10;  // [8][16][256]
  u16*   dq   = (u16*)W;   W += (size_t)8  << 20;   // [8][2048][256] bf16 e^B
  u16*   dk   = (u16*)W;   W += (size_t)8  << 20;   // e^-B
  u16*   UT   = (u16*)W;   W += (size_t)32 << 20;   // [8][512][16][256]
  u16*   Aw   = (u16*)W;   W += (size_t)4  << 20;   // [128][128][128]
  u16*   ob   = (u16*)W;   W += (size_t)16 << 20;   // [4096][2048]
  float* pout = (float*)W; W += (size_t)32 << 20;   // [2][4096][1024]

  // gate pipeline first (dq/dk needed by proj_all)
  hipLaunchKernelGGL(lowrank1, dim3(256), dim3(256), 0, stream, x, w1, tmp);
  hipLaunchKernelGGL(gate_cum, dim3(4, 32), dim3(256), 0, stream,
                     tmp, w2, gb, dq, dk, Dc);

  // bf16 conversions / weight transposes
  hipLaunchKernelGGL(cast_b, dim3(4096), dim3(256), 0, stream, x, xb);
  hipLaunchKernelGGL(wtrans, dim3(32, 32), dim3(256), 0, stream, Wq, WTa, 1024, 1024);
  hipLaunchKernelGGL(wtrans, dim3(32, 32), dim3(256), 0, stream, Wk, WTa + 1048576, 1024, 1024);
  hipLaunchKernelGGL(wtrans, dim3(64, 32), dim3(256), 0, stream, Wv, WTa + 2097152, 1024, 2048);
  hipLaunchKernelGGL(wtrans, dim3(64, 32), dim3(256), 0, stream, Wg, WTa + 4194304, 1024, 2048);
  hipLaunchKernelGGL(wtrans, dim3(32, 64), dim3(256), 0, stream, Wo, WoT, 2048, 1024);

  // fused q/k/v/g projections with decay applied in epilogue
  hipLaunchKernelGGL(proj_all, dim3(1536), dim3(256), 0, stream,
                     xb, WTa, dq, dk, qt, kt, vr, gpre);

  // layout transposes for the scan GEMMs
  hipLaunchKernelGGL(trans_b16, dim3(8, 64, 8), dim3(256), 0, stream,
                     kt, ktT, 2048, 256);
  hipLaunchKernelGGL(trans_b16, dim3(16, 64, 8), dim3(256), 0, stream,
                     vr, vT, 2048, 512);

  // chunked scan: (chunk_state || qk_causal) -> state_scan -> intra
  hipLaunchKernelGGL(scan_gemms, dim3(9, 128), dim3(256), 0, stream,
                     vT, ktT, qt, kt, UT, Aw);
  hipLaunchKernelGGL(state_scan, dim3(4096), dim3(256), 0, stream, UT, Dc);
  hipLaunchKernelGGL(intra_k, dim3(4, 128), dim3(256), 0, stream, Aw, qt, vT, UT, ob);

  // group RMSNorm + SiLU gate (in place), then output projection (split-K)
  hipLaunchKernelGGL(rms_silu, dim3(4096), dim3(256), 0, stream, ob, gpre, rmsw);
  hipLaunchKernelGGL(gemm_out, dim3(512), dim3(256), 0, stream, ob, WoT, pout);
  hipLaunchKernelGGL(reduce_out, dim3(4096), dim3(256), 0, stream, pout, out);
}

// Round 6
// 317.566 us; speedup vs baseline: 8.8506x; 1.0137x over previous
//
#include <hip/hip_runtime.h>
#include <cstdint>
#include <cstddef>

// GLA forward, bf16 MFMA pipeline, 3-deep counted-vmcnt LDS pipeline (T4).
// B=2, T=2048, D=1024, H=4, HK=256, HV=512, DK=1024, DV=2048, LR=16, CHUNK=128

typedef unsigned short u16;
typedef __attribute__((ext_vector_type(8))) short s8v;   // 8 x bf16 (4 VGPR)
typedef __attribute__((ext_vector_type(4))) float f4v;   // MFMA accumulator

__device__ __forceinline__ u16 f2b(float f) {
  unsigned u = __builtin_bit_cast(unsigned, f);
  unsigned r = u + 0x7FFFu + ((u >> 16) & 1u);   // RNE
  return (u16)(r >> 16);
}
__device__ __forceinline__ float b2f(u16 h) {
  unsigned u = ((unsigned)h) << 16;
  return __builtin_bit_cast(float, u);
}

// async global->LDS, 16B per lane; LDS dest is wave-uniform base + lane*16
__device__ __forceinline__ void cp16(const void* g, void* l) {
  __builtin_amdgcn_global_load_lds(
      (const __attribute__((address_space(1))) unsigned int*)g,
      (__attribute__((address_space(3))) unsigned int*)l, 16, 0, 0);
}

// ---- shared MFMA core: C[128x128] += A[128xK] * BT[128xK]^T, bf16, BK=32 ----
// Triple-buffered, counted vmcnt: tile t confirmed by vmcnt while t+1,t+2
// stay in flight. stage = 4 gload_lds per wave (2 A-chunks + 2 B-chunks).
__device__ __forceinline__ void stage_tile(const u16* g, int ld, u16* lds,
                                           int wv, int ln) {
#pragma unroll
  for (int i = 0; i < 2; ++i) {
    const int c = wv * 2 + i;                       // 1KB chunk id 0..7
    const u16* src = g + (size_t)(c * 16 + (ln >> 2)) * ld + (ln & 3) * 8;
    cp16(src, lds + c * 512);
  }
}

__device__ __forceinline__ void gemm_core(
    const u16* __restrict__ A, int lda, const u16* __restrict__ BT, int ldb,
    int K, u16* As, u16* Bs, f4v acc[4][4])
{
  const int tid = threadIdx.x;
  const int ln = tid & 63, wv = tid >> 6;
  const int arow = (wv >> 1) * 64 + (ln & 15);
  const int brow = (wv & 1) * 64 + (ln & 15);
  const int kq = (ln >> 4) * 8;
  const int nt = K >> 5;                     // #K-tiles, always >= 4 here
  // prologue: fill all 3 slots (12 loads per wave in flight)
  stage_tile(A, lda, As, wv, ln);
  stage_tile(BT, ldb, Bs, wv, ln);
  stage_tile(A + 32, lda, As + 4096, wv, ln);
  stage_tile(BT + 32, ldb, Bs + 4096, wv, ln);
  stage_tile(A + 64, lda, As + 8192, wv, ln);
  stage_tile(BT + 64, ldb, Bs + 8192, wv, ln);
  int slot = 0;
  for (int t = 0; t < nt; ++t) {
    const int rem = nt - 1 - t;
    // confirm tile t landed; keep newer tiles' loads in flight (T4)
    if (rem >= 2)      asm volatile("s_waitcnt vmcnt(8)" ::: "memory");
    else if (rem == 1) asm volatile("s_waitcnt vmcnt(4)" ::: "memory");
    else               asm volatile("s_waitcnt vmcnt(0)" ::: "memory");
    __builtin_amdgcn_s_barrier();            // all waves: slot data ready
    __builtin_amdgcn_sched_barrier(0);
    const u16* Ab = As + slot * 4096;
    const u16* Bb = Bs + slot * 4096;
    s8v af[4], bf[4];
#pragma unroll
    for (int f = 0; f < 4; ++f)
      af[f] = *(const s8v*)(Ab + (arow + f * 16) * 32 + kq);
#pragma unroll
    for (int f = 0; f < 4; ++f)
      bf[f] = *(const s8v*)(Bb + (brow + f * 16) * 32 + kq);
#pragma unroll
    for (int mf = 0; mf < 4; ++mf)
#pragma unroll
      for (int nf = 0; nf < 4; ++nf)
        acc[mf][nf] = __builtin_amdgcn_mfma_f32_16x16x32_bf16(
            af[mf], bf[nf], acc[mf][nf], 0, 0, 0);
    __builtin_amdgcn_sched_barrier(0);
    __builtin_amdgcn_s_barrier();            // all waves done reading slot
    if (t + 3 < nt) {                        // refill freed slot
      stage_tile(A + (t + 3) * 32, lda, As + slot * 4096, wv, ln);
      stage_tile(BT + (t + 3) * 32, ldb, Bs + slot * 4096, wv, ln);
    }
    slot = (slot == 2) ? 0 : slot + 1;
  }
}

#define EPI_SETUP                                            \
  const int tid = threadIdx.x;                               \
  const int ln = tid & 63, wv = tid >> 6;                    \
  const int wr = wv >> 1, wc = wv & 1;

#define ZERO_ACC(acc)                                        \
  _Pragma("unroll")                                          \
  for (int zi = 0; zi < 4; ++zi)                             \
    _Pragma("unroll")                                        \
    for (int zj = 0; zj < 4; ++zj)                           \
      acc[zi][zj] = (f4v){0.f, 0.f, 0.f, 0.f};

// ---------------- elementwise / transpose helpers ----------------
__global__ __launch_bounds__(256) void cast_b(const float* __restrict__ in,
                                              u16* __restrict__ out) {
  const int i = blockIdx.x * 256 + threadIdx.x;
  const float4 v = ((const float4*)in)[i];
  u16* p = out + i * 4;
  p[0] = f2b(v.x); p[1] = f2b(v.y); p[2] = f2b(v.z); p[3] = f2b(v.w);
}

// W [R][C] f32 -> WT [C][R] bf16
__global__ __launch_bounds__(256) void wtrans(const float* __restrict__ in,
                                              u16* __restrict__ out, int R, int C) {
  __shared__ float t[32][33];
  const int c0 = blockIdx.x * 32, r0 = blockIdx.y * 32;
  const int lx = threadIdx.x & 31, ly = threadIdx.x >> 5;
#pragma unroll
  for (int i = 0; i < 32; i += 8)
    t[ly + i][lx] = in[(size_t)(r0 + ly + i) * C + c0 + lx];
  __syncthreads();
#pragma unroll
  for (int i = 0; i < 32; i += 8)
    out[(size_t)(c0 + ly + i) * R + r0 + lx] = f2b(t[lx][ly + i]);
}

// bf16 [z][R][C] -> [z][C][R]
__global__ __launch_bounds__(256) void trans_b16(const u16* __restrict__ in,
                                                 u16* __restrict__ out, int R, int C) {
  __shared__ u16 t[32][33];
  const size_t boff = (size_t)blockIdx.z * R * C;
  const int c0 = blockIdx.x * 32, r0 = blockIdx.y * 32;
  const int lx = threadIdx.x & 31, ly = threadIdx.x >> 5;
#pragma unroll
  for (int i = 0; i < 32; i += 8)
    t[ly + i][lx] = in[boff + (size_t)(r0 + ly + i) * C + c0 + lx];
  __syncthreads();
#pragma unroll
  for (int i = 0; i < 32; i += 8)
    out[boff + (size_t)(c0 + ly + i) * R + r0 + lx] = t[lx][ly + i];
}

// ---------------- low-rank gate part 1: tmp[4096,16] = x @ w1 ----------------
__global__ __launch_bounds__(256) void lowrank1(
    const float* __restrict__ x, const float* __restrict__ w1,
    float* __restrict__ tmp)
{
  const int idx = blockIdx.x * 256 + threadIdx.x;
  const int m = idx >> 4, i = idx & 15;
  const float* xr = x + (size_t)m * 1024;
  float acc = 0.f;
#pragma unroll 4
  for (int kk = 0; kk < 1024; kk += 4) {
    const float4 xv = *(const float4*)(xr + kk);
    acc = fmaf(xv.x, w1[(kk + 0) * 16 + i], acc);
    acc = fmaf(xv.y, w1[(kk + 1) * 16 + i], acc);
    acc = fmaf(xv.z, w1[(kk + 2) * 16 + i], acc);
    acc = fmaf(xv.w, w1[(kk + 3) * 16 + i], acc);
  }
  tmp[idx] = acc;
}

// -------- gate cumsum -> bf16 decay factors dq = e^B, dk = e^-B; Dc = e^B_end
__global__ __launch_bounds__(256) void gate_cum(
    const float* __restrict__ tmp, const float* __restrict__ w2,
    const float* __restrict__ bias, u16* __restrict__ dq, u16* __restrict__ dk,
    float* __restrict__ Dc)
{
  __shared__ float ls_t[2048];   // tmp slice for this (b, c): 128 t x 16
  const int b = blockIdx.y >> 4, c = blockIdx.y & 15;
  const int h = blockIdx.x;
  const int i = threadIdx.x;
  const int n = h * 256 + i;
  const int bh = b * 4 + h;
  const float* tp = tmp + ((size_t)(b * 2048 + c * 128)) * 16;
#pragma unroll
  for (int r = 0; r < 8; ++r) ls_t[r * 256 + threadIdx.x] = tp[r * 256 + threadIdx.x];
  __syncthreads();
  float w2c[16];
#pragma unroll
  for (int r = 0; r < 16; ++r) w2c[r] = w2[r * 1024 + n];
  const float bn = bias[n];
  const size_t base = ((size_t)bh * 2048 + c * 128) * 256 + i;
  float B = 0.f;
  for (int t = 0; t < 128; ++t) {
    float gl = bn;
    const float* tr = ls_t + t * 16;
#pragma unroll
    for (int r = 0; r < 16; ++r) gl = fmaf(tr[r], w2c[r], gl);
    const float ls = fminf(gl, 0.f) - log1pf(expf(-fabsf(gl)));
    B += ls * 0.0625f;
    const float eB = expf(B);
    dq[base + (size_t)t * 256] = f2b(eB);
    dk[base + (size_t)t * 256] = f2b(1.f / eB);
  }
  Dc[(bh * 16 + c) * 256 + i] = expf(B);
}

// ---------------- fused projections: xb[4096,1024] @ [Wq|Wk|Wv|Wg] ----------
// decay fused via precomputed bf16 factors. v row-major, gpre plain.
__global__ __launch_bounds__(256) void proj_all(
    const u16* __restrict__ xb, const u16* __restrict__ WT,
    const u16* __restrict__ dq, const u16* __restrict__ dk,
    u16* __restrict__ qt, u16* __restrict__ kt,
    u16* __restrict__ vr, u16* __restrict__ gpre)
{
  __shared__ __align__(16) u16 As[12288], Bs[12288];
  // XCD-chunked swizzle, n-fast within XCD: A-tile stays hot across its 6 uses
  const int id = blockIdx.x;
  const int xcd = id & 7, j = id >> 3;         // j in [0,192)
  const int m0 = (j / 6) * 128;
  const int n0 = (xcd * 6 + (j % 6)) * 128;
  f4v acc[4][4];
  ZERO_ACC(acc)
  gemm_core(xb + (size_t)m0 * 1024, 1024, WT + (size_t)n0 * 1024, 1024, 1024,
            As, Bs, acc);
  EPI_SETUP
#pragma unroll
  for (int mf = 0; mf < 4; ++mf)
#pragma unroll
    for (int nf = 0; nf < 4; ++nf)
#pragma unroll
      for (int r = 0; r < 4; ++r) {
        const int m = m0 + wr * 64 + mf * 16 + ((ln >> 4) << 2) + r;
        const int n = n0 + wc * 64 + nf * 16 + (ln & 15);
        const float val = acc[mf][nf][r];
        const int b = m >> 11, t = m & 2047;
        if (n0 < 1024) {
          const int bh = b * 4 + (n >> 8), i = n & 255;
          const size_t off = ((size_t)bh * 2048 + t) * 256 + i;
          qt[off] = f2b(val * 0.0625f * b2f(dq[off]));
        } else if (n0 < 2048) {
          const int nn = n - 1024;
          const int bh = b * 4 + (nn >> 8), i = nn & 255;
          const size_t off = ((size_t)bh * 2048 + t) * 256 + i;
          kt[off] = f2b(val * b2f(dk[off]));
        } else if (n0 < 4096) {
          const int nn = n - 2048;
          const int bh = b * 4 + (nn >> 9), jj = nn & 511;
          vr[((size_t)bh * 2048 + t) * 512 + jj] = f2b(val);
        } else {
          gpre[(size_t)m * 2048 + (n - 4096)] = f2b(val);
        }
      }
}

// ------- merged scan GEMMs: x<8 -> chunk_state tile, x==8 -> qk_causal ------
// UT layout: [bh][j][c][i]  (c-stride 256 elems -> coalesced state_scan)
__global__ __launch_bounds__(256) void scan_gemms(
    const u16* __restrict__ vT, const u16* __restrict__ ktT,
    const u16* __restrict__ qt, const u16* __restrict__ kt,
    u16* __restrict__ UT, u16* __restrict__ Aw)
{
  __shared__ __align__(16) u16 As[12288], Bs[12288];
  const int bhc = blockIdx.y, bh = bhc >> 4, c = bhc & 15;
  f4v acc[4][4];
  ZERO_ACC(acc)
  if (blockIdx.x < 8) {
    const int mt = blockIdx.x >> 1, nt = blockIdx.x & 1;
    gemm_core(vT + ((size_t)bh * 512 + mt * 128) * 2048 + c * 128, 2048,
              ktT + ((size_t)bh * 256 + nt * 128) * 2048 + c * 128, 2048, 128,
              As, Bs, acc);
    EPI_SETUP
#pragma unroll
    for (int mf = 0; mf < 4; ++mf)
#pragma unroll
      for (int nf = 0; nf < 4; ++nf)
#pragma unroll
        for (int r = 0; r < 4; ++r) {
          const int j = mt * 128 + wr * 64 + mf * 16 + ((ln >> 4) << 2) + r;
          const int i = nt * 128 + wc * 64 + nf * 16 + (ln & 15);
          UT[(((size_t)(bh * 512 + j)) * 16 + c) * 256 + i] = f2b(acc[mf][nf][r]);
        }
  } else {
    const size_t base = ((size_t)bh * 2048 + c * 128) * 256;
    gemm_core(qt + base, 256, kt + base, 256, 256, As, Bs, acc);
    EPI_SETUP
    u16* Ap = Aw + (size_t)bhc * 16384;
#pragma unroll
    for (int mf = 0; mf < 4; ++mf)
#pragma unroll
      for (int nf = 0; nf < 4; ++nf)
#pragma unroll
        for (int r = 0; r < 4; ++r) {
          const int t = wr * 64 + mf * 16 + ((ln >> 4) << 2) + r;
          const int s = wc * 64 + nf * 16 + (ln & 15);
          Ap[t * 128 + s] = (s <= t) ? f2b(acc[mf][nf][r]) : (u16)0;
        }
  }
}

// ------ serial inter-chunk scan, in place on UT (bf16, fp32 accum) ----------
__global__ __launch_bounds__(256) void state_scan(
    u16* __restrict__ UT, const float* __restrict__ Dc)
{
  const int blk = blockIdx.x;               // 4096 = bh*512 + j
  const int bh = blk >> 9, j = blk & 511;
  const int i = threadIdx.x;
  u16* Up = UT + ((size_t)(bh * 512 + j)) * 16 * 256 + i;
  const float* Dp = Dc + bh * 16 * 256 + i;
  float S = 0.f;
  for (int c = 0; c < 16; ++c) {
    const float u = b2f(Up[c * 256]);
    Up[c * 256] = f2b(S);
    S = Dp[c * 256] * (S + u);
  }
}

// -------- ob = Aw @ V + qt @ S  (per bhc, 128-col tile of HV) ---------------
__global__ __launch_bounds__(256) void intra_k(
    const u16* __restrict__ Aw, const u16* __restrict__ qt,
    const u16* __restrict__ vT, const u16* __restrict__ UT, u16* __restrict__ ob)
{
  __shared__ __align__(16) u16 As[12288], Bs[12288];
  const int jt = blockIdx.x;
  const int bhc = blockIdx.y, bh = bhc >> 4, c = bhc & 15;
  f4v acc[4][4];
  ZERO_ACC(acc)
  gemm_core(Aw + (size_t)bhc * 16384, 128,
            vT + ((size_t)bh * 512 + jt * 128) * 2048 + c * 128, 2048, 128,
            As, Bs, acc);
  gemm_core(qt + ((size_t)bh * 2048 + c * 128) * 256, 256,
            UT + ((size_t)(bh * 512 + jt * 128)) * 4096 + (size_t)c * 256, 4096, 256,
            As, Bs, acc);
  EPI_SETUP
  const int b = bh >> 2, h = bh & 3;
#pragma unroll
  for (int mf = 0; mf < 4; ++mf)
#pragma unroll
    for (int nf = 0; nf < 4; ++nf)
#pragma unroll
      for (int r = 0; r < 4; ++r) {
        const int t = c * 128 + wr * 64 + mf * 16 + ((ln >> 4) << 2) + r;
        const int j = jt * 128 + wc * 64 + nf * 16 + (ln & 15);
        ob[((size_t)(b * 2048 + t)) * 2048 + h * 512 + j] = f2b(acc[mf][nf][r]);
      }
}

// ---------------- group RMSNorm (512) + SiLU gate, in place on ob -----------
__global__ __launch_bounds__(256) void rms_silu(
    u16* __restrict__ o, const u16* __restrict__ gpre, const float* __restrict__ w)
{
  const int grp = blockIdx.x * 4 + (threadIdx.x >> 6);
  const int lane = threadIdx.x & 63;
  const size_t base = (size_t)(grp >> 2) * 2048 + (grp & 3) * 512;
  float xv[8];
  float ss = 0.f;
#pragma unroll
  for (int i = 0; i < 8; ++i) {
    xv[i] = b2f(o[base + i * 64 + lane]);
    ss = fmaf(xv[i], xv[i], ss);
  }
#pragma unroll
  for (int off = 1; off < 64; off <<= 1) ss += __shfl_xor(ss, off, 64);
  const float r = rsqrtf(ss * (1.f / 512.f) + 1e-5f);
#pragma unroll
  for (int i = 0; i < 8; ++i) {
    const int cidx = i * 64 + lane;
    const float gp = b2f(gpre[base + cidx]);
    const float sig = 1.f / (1.f + expf(-gp));
    o[base + cidx] = f2b(xv[i] * r * w[cidx] * gp * sig);
  }
}

// ---------------- final: out = ob @ Wo, split-K=2 into pout -----------------
__global__ __launch_bounds__(256) void gemm_out(
    const u16* __restrict__ ob, const u16* __restrict__ WoT,
    float* __restrict__ pout)
{
  __shared__ __align__(16) u16 As[12288], Bs[12288];
  const int id = blockIdx.x;                 // 512 blocks, 64 per XCD
  const int wg = (id & 7) * 64 + (id >> 3);
  const int ks = wg >> 8;                    // K-half
  const int tt = wg & 255;
  const int m0 = (tt & 31) * 128, n0 = (tt >> 5) * 128;
  f4v acc[4][4];
  ZERO_ACC(acc)
  gemm_core(ob + (size_t)m0 * 2048 + ks * 1024, 2048,
            WoT + (size_t)n0 * 2048 + ks * 1024, 2048, 1024, As, Bs, acc);
  EPI_SETUP
  float* po = pout + (size_t)ks * 4194304;
#pragma unroll
  for (int mf = 0; mf < 4; ++mf)
#pragma unroll
    for (int nf = 0; nf < 4; ++nf)
#pragma unroll
      for (int r = 0; r < 4; ++r) {
        const int m = m0 + wr * 64 + mf * 16 + ((ln >> 4) << 2) + r;
        const int n = n0 + wc * 64 + nf * 16 + (ln & 15);
        po[(size_t)m * 1024 + n] = acc[mf][nf][r];
      }
}

__global__ __launch_bounds__(256) void reduce_out(
    const float* __restrict__ p, float* __restrict__ out)
{
  const int i = blockIdx.x * 256 + threadIdx.x;   // float4 granularity
  const float4 a = ((const float4*)p)[i];
  const float4 b = ((const float4*)(p + 4194304))[i];
  ((float4*)out)[i] = make_float4(a.x + b.x, a.y + b.y, a.z + b.z, a.w + b.w);
}

extern "C" void kernel_launch(void* const* d_in, const int* in_sizes, int n_in,
                              void* d_out, int out_size, void* d_ws, size_t ws_size,
                              hipStream_t stream) {
  const float* x    = (const float*)d_in[0];
  const float* Wq   = (const float*)d_in[1];
  const float* Wk   = (const float*)d_in[2];
  const float* Wv   = (const float*)d_in[3];
  const float* Wg   = (const float*)d_in[4];
  const float* w1   = (const float*)d_in[5];
  const float* w2   = (const float*)d_in[6];
  const float* gb   = (const float*)d_in[7];
  const float* Wo   = (const float*)d_in[8];
  const float* rmsw = (const float*)d_in[9];
  float* out = (float*)d_out;

  char* W = (char*)d_ws;
  u16*   xb   = (u16*)W;   W += (size_t)8  << 20;   // [4096][1024]
  u16*   WTa  = (u16*)W;   W += (size_t)12 << 20;   // [6144][1024]
  u16*   WoT  = (u16*)W;   W += (size_t)4  << 20;   // [1024][2048]
  u16*   qt   = (u16*)W;   W += (size_t)8  << 20;   // [8][2048][256]
  u16*   kt   = (u16*)W;   W += (size_t)8  << 20;
  u16*   vr   = (u16*)W;   W += (size_t)16 << 20;   // [8][2048][512]
  u16*   vT   = (u16*)W;   W += (size_t)16 << 20;   // [8][512][2048]
  u16*   ktT  = (u16*)W;   W += (size_t)8  << 20;   // [8][256][2048]
  u16*   gpre = (u16*)W;   W += (size_t)16 << 20;   // [4096][2048]
  float* tmp  = (float*)W; W += (size_t)256 << 10;  // [4096][16]
  float* Dc   = (float*)W; W += (size_t)128 << 10;  // [8][16][256]
  u16*   dq   = (u16*)W;   W += (size_t)8  << 20;   // [8][2048][256] bf16 e^B
  u16*   dk   = (u16*)W;   W += (size_t)8  << 20;   // e^-B
  u16*   UT   = (u16*)W;   W += (size_t)32 << 20;   // [8][512][16][256]
  u16*   Aw   = (u16*)W;   W += (size_t)4  << 20;   // [128][128][128]
  u16*   ob   = (u16*)W;   W += (size_t)16 << 20;   // [4096][2048]
  float* pout = (float*)W; W += (size_t)32 << 20;   // [2][4096][1024]

  // gate pipeline first (dq/dk needed by proj_all)
  hipLaunchKernelGGL(lowrank1, dim3(256), dim3(256), 0, stream, x, w1, tmp);
  hipLaunchKernelGGL(gate_cum, dim3(4, 32), dim3(256), 0, stream,
                     tmp, w2, gb, dq, dk, Dc);

  // bf16 conversions / weight transposes
  hipLaunchKernelGGL(cast_b, dim3(4096), dim3(256), 0, stream, x, xb);
  hipLaunchKernelGGL(wtrans, dim3(32, 32), dim3(256), 0, stream, Wq, WTa, 1024, 1024);
  hipLaunchKernelGGL(wtrans, dim3(32, 32), dim3(256), 0, stream, Wk, WTa + 1048576, 1024, 1024);
  hipLaunchKernelGGL(wtrans, dim3(64, 32), dim3(256), 0, stream, Wv, WTa + 2097152, 1024, 2048);
  hipLaunchKernelGGL(wtrans, dim3(64, 32), dim3(256), 0, stream, Wg, WTa + 4194304, 1024, 2048);
  hipLaunchKernelGGL(wtrans, dim3(32, 64), dim3(256), 0, stream, Wo, WoT, 2048, 1024);

  // fused q/k/v/g projections with decay applied in epilogue
  hipLaunchKernelGGL(proj_all, dim3(1536), dim3(256), 0, stream,
                     xb, WTa, dq, dk, qt, kt, vr, gpre);

  // layout transposes for the scan GEMMs
  hipLaunchKernelGGL(trans_b16, dim3(8, 64, 8), dim3(256), 0, stream,
                     kt, ktT, 2048, 256);
  hipLaunchKernelGGL(trans_b16, dim3(16, 64, 8), dim3(256), 0, stream,
                     vr, vT, 2048, 512);

  // chunked scan: (chunk_state || qk_causal) -> state_scan -> intra
  hipLaunchKernelGGL(scan_gemms, dim3(9, 128), dim3(256), 0, stream,
                     vT, ktT, qt, kt, UT, Aw);
  hipLaunchKernelGGL(state_scan, dim3(4096), dim3(256), 0, stream, UT, Dc);
  hipLaunchKernelGGL(intra_k, dim3(4, 128), dim3(256), 0, stream, Aw, qt, vT, UT, ob);

  // group RMSNorm + SiLU gate (in place), then output projection (split-K)
  hipLaunchKernelGGL(rms_silu, dim3(4096), dim3(256), 0, stream, ob, gpre, rmsw);
  hipLaunchKernelGGL(gemm_out, dim3(512), dim3(256), 0, stream, ob, WoT, pout);
  hipLaunchKernelGGL(reduce_out, dim3(4096), dim3(256), 0, stream, pout, out);
}

// Round 7
// 307.598 us; speedup vs baseline: 9.1375x; 1.0324x over previous
//
#include <hip/hip_runtime.h>
#include <cstdint>
#include <cstddef>

// GLA forward, bf16 MFMA pipeline, 3-deep counted-vmcnt + conflict-free
// XOR-swizzled LDS (pre-swizzled global source, rule #21 both-sides).
// B=2, T=2048, D=1024, H=4, HK=256, HV=512, DK=1024, DV=2048, LR=16, CHUNK=128

typedef unsigned short u16;
typedef __attribute__((ext_vector_type(8))) short s8v;   // 8 x bf16 (4 VGPR)
typedef __attribute__((ext_vector_type(4))) float f4v;   // MFMA accumulator

__device__ __forceinline__ u16 f2b(float f) {
  unsigned u = __builtin_bit_cast(unsigned, f);
  unsigned r = u + 0x7FFFu + ((u >> 16) & 1u);   // RNE
  return (u16)(r >> 16);
}
__device__ __forceinline__ float b2f(u16 h) {
  unsigned u = ((unsigned)h) << 16;
  return __builtin_bit_cast(float, u);
}

// async global->LDS, 16B per lane; LDS dest is wave-uniform base + lane*16
__device__ __forceinline__ void cp16(const void* g, void* l) {
  __builtin_amdgcn_global_load_lds(
      (const __attribute__((address_space(1))) unsigned int*)g,
      (__attribute__((address_space(3))) unsigned int*)l, 16, 0, 0);
}

// ---- shared MFMA core: C[128x128] += A[128xK] * BT[128xK]^T, bf16, BK=32 ----
// LDS tile logical [128 rows][32 cols]; element (R, quarter Q) stored at
// physical quarter Q ^ ((R>>1)&3)  -> 2-way max bank aliasing on ds_read_b128.
// Stage keeps LDS dest linear; the global SOURCE is quarter-permuted instead.
__device__ __forceinline__ void stage_tile(const u16* g, int ld, u16* lds,
                                           int wv, int ln) {
  // dest row r = c*16 + (ln>>2), dest slot = ln&3; content = logical quarter
  // q = slot ^ ((r>>1)&3) = (ln&3) ^ ((ln>>3)&3)
  const int q = (ln & 3) ^ ((ln >> 3) & 3);
#pragma unroll
  for (int i = 0; i < 2; ++i) {
    const int c = wv * 2 + i;                       // 1KB chunk id 0..7
    const u16* src = g + (size_t)(c * 16 + (ln >> 2)) * ld + q * 8;
    cp16(src, lds + c * 512);
  }
}

__device__ __forceinline__ void gemm_core(
    const u16* __restrict__ A, int lda, const u16* __restrict__ BT, int ldb,
    int K, u16* As, u16* Bs, f4v acc[4][4])
{
  const int tid = threadIdx.x;
  const int ln = tid & 63, wv = tid >> 6;
  const int arow = (wv >> 1) * 64 + (ln & 15);
  const int brow = (wv & 1) * 64 + (ln & 15);
  // swizzled K-offset: logical quarter ln>>4 of row R -> physical
  // quarter (ln>>4) ^ ((R>>1)&3); (R>>1)&3 == (ln>>1)&3 (R = 16a + (ln&15)).
  const int koff = (((ln >> 4) ^ ((ln >> 1) & 3)) * 8);
  const int nt = K >> 5;                     // #K-tiles, always >= 4 here
  // prologue: fill all 3 slots (12 loads per wave in flight)
  stage_tile(A, lda, As, wv, ln);
  stage_tile(BT, ldb, Bs, wv, ln);
  stage_tile(A + 32, lda, As + 4096, wv, ln);
  stage_tile(BT + 32, ldb, Bs + 4096, wv, ln);
  stage_tile(A + 64, lda, As + 8192, wv, ln);
  stage_tile(BT + 64, ldb, Bs + 8192, wv, ln);
  int slot = 0;
  for (int t = 0; t < nt; ++t) {
    const int rem = nt - 1 - t;
    // confirm tile t landed; keep newer tiles' loads in flight (T4)
    if (rem >= 2)      asm volatile("s_waitcnt vmcnt(8)" ::: "memory");
    else if (rem == 1) asm volatile("s_waitcnt vmcnt(4)" ::: "memory");
    else               asm volatile("s_waitcnt vmcnt(0)" ::: "memory");
    __builtin_amdgcn_s_barrier();            // all waves: slot data ready
    __builtin_amdgcn_sched_barrier(0);
    const u16* Ab = As + slot * 4096;
    const u16* Bb = Bs + slot * 4096;
    s8v af[4], bf[4];
#pragma unroll
    for (int f = 0; f < 4; ++f)
      af[f] = *(const s8v*)(Ab + (arow + f * 16) * 32 + koff);
#pragma unroll
    for (int f = 0; f < 4; ++f)
      bf[f] = *(const s8v*)(Bb + (brow + f * 16) * 32 + koff);
#pragma unroll
    for (int mf = 0; mf < 4; ++mf)
#pragma unroll
      for (int nf = 0; nf < 4; ++nf)
        acc[mf][nf] = __builtin_amdgcn_mfma_f32_16x16x32_bf16(
            af[mf], bf[nf], acc[mf][nf], 0, 0, 0);
    __builtin_amdgcn_sched_barrier(0);
    __builtin_amdgcn_s_barrier();            // all waves done reading slot
    if (t + 3 < nt) {                        // refill freed slot
      stage_tile(A + (t + 3) * 32, lda, As + slot * 4096, wv, ln);
      stage_tile(BT + (t + 3) * 32, ldb, Bs + slot * 4096, wv, ln);
    }
    slot = (slot == 2) ? 0 : slot + 1;
  }
}

#define EPI_SETUP                                            \
  const int tid = threadIdx.x;                               \
  const int ln = tid & 63, wv = tid >> 6;                    \
  const int wr = wv >> 1, wc = wv & 1;

#define ZERO_ACC(acc)                                        \
  _Pragma("unroll")                                          \
  for (int zi = 0; zi < 4; ++zi)                             \
    _Pragma("unroll")                                        \
    for (int zj = 0; zj < 4; ++zj)                           \
      acc[zi][zj] = (f4v){0.f, 0.f, 0.f, 0.f};

// ---------------- elementwise / transpose helpers ----------------
__global__ __launch_bounds__(256) void cast_b(const float* __restrict__ in,
                                              u16* __restrict__ out) {
  const int i = blockIdx.x * 256 + threadIdx.x;
  const float4 v = ((const float4*)in)[i];
  u16* p = out + i * 4;
  p[0] = f2b(v.x); p[1] = f2b(v.y); p[2] = f2b(v.z); p[3] = f2b(v.w);
}

// all 5 weight transposes fused: W [R][C] f32 -> WT [C][R] bf16
__global__ __launch_bounds__(256) void wtrans_all(
    const float* __restrict__ Wq, const float* __restrict__ Wk,
    const float* __restrict__ Wv, const float* __restrict__ Wg,
    const float* __restrict__ Wo, u16* __restrict__ WTa, u16* __restrict__ WoT)
{
  __shared__ float t[32][33];
  const int id = blockIdx.x;
  const float* src; u16* dst; int R, C, local;
  if (id < 1024)      { src = Wq; dst = WTa;           R = 1024; C = 1024; local = id; }
  else if (id < 2048) { src = Wk; dst = WTa + 1048576; R = 1024; C = 1024; local = id - 1024; }
  else if (id < 4096) { src = Wv; dst = WTa + 2097152; R = 1024; C = 2048; local = id - 2048; }
  else if (id < 6144) { src = Wg; dst = WTa + 4194304; R = 1024; C = 2048; local = id - 4096; }
  else                { src = Wo; dst = WoT;           R = 2048; C = 1024; local = id - 6144; }
  const int nx = C >> 5;
  const int c0 = (local % nx) * 32, r0 = (local / nx) * 32;
  const int lx = threadIdx.x & 31, ly = threadIdx.x >> 5;
#pragma unroll
  for (int i = 0; i < 32; i += 8)
    t[ly + i][lx] = src[(size_t)(r0 + ly + i) * C + c0 + lx];
  __syncthreads();
#pragma unroll
  for (int i = 0; i < 32; i += 8)
    dst[(size_t)(c0 + ly + i) * R + r0 + lx] = f2b(t[lx][ly + i]);
}

// both activation transposes fused: kt->ktT (8x[2048][256]), vr->vT (8x[2048][512])
__global__ __launch_bounds__(256) void trans_all(
    const u16* __restrict__ kt, u16* __restrict__ ktT,
    const u16* __restrict__ vr, u16* __restrict__ vT)
{
  __shared__ u16 t[32][33];
  const int id = blockIdx.x;
  const u16* in; u16* out; int R = 2048, C, z, local;
  if (id < 4096) { in = kt; out = ktT; C = 256;  z = id >> 9;  local = id & 511; }
  else { const int i2 = id - 4096; in = vr; out = vT; C = 512; z = i2 >> 10; local = i2 & 1023; }
  const int nx = C >> 5;
  const int c0 = (local % nx) * 32, r0 = (local / nx) * 32;
  const size_t boff = (size_t)z * R * C;
  const int lx = threadIdx.x & 31, ly = threadIdx.x >> 5;
#pragma unroll
  for (int i = 0; i < 32; i += 8)
    t[ly + i][lx] = in[boff + (size_t)(r0 + ly + i) * C + c0 + lx];
  __syncthreads();
#pragma unroll
  for (int i = 0; i < 32; i += 8)
    out[boff + (size_t)(c0 + ly + i) * R + r0 + lx] = t[lx][ly + i];
}

// ---------------- low-rank gate part 1: tmp[4096,16] = x @ w1 ----------------
__global__ __launch_bounds__(256) void lowrank1(
    const float* __restrict__ x, const float* __restrict__ w1,
    float* __restrict__ tmp)
{
  const int idx = blockIdx.x * 256 + threadIdx.x;
  const int m = idx >> 4, i = idx & 15;
  const float* xr = x + (size_t)m * 1024;
  float acc = 0.f;
#pragma unroll 4
  for (int kk = 0; kk < 1024; kk += 4) {
    const float4 xv = *(const float4*)(xr + kk);
    acc = fmaf(xv.x, w1[(kk + 0) * 16 + i], acc);
    acc = fmaf(xv.y, w1[(kk + 1) * 16 + i], acc);
    acc = fmaf(xv.z, w1[(kk + 2) * 16 + i], acc);
    acc = fmaf(xv.w, w1[(kk + 3) * 16 + i], acc);
  }
  tmp[idx] = acc;
}

// -------- gate cumsum -> bf16 decay factors dq = e^B, dk = e^-B; Dc = e^B_end
__global__ __launch_bounds__(256) void gate_cum(
    const float* __restrict__ tmp, const float* __restrict__ w2,
    const float* __restrict__ bias, u16* __restrict__ dq, u16* __restrict__ dk,
    float* __restrict__ Dc)
{
  __shared__ float ls_t[2048];   // tmp slice for this (b, c): 128 t x 16
  const int b = blockIdx.y >> 4, c = blockIdx.y & 15;
  const int h = blockIdx.x;
  const int i = threadIdx.x;
  const int n = h * 256 + i;
  const int bh = b * 4 + h;
  const float* tp = tmp + ((size_t)(b * 2048 + c * 128)) * 16;
#pragma unroll
  for (int r = 0; r < 8; ++r) ls_t[r * 256 + threadIdx.x] = tp[r * 256 + threadIdx.x];
  __syncthreads();
  float w2c[16];
#pragma unroll
  for (int r = 0; r < 16; ++r) w2c[r] = w2[r * 1024 + n];
  const float bn = bias[n];
  const size_t base = ((size_t)bh * 2048 + c * 128) * 256 + i;
  float B = 0.f;
  for (int t = 0; t < 128; ++t) {
    float gl = bn;
    const float* tr = ls_t + t * 16;
#pragma unroll
    for (int r = 0; r < 16; ++r) gl = fmaf(tr[r], w2c[r], gl);
    const float ls = fminf(gl, 0.f) - log1pf(expf(-fabsf(gl)));
    B += ls * 0.0625f;
    const float eB = expf(B);
    dq[base + (size_t)t * 256] = f2b(eB);
    dk[base + (size_t)t * 256] = f2b(1.f / eB);
  }
  Dc[(bh * 16 + c) * 256 + i] = expf(B);
}

// ---------------- fused projections: xb[4096,1024] @ [Wq|Wk|Wv|Wg] ----------
__global__ __launch_bounds__(256) void proj_all(
    const u16* __restrict__ xb, const u16* __restrict__ WT,
    const u16* __restrict__ dq, const u16* __restrict__ dk,
    u16* __restrict__ qt, u16* __restrict__ kt,
    u16* __restrict__ vr, u16* __restrict__ gpre)
{
  __shared__ __align__(16) u16 As[12288], Bs[12288];
  // XCD-chunked swizzle, n-fast within XCD: A-tile stays hot across its 6 uses
  const int id = blockIdx.x;
  const int xcd = id & 7, j = id >> 3;         // j in [0,192)
  const int m0 = (j / 6) * 128;
  const int n0 = (xcd * 6 + (j % 6)) * 128;
  f4v acc[4][4];
  ZERO_ACC(acc)
  gemm_core(xb + (size_t)m0 * 1024, 1024, WT + (size_t)n0 * 1024, 1024, 1024,
            As, Bs, acc);
  EPI_SETUP
#pragma unroll
  for (int mf = 0; mf < 4; ++mf)
#pragma unroll
    for (int nf = 0; nf < 4; ++nf)
#pragma unroll
      for (int r = 0; r < 4; ++r) {
        const int m = m0 + wr * 64 + mf * 16 + ((ln >> 4) << 2) + r;
        const int n = n0 + wc * 64 + nf * 16 + (ln & 15);
        const float val = acc[mf][nf][r];
        const int b = m >> 11, t = m & 2047;
        if (n0 < 1024) {
          const int bh = b * 4 + (n >> 8), i = n & 255;
          const size_t off = ((size_t)bh * 2048 + t) * 256 + i;
          qt[off] = f2b(val * 0.0625f * b2f(dq[off]));
        } else if (n0 < 2048) {
          const int nn = n - 1024;
          const int bh = b * 4 + (nn >> 8), i = nn & 255;
          const size_t off = ((size_t)bh * 2048 + t) * 256 + i;
          kt[off] = f2b(val * b2f(dk[off]));
        } else if (n0 < 4096) {
          const int nn = n - 2048;
          const int bh = b * 4 + (nn >> 9), jj = nn & 511;
          vr[((size_t)bh * 2048 + t) * 512 + jj] = f2b(val);
        } else {
          gpre[(size_t)m * 2048 + (n - 4096)] = f2b(val);
        }
      }
}

// ------- merged scan GEMMs: x<8 -> chunk_state tile, x==8 -> qk_causal ------
__global__ __launch_bounds__(256) void scan_gemms(
    const u16* __restrict__ vT, const u16* __restrict__ ktT,
    const u16* __restrict__ qt, const u16* __restrict__ kt,
    u16* __restrict__ UT, u16* __restrict__ Aw)
{
  __shared__ __align__(16) u16 As[12288], Bs[12288];
  const int bhc = blockIdx.y, bh = bhc >> 4, c = bhc & 15;
  f4v acc[4][4];
  ZERO_ACC(acc)
  if (blockIdx.x < 8) {
    const int mt = blockIdx.x >> 1, nt = blockIdx.x & 1;
    gemm_core(vT + ((size_t)bh * 512 + mt * 128) * 2048 + c * 128, 2048,
              ktT + ((size_t)bh * 256 + nt * 128) * 2048 + c * 128, 2048, 128,
              As, Bs, acc);
    EPI_SETUP
#pragma unroll
    for (int mf = 0; mf < 4; ++mf)
#pragma unroll
      for (int nf = 0; nf < 4; ++nf)
#pragma unroll
        for (int r = 0; r < 4; ++r) {
          const int j = mt * 128 + wr * 64 + mf * 16 + ((ln >> 4) << 2) + r;
          const int i = nt * 128 + wc * 64 + nf * 16 + (ln & 15);
          UT[(((size_t)(bh * 512 + j)) * 16 + c) * 256 + i] = f2b(acc[mf][nf][r]);
        }
  } else {
    const size_t base = ((size_t)bh * 2048 + c * 128) * 256;
    gemm_core(qt + base, 256, kt + base, 256, 256, As, Bs, acc);
    EPI_SETUP
    u16* Ap = Aw + (size_t)bhc * 16384;
#pragma unroll
    for (int mf = 0; mf < 4; ++mf)
#pragma unroll
      for (int nf = 0; nf < 4; ++nf)
#pragma unroll
        for (int r = 0; r < 4; ++r) {
          const int t = wr * 64 + mf * 16 + ((ln >> 4) << 2) + r;
          const int s = wc * 64 + nf * 16 + (ln & 15);
          Ap[t * 128 + s] = (s <= t) ? f2b(acc[mf][nf][r]) : (u16)0;
        }
  }
}

// ------ serial inter-chunk scan, in place on UT (bf16, fp32 accum) ----------
__global__ __launch_bounds__(256) void state_scan(
    u16* __restrict__ UT, const float* __restrict__ Dc)
{
  const int blk = blockIdx.x;               // 4096 = bh*512 + j
  const int bh = blk >> 9, j = blk & 511;
  const int i = threadIdx.x;
  u16* Up = UT + ((size_t)(bh * 512 + j)) * 16 * 256 + i;
  const float* Dp = Dc + bh * 16 * 256 + i;
  float S = 0.f;
  for (int c = 0; c < 16; ++c) {
    const float u = b2f(Up[c * 256]);
    Up[c * 256] = f2b(S);
    S = Dp[c * 256] * (S + u);
  }
}

// -------- ob = Aw @ V + qt @ S  (per bhc, 128-col tile of HV) ---------------
__global__ __launch_bounds__(256) void intra_k(
    const u16* __restrict__ Aw, const u16* __restrict__ qt,
    const u16* __restrict__ vT, const u16* __restrict__ UT, u16* __restrict__ ob)
{
  __shared__ __align__(16) u16 As[12288], Bs[12288];
  const int jt = blockIdx.x;
  const int bhc = blockIdx.y, bh = bhc >> 4, c = bhc & 15;
  f4v acc[4][4];
  ZERO_ACC(acc)
  gemm_core(Aw + (size_t)bhc * 16384, 128,
            vT + ((size_t)bh * 512 + jt * 128) * 2048 + c * 128, 2048, 128,
            As, Bs, acc);
  gemm_core(qt + ((size_t)bh * 2048 + c * 128) * 256, 256,
            UT + ((size_t)(bh * 512 + jt * 128)) * 4096 + (size_t)c * 256, 4096, 256,
            As, Bs, acc);
  EPI_SETUP
  const int b = bh >> 2, h = bh & 3;
#pragma unroll
  for (int mf = 0; mf < 4; ++mf)
#pragma unroll
    for (int nf = 0; nf < 4; ++nf)
#pragma unroll
      for (int r = 0; r < 4; ++r) {
        const int t = c * 128 + wr * 64 + mf * 16 + ((ln >> 4) << 2) + r;
        const int j = jt * 128 + wc * 64 + nf * 16 + (ln & 15);
        ob[((size_t)(b * 2048 + t)) * 2048 + h * 512 + j] = f2b(acc[mf][nf][r]);
      }
}

// ---------------- group RMSNorm (512) + SiLU gate, in place on ob -----------
__global__ __launch_bounds__(256) void rms_silu(
    u16* __restrict__ o, const u16* __restrict__ gpre, const float* __restrict__ w)
{
  const int grp = blockIdx.x * 4 + (threadIdx.x >> 6);
  const int lane = threadIdx.x & 63;
  const size_t base = (size_t)(grp >> 2) * 2048 + (grp & 3) * 512;
  float xv[8];
  float ss = 0.f;
#pragma unroll
  for (int i = 0; i < 8; ++i) {
    xv[i] = b2f(o[base + i * 64 + lane]);
    ss = fmaf(xv[i], xv[i], ss);
  }
#pragma unroll
  for (int off = 1; off < 64; off <<= 1) ss += __shfl_xor(ss, off, 64);
  const float r = rsqrtf(ss * (1.f / 512.f) + 1e-5f);
#pragma unroll
  for (int i = 0; i < 8; ++i) {
    const int cidx = i * 64 + lane;
    const float gp = b2f(gpre[base + cidx]);
    const float sig = 1.f / (1.f + expf(-gp));
    o[base + cidx] = f2b(xv[i] * r * w[cidx] * gp * sig);
  }
}

// ---------------- final: out = ob @ Wo, split-K=2 into pout -----------------
__global__ __launch_bounds__(256) void gemm_out(
    const u16* __restrict__ ob, const u16* __restrict__ WoT,
    float* __restrict__ pout)
{
  __shared__ __align__(16) u16 As[12288], Bs[12288];
  const int id = blockIdx.x;                 // 512 blocks, 64 per XCD
  const int wg = (id & 7) * 64 + (id >> 3);
  const int ks = wg >> 8;                    // K-half
  const int tt = wg & 255;
  const int m0 = (tt & 31) * 128, n0 = (tt >> 5) * 128;
  f4v acc[4][4];
  ZERO_ACC(acc)
  gemm_core(ob + (size_t)m0 * 2048 + ks * 1024, 2048,
            WoT + (size_t)n0 * 2048 + ks * 1024, 2048, 1024, As, Bs, acc);
  EPI_SETUP
  float* po = pout + (size_t)ks * 4194304;
#pragma unroll
  for (int mf = 0; mf < 4; ++mf)
#pragma unroll
    for (int nf = 0; nf < 4; ++nf)
#pragma unroll
      for (int r = 0; r < 4; ++r) {
        const int m = m0 + wr * 64 + mf * 16 + ((ln >> 4) << 2) + r;
        const int n = n0 + wc * 64 + nf * 16 + (ln & 15);
        po[(size_t)m * 1024 + n] = acc[mf][nf][r];
      }
}

__global__ __launch_bounds__(256) void reduce_out(
    const float* __restrict__ p, float* __restrict__ out)
{
  const int i = blockIdx.x * 256 + threadIdx.x;   // float4 granularity
  const float4 a = ((const float4*)p)[i];
  const float4 b = ((const float4*)(p + 4194304))[i];
  ((float4*)out)[i] = make_float4(a.x + b.x, a.y + b.y, a.z + b.z, a.w + b.w);
}

extern "C" void kernel_launch(void* const* d_in, const int* in_sizes, int n_in,
                              void* d_out, int out_size, void* d_ws, size_t ws_size,
                              hipStream_t stream) {
  const float* x    = (const float*)d_in[0];
  const float* Wq   = (const float*)d_in[1];
  const float* Wk   = (const float*)d_in[2];
  const float* Wv   = (const float*)d_in[3];
  const float* Wg   = (const float*)d_in[4];
  const float* w1   = (const float*)d_in[5];
  const float* w2   = (const float*)d_in[6];
  const float* gb   = (const float*)d_in[7];
  const float* Wo   = (const float*)d_in[8];
  const float* rmsw = (const float*)d_in[9];
  float* out = (float*)d_out;

  char* W = (char*)d_ws;
  u16*   xb   = (u16*)W;   W += (size_t)8  << 20;   // [4096][1024]
  u16*   WTa  = (u16*)W;   W += (size_t)12 << 20;   // [6144][1024]
  u16*   WoT  = (u16*)W;   W += (size_t)4  << 20;   // [1024][2048]
  u16*   qt   = (u16*)W;   W += (size_t)8  << 20;   // [8][2048][256]
  u16*   kt   = (u16*)W;   W += (size_t)8  << 20;
  u16*   vr   = (u16*)W;   W += (size_t)16 << 20;   // [8][2048][512]
  u16*   vT   = (u16*)W;   W += (size_t)16 << 20;   // [8][512][2048]
  u16*   ktT  = (u16*)W;   W += (size_t)8  << 20;   // [8][256][2048]
  u16*   gpre = (u16*)W;   W += (size_t)16 << 20;   // [4096][2048]
  float* tmp  = (float*)W; W += (size_t)256 << 10;  // [4096][16]
  float* Dc   = (float*)W; W += (size_t)128 << 10;  // [8][16][256]
  u16*   dq   = (u16*)W;   W += (size_t)8  << 20;   // [8][2048][256] bf16 e^B
  u16*   dk   = (u16*)W;   W += (size_t)8  << 20;   // e^-B
  u16*   UT   = (u16*)W;   W += (size_t)32 << 20;   // [8][512][16][256]
  u16*   Aw   = (u16*)W;   W += (size_t)4  << 20;   // [128][128][128]
  u16*   ob   = (u16*)W;   W += (size_t)16 << 20;   // [4096][2048]
  float* pout = (float*)W; W += (size_t)32 << 20;   // [2][4096][1024]

  // gate pipeline first (dq/dk needed by proj_all)
  hipLaunchKernelGGL(lowrank1, dim3(256), dim3(256), 0, stream, x, w1, tmp);
  hipLaunchKernelGGL(gate_cum, dim3(4, 32), dim3(256), 0, stream,
                     tmp, w2, gb, dq, dk, Dc);

  // bf16 conversions / weight transposes (fused)
  hipLaunchKernelGGL(cast_b, dim3(4096), dim3(256), 0, stream, x, xb);
  hipLaunchKernelGGL(wtrans_all, dim3(8192), dim3(256), 0, stream,
                     Wq, Wk, Wv, Wg, Wo, WTa, WoT);

  // fused q/k/v/g projections with decay applied in epilogue
  hipLaunchKernelGGL(proj_all, dim3(1536), dim3(256), 0, stream,
                     xb, WTa, dq, dk, qt, kt, vr, gpre);

  // layout transposes for the scan GEMMs (fused)
  hipLaunchKernelGGL(trans_all, dim3(12288), dim3(256), 0, stream,
                     kt, ktT, vr, vT);

  // chunked scan: (chunk_state || qk_causal) -> state_scan -> intra
  hipLaunchKernelGGL(scan_gemms, dim3(9, 128), dim3(256), 0, stream,
                     vT, ktT, qt, kt, UT, Aw);
  hipLaunchKernelGGL(state_scan, dim3(4096), dim3(256), 0, stream, UT, Dc);
  hipLaunchKernelGGL(intra_k, dim3(4, 128), dim3(256), 0, stream, Aw, qt, vT, UT, ob);

  // group RMSNorm + SiLU gate (in place), then output projection (split-K)
  hipLaunchKernelGGL(rms_silu, dim3(4096), dim3(256), 0, stream, ob, gpre, rmsw);
  hipLaunchKernelGGL(gemm_out, dim3(512), dim3(256), 0, stream, ob, WoT, pout);
  hipLaunchKernelGGL(reduce_out, dim3(4096), dim3(256), 0, stream, pout, out);
}

// Round 9
// 277.399 us; speedup vs baseline: 10.1322x; 1.1089x over previous
//
#include <hip/hip_runtime.h>
#include <cstdint>
#include <cstddef>

// GLA forward, bf16 MFMA pipeline: 2-slot counted-vmcnt loop, XOR-swizzled LDS,
// coalesced LDS-roundtrip epilogues (lambda-based).
// B=2, T=2048, D=1024, H=4, HK=256, HV=512, DK=1024, DV=2048, LR=16, CHUNK=128

typedef unsigned short u16;
typedef __attribute__((ext_vector_type(8))) short s8v;   // 8 x bf16 (4 VGPR)
typedef __attribute__((ext_vector_type(4))) float f4v;   // MFMA accumulator

__device__ __forceinline__ u16 f2b(float f) {
  unsigned u = __builtin_bit_cast(unsigned, f);
  unsigned r = u + 0x7FFFu + ((u >> 16) & 1u);   // RNE
  return (u16)(r >> 16);
}
__device__ __forceinline__ float b2f(u16 h) {
  unsigned u = ((unsigned)h) << 16;
  return __builtin_bit_cast(float, u);
}

// async global->LDS, 16B per lane; LDS dest is wave-uniform base + lane*16
__device__ __forceinline__ void cp16(const void* g, void* l) {
  __builtin_amdgcn_global_load_lds(
      (const __attribute__((address_space(1))) unsigned int*)g,
      (__attribute__((address_space(3))) unsigned int*)l, 16, 0, 0);
}

// ---- shared MFMA core: C[128x128] += A[128xK] * BT[128xK]^T, bf16, BK=32 ----
// LDS tile logical [128 rows][32 cols]; element (R, quarter Q) stored at
// physical quarter Q ^ ((R>>1)&3). Stage keeps LDS dest linear; global SOURCE
// is quarter-permuted (rule #21 both-sides). 2-slot double buffer,
// counted vmcnt(4) so next tile's loads stay in flight across barriers.
__device__ __forceinline__ void stage_tile(const u16* g, int ld, u16* lds,
                                           int wv, int ln) {
  const int q = (ln & 3) ^ ((ln >> 3) & 3);
#pragma unroll
  for (int i = 0; i < 2; ++i) {
    const int c = wv * 2 + i;                       // 1KB chunk id 0..7
    const u16* src = g + (size_t)(c * 16 + (ln >> 2)) * ld + q * 8;
    cp16(src, lds + c * 512);
  }
}

__device__ __forceinline__ void gemm_core(
    const u16* __restrict__ A, int lda, const u16* __restrict__ BT, int ldb,
    int K, u16* As, u16* Bs, f4v acc[4][4])
{
  const int tid = threadIdx.x;
  const int ln = tid & 63, wv = tid >> 6;
  const int arow = (wv >> 1) * 64 + (ln & 15);
  const int brow = (wv & 1) * 64 + (ln & 15);
  const int koff = (((ln >> 4) ^ ((ln >> 1) & 3)) * 8);
  const int nt = K >> 5;                     // #K-tiles, >= 4 for all callers
  // prologue: fill both slots (8 loads per wave in flight)
  stage_tile(A, lda, As, wv, ln);
  stage_tile(BT, ldb, Bs, wv, ln);
  stage_tile(A + 32, lda, As + 4096, wv, ln);
  stage_tile(BT + 32, ldb, Bs + 4096, wv, ln);
  int slot = 0;
  for (int t = 0; t < nt; ++t) {
    if (t + 1 < nt) asm volatile("s_waitcnt vmcnt(4)" ::: "memory");
    else            asm volatile("s_waitcnt vmcnt(0)" ::: "memory");
    __builtin_amdgcn_s_barrier();            // all waves: slot data ready
    __builtin_amdgcn_sched_barrier(0);
    const u16* Ab = As + slot * 4096;
    const u16* Bb = Bs + slot * 4096;
    s8v af[4], bf[4];
#pragma unroll
    for (int f = 0; f < 4; ++f)
      af[f] = *(const s8v*)(Ab + (arow + f * 16) * 32 + koff);
#pragma unroll
    for (int f = 0; f < 4; ++f)
      bf[f] = *(const s8v*)(Bb + (brow + f * 16) * 32 + koff);
#pragma unroll
    for (int mf = 0; mf < 4; ++mf)
#pragma unroll
      for (int nf = 0; nf < 4; ++nf)
        acc[mf][nf] = __builtin_amdgcn_mfma_f32_16x16x32_bf16(
            af[mf], bf[nf], acc[mf][nf], 0, 0, 0);
    __builtin_amdgcn_sched_barrier(0);
    __builtin_amdgcn_s_barrier();            // all waves done reading slot
    if (t + 2 < nt) {                        // refill freed slot
      stage_tile(A + (t + 2) * 32, lda, As + slot * 4096, wv, ln);
      stage_tile(BT + (t + 2) * 32, ldb, Bs + slot * 4096, wv, ln);
    }
    slot ^= 1;
  }
}

// ---- epilogue part 1: fragments -> LDS (bf16, row stride 72 = 16B aligned) --
// wave wv's 64x64 quadrant at S + wv*4608. C-layout: col=ln&15, row=(ln>>4)*4+r
__device__ __forceinline__ void frag_to_lds(u16* S, const f4v acc[4][4],
                                            int ln, int wv) {
  u16* q = S + wv * 4608;
#pragma unroll
  for (int mf = 0; mf < 4; ++mf)
#pragma unroll
    for (int nf = 0; nf < 4; ++nf)
#pragma unroll
      for (int r = 0; r < 4; ++r)
        q[(mf * 16 + ((ln >> 4) << 2) + r) * 72 + nf * 16 + (ln & 15)] =
            f2b(acc[mf][nf][r]);
}

// epilogue part 2: 8 passes, 16 threads/row, one b128 LDS read per thread,
// then the caller's functor issues one coalesced 16B global store.
template <typename F>
__device__ __forceinline__ void epi_loop(u16* S, const f4v acc[4][4], F f) {
  const int tid = threadIdx.x;
  frag_to_lds(S, acc, tid & 63, tid >> 6);
  __syncthreads();
#pragma unroll
  for (int p = 0; p < 8; ++p) {
    const int r = p * 16 + (tid >> 4);
    const int c0 = (tid & 15) * 8;
    const int quad = ((r >> 6) << 1) + (c0 >> 6);
    s8v vv = *(const s8v*)(S + quad * 4608 + (r & 63) * 72 + (c0 & 63));
    f(r, c0, vv);
  }
}

// ---------------- elementwise / transpose helpers ----------------
__global__ __launch_bounds__(256) void cast_b(const float* __restrict__ in,
                                              u16* __restrict__ out) {
  const int i = blockIdx.x * 256 + threadIdx.x;
  const float4 v = ((const float4*)in)[i];
  u16* p = out + i * 4;
  p[0] = f2b(v.x); p[1] = f2b(v.y); p[2] = f2b(v.z); p[3] = f2b(v.w);
}

// all 5 weight transposes fused: W [R][C] f32 -> WT [C][R] bf16
__global__ __launch_bounds__(256) void wtrans_all(
    const float* __restrict__ Wq, const float* __restrict__ Wk,
    const float* __restrict__ Wv, const float* __restrict__ Wg,
    const float* __restrict__ Wo, u16* __restrict__ WTa, u16* __restrict__ WoT)
{
  __shared__ float t[32][33];
  const int id = blockIdx.x;
  const float* src; u16* dst; int R, C, local;
  if (id < 1024)      { src = Wq; dst = WTa;           R = 1024; C = 1024; local = id; }
  else if (id < 2048) { src = Wk; dst = WTa + 1048576; R = 1024; C = 1024; local = id - 1024; }
  else if (id < 4096) { src = Wv; dst = WTa + 2097152; R = 1024; C = 2048; local = id - 2048; }
  else if (id < 6144) { src = Wg; dst = WTa + 4194304; R = 1024; C = 2048; local = id - 4096; }
  else                { src = Wo; dst = WoT;           R = 2048; C = 1024; local = id - 6144; }
  const int nx = C >> 5;
  const int c0 = (local % nx) * 32, r0 = (local / nx) * 32;
  const int lx = threadIdx.x & 31, ly = threadIdx.x >> 5;
#pragma unroll
  for (int i = 0; i < 32; i += 8)
    t[ly + i][lx] = src[(size_t)(r0 + ly + i) * C + c0 + lx];
  __syncthreads();
#pragma unroll
  for (int i = 0; i < 32; i += 8)
    dst[(size_t)(c0 + ly + i) * R + r0 + lx] = f2b(t[lx][ly + i]);
}

// both activation transposes fused: kt->ktT, vr->vT
__global__ __launch_bounds__(256) void trans_all(
    const u16* __restrict__ kt, u16* __restrict__ ktT,
    const u16* __restrict__ vr, u16* __restrict__ vT)
{
  __shared__ u16 t[32][33];
  const int id = blockIdx.x;
  const u16* in; u16* out; int R = 2048, C, z, local;
  if (id < 4096) { in = kt; out = ktT; C = 256;  z = id >> 9;  local = id & 511; }
  else { const int i2 = id - 4096; in = vr; out = vT; C = 512; z = i2 >> 10; local = i2 & 1023; }
  const int nx = C >> 5;
  const int c0 = (local % nx) * 32, r0 = (local / nx) * 32;
  const size_t boff = (size_t)z * R * C;
  const int lx = threadIdx.x & 31, ly = threadIdx.x >> 5;
#pragma unroll
  for (int i = 0; i < 32; i += 8)
    t[ly + i][lx] = in[boff + (size_t)(r0 + ly + i) * C + c0 + lx];
  __syncthreads();
#pragma unroll
  for (int i = 0; i < 32; i += 8)
    out[boff + (size_t)(c0 + ly + i) * R + r0 + lx] = t[lx][ly + i];
}

// ---------------- low-rank gate part 1: tmp[4096,16] = x @ w1 ----------------
__global__ __launch_bounds__(256) void lowrank1(
    const float* __restrict__ x, const float* __restrict__ w1,
    float* __restrict__ tmp)
{
  const int idx = blockIdx.x * 256 + threadIdx.x;
  const int m = idx >> 4, i = idx & 15;
  const float* xr = x + (size_t)m * 1024;
  float acc = 0.f;
#pragma unroll 4
  for (int kk = 0; kk < 1024; kk += 4) {
    const float4 xv = *(const float4*)(xr + kk);
    acc = fmaf(xv.x, w1[(kk + 0) * 16 + i], acc);
    acc = fmaf(xv.y, w1[(kk + 1) * 16 + i], acc);
    acc = fmaf(xv.z, w1[(kk + 2) * 16 + i], acc);
    acc = fmaf(xv.w, w1[(kk + 3) * 16 + i], acc);
  }
  tmp[idx] = acc;
}

// -------- gate cumsum -> bf16 decay factors dq = e^B, dk = e^-B; Dc = e^B_end
__global__ __launch_bounds__(256) void gate_cum(
    const float* __restrict__ tmp, const float* __restrict__ w2,
    const float* __restrict__ bias, u16* __restrict__ dq, u16* __restrict__ dk,
    float* __restrict__ Dc)
{
  __shared__ float ls_t[2048];   // tmp slice for this (b, c): 128 t x 16
  const int b = blockIdx.y >> 4, c = blockIdx.y & 15;
  const int h = blockIdx.x;
  const int i = threadIdx.x;
  const int n = h * 256 + i;
  const int bh = b * 4 + h;
  const float* tp = tmp + ((size_t)(b * 2048 + c * 128)) * 16;
#pragma unroll
  for (int r = 0; r < 8; ++r) ls_t[r * 256 + threadIdx.x] = tp[r * 256 + threadIdx.x];
  __syncthreads();
  float w2c[16];
#pragma unroll
  for (int r = 0; r < 16; ++r) w2c[r] = w2[r * 1024 + n];
  const float bn = bias[n];
  const size_t base = ((size_t)bh * 2048 + c * 128) * 256 + i;
  float B = 0.f;
  for (int t = 0; t < 128; ++t) {
    float gl = bn;
    const float* tr = ls_t + t * 16;
#pragma unroll
    for (int r = 0; r < 16; ++r) gl = fmaf(tr[r], w2c[r], gl);
    const float ls = fminf(gl, 0.f) - log1pf(expf(-fabsf(gl)));
    B += ls * 0.0625f;
    const float eB = expf(B);
    dq[base + (size_t)t * 256] = f2b(eB);
    dk[base + (size_t)t * 256] = f2b(1.f / eB);
  }
  Dc[(bh * 16 + c) * 256 + i] = expf(B);
}

// ---------------- fused projections: xb[4096,1024] @ [Wq|Wk|Wv|Wg] ----------
__global__ __launch_bounds__(256) void proj_all(
    const u16* __restrict__ xb, const u16* __restrict__ WT,
    const u16* __restrict__ dq, const u16* __restrict__ dk,
    u16* __restrict__ qt, u16* __restrict__ kt,
    u16* __restrict__ vr, u16* __restrict__ gpre)
{
  __shared__ __align__(16) u16 S[18432];
  u16* As = S; u16* Bs = S + 8192;
  // XCD-chunked swizzle, n-fast within XCD
  const int id = blockIdx.x;
  const int xcd = id & 7, jb = id >> 3;
  const int m0 = (jb / 6) * 128;
  const int n0 = (xcd * 6 + (jb % 6)) * 128;
  f4v acc[4][4];
#pragma unroll
  for (int zi = 0; zi < 4; ++zi)
#pragma unroll
    for (int zj = 0; zj < 4; ++zj) acc[zi][zj] = (f4v){0.f, 0.f, 0.f, 0.f};
  gemm_core(xb + (size_t)m0 * 1024, 1024, WT + (size_t)n0 * 1024, 1024, 1024,
            As, Bs, acc);
  epi_loop(S, acc, [&](int r, int c0, s8v vv) {
    const int m = m0 + r;
    const int n = n0 + c0;
    const int bb = m >> 11;
    const int t = m & 2047;
    if (n0 < 1024) {
      const int bh = bb * 4 + (n >> 8);
      const int i = n & 255;
      const size_t off = ((size_t)bh * 2048 + t) * 256 + i;
      const s8v dv = *(const s8v*)(dq + off);
      s8v o8;
#pragma unroll
      for (int e = 0; e < 8; ++e)
        o8[e] = (short)f2b(b2f((u16)vv[e]) * 0.0625f * b2f((u16)dv[e]));
      *(s8v*)(qt + off) = o8;
    } else if (n0 < 2048) {
      const int nn = n - 1024;
      const int bh = bb * 4 + (nn >> 8);
      const int i = nn & 255;
      const size_t off = ((size_t)bh * 2048 + t) * 256 + i;
      const s8v dv = *(const s8v*)(dk + off);
      s8v o8;
#pragma unroll
      for (int e = 0; e < 8; ++e)
        o8[e] = (short)f2b(b2f((u16)vv[e]) * b2f((u16)dv[e]));
      *(s8v*)(kt + off) = o8;
    } else if (n0 < 4096) {
      const int nn = n - 2048;
      const int bh = bb * 4 + (nn >> 9);
      const int jj = nn & 511;
      *(s8v*)(vr + ((size_t)bh * 2048 + t) * 512 + jj) = vv;
    } else {
      *(s8v*)(gpre + (size_t)m * 2048 + (n - 4096)) = vv;
    }
  });
}

// ------- merged scan GEMMs: x<8 -> chunk_state tile, x==8 -> qk_causal ------
__global__ __launch_bounds__(256) void scan_gemms(
    const u16* __restrict__ vT, const u16* __restrict__ ktT,
    const u16* __restrict__ qt, const u16* __restrict__ kt,
    u16* __restrict__ UT, u16* __restrict__ Aw)
{
  __shared__ __align__(16) u16 S[18432];
  u16* As = S; u16* Bs = S + 8192;
  const int bhc = blockIdx.y, bh = bhc >> 4, c = bhc & 15;
  f4v acc[4][4];
#pragma unroll
  for (int zi = 0; zi < 4; ++zi)
#pragma unroll
    for (int zj = 0; zj < 4; ++zj) acc[zi][zj] = (f4v){0.f, 0.f, 0.f, 0.f};
  if (blockIdx.x < 8) {
    const int mt = blockIdx.x >> 1, nt = blockIdx.x & 1;
    gemm_core(vT + ((size_t)bh * 512 + mt * 128) * 2048 + c * 128, 2048,
              ktT + ((size_t)bh * 256 + nt * 128) * 2048 + c * 128, 2048, 128,
              As, Bs, acc);
    epi_loop(S, acc, [&](int r, int c0, s8v vv) {
      const int j = mt * 128 + r;
      const int i = nt * 128 + c0;
      *(s8v*)(UT + (((size_t)(bh * 512 + j)) * 16 + c) * 256 + i) = vv;
    });
  } else {
    const size_t base = ((size_t)bh * 2048 + c * 128) * 256;
    gemm_core(qt + base, 256, kt + base, 256, 256, As, Bs, acc);
    u16* Ap = Aw + (size_t)bhc * 16384;
    epi_loop(S, acc, [&](int r, int c0, s8v vv) {
      s8v o8;
#pragma unroll
      for (int e = 0; e < 8; ++e)
        o8[e] = (c0 + e <= r) ? vv[e] : (short)0;
      *(s8v*)(Ap + r * 128 + c0) = o8;
    });
  }
}

// ------ serial inter-chunk scan, in place on UT (bf16, fp32 accum) ----------
__global__ __launch_bounds__(256) void state_scan(
    u16* __restrict__ UT, const float* __restrict__ Dc)
{
  const int blk = blockIdx.x;               // 4096 = bh*512 + j
  const int bh = blk >> 9, j = blk & 511;
  const int i = threadIdx.x;
  u16* Up = UT + ((size_t)(bh * 512 + j)) * 16 * 256 + i;
  const float* Dp = Dc + bh * 16 * 256 + i;
  float Sa = 0.f;
  for (int c = 0; c < 16; ++c) {
    const float u = b2f(Up[c * 256]);
    Up[c * 256] = f2b(Sa);
    Sa = Dp[c * 256] * (Sa + u);
  }
}

// -------- ob = Aw @ V + qt @ S  (per bhc, 128-col tile of HV) ---------------
__global__ __launch_bounds__(256) void intra_k(
    const u16* __restrict__ Aw, const u16* __restrict__ qt,
    const u16* __restrict__ vT, const u16* __restrict__ UT, u16* __restrict__ ob)
{
  __shared__ __align__(16) u16 S[18432];
  u16* As = S; u16* Bs = S + 8192;
  const int jt = blockIdx.x;
  const int bhc = blockIdx.y, bh = bhc >> 4, c = bhc & 15;
  f4v acc[4][4];
#pragma unroll
  for (int zi = 0; zi < 4; ++zi)
#pragma unroll
    for (int zj = 0; zj < 4; ++zj) acc[zi][zj] = (f4v){0.f, 0.f, 0.f, 0.f};
  gemm_core(Aw + (size_t)bhc * 16384, 128,
            vT + ((size_t)bh * 512 + jt * 128) * 2048 + c * 128, 2048, 128,
            As, Bs, acc);
  gemm_core(qt + ((size_t)bh * 2048 + c * 128) * 256, 256,
            UT + ((size_t)(bh * 512 + jt * 128)) * 4096 + (size_t)c * 256, 4096, 256,
            As, Bs, acc);
  const int b = bh >> 2, h = bh & 3;
  epi_loop(S, acc, [&](int r, int c0, s8v vv) {
    const int t = c * 128 + r;
    const int j = jt * 128 + c0;
    *(s8v*)(ob + ((size_t)(b * 2048 + t)) * 2048 + h * 512 + j) = vv;
  });
}

// ---------------- group RMSNorm (512) + SiLU gate, in place on ob -----------
__global__ __launch_bounds__(256) void rms_silu(
    u16* __restrict__ o, const u16* __restrict__ gpre, const float* __restrict__ w)
{
  const int grp = blockIdx.x * 4 + (threadIdx.x >> 6);
  const int lane = threadIdx.x & 63;
  const size_t base = (size_t)(grp >> 2) * 2048 + (grp & 3) * 512;
  float xv[8];
  float ss = 0.f;
#pragma unroll
  for (int i = 0; i < 8; ++i) {
    xv[i] = b2f(o[base + i * 64 + lane]);
    ss = fmaf(xv[i], xv[i], ss);
  }
#pragma unroll
  for (int off = 1; off < 64; off <<= 1) ss += __shfl_xor(ss, off, 64);
  const float r = rsqrtf(ss * (1.f / 512.f) + 1e-5f);
#pragma unroll
  for (int i = 0; i < 8; ++i) {
    const int cidx = i * 64 + lane;
    const float gp = b2f(gpre[base + cidx]);
    const float sig = 1.f / (1.f + expf(-gp));
    o[base + cidx] = f2b(xv[i] * r * w[cidx] * gp * sig);
  }
}

// ---------------- final: out = ob @ Wo, split-K=2 into pout -----------------
__global__ __launch_bounds__(256) void gemm_out(
    const u16* __restrict__ ob, const u16* __restrict__ WoT,
    float* __restrict__ pout)
{
  __shared__ __align__(16) u16 S[18432];
  u16* As = S; u16* Bs = S + 8192;
  const int id = blockIdx.x;                 // 512 blocks, 64 per XCD
  const int wg = (id & 7) * 64 + (id >> 3);
  const int ks = wg >> 8;                    // K-half
  const int tt = wg & 255;
  const int m0 = (tt & 31) * 128, n0 = (tt >> 5) * 128;
  f4v acc[4][4];
#pragma unroll
  for (int zi = 0; zi < 4; ++zi)
#pragma unroll
    for (int zj = 0; zj < 4; ++zj) acc[zi][zj] = (f4v){0.f, 0.f, 0.f, 0.f};
  gemm_core(ob + (size_t)m0 * 2048 + ks * 1024, 2048,
            WoT + (size_t)n0 * 2048 + ks * 1024, 2048, 1024, As, Bs, acc);
  const int tid = threadIdx.x;
  const int ln = tid & 63, wv = tid >> 6;
  const int wr = wv >> 1, wc = wv & 1;
  float* po = pout + (size_t)ks * 4194304;
#pragma unroll
  for (int mf = 0; mf < 4; ++mf)
#pragma unroll
    for (int nf = 0; nf < 4; ++nf)
#pragma unroll
      for (int r = 0; r < 4; ++r) {
        const int m = m0 + wr * 64 + mf * 16 + ((ln >> 4) << 2) + r;
        const int n = n0 + wc * 64 + nf * 16 + (ln & 15);
        po[(size_t)m * 1024 + n] = acc[mf][nf][r];
      }
}

__global__ __launch_bounds__(256) void reduce_out(
    const float* __restrict__ p, float* __restrict__ out)
{
  const int i = blockIdx.x * 256 + threadIdx.x;   // float4 granularity
  const float4 a = ((const float4*)p)[i];
  const float4 b = ((const float4*)(p + 4194304))[i];
  ((float4*)out)[i] = make_float4(a.x + b.x, a.y + b.y, a.z + b.z, a.w + b.w);
}

extern "C" void kernel_launch(void* const* d_in, const int* in_sizes, int n_in,
                              void* d_out, int out_size, void* d_ws, size_t ws_size,
                              hipStream_t stream) {
  const float* x    = (const float*)d_in[0];
  const float* Wq   = (const float*)d_in[1];
  const float* Wk   = (const float*)d_in[2];
  const float* Wv   = (const float*)d_in[3];
  const float* Wg   = (const float*)d_in[4];
  const float* w1   = (const float*)d_in[5];
  const float* w2   = (const float*)d_in[6];
  const float* gb   = (const float*)d_in[7];
  const float* Wo   = (const float*)d_in[8];
  const float* rmsw = (const float*)d_in[9];
  float* out = (float*)d_out;

  char* W = (char*)d_ws;
  u16*   xb   = (u16*)W;   W += (size_t)8  << 20;   // [4096][1024]
  u16*   WTa  = (u16*)W;   W += (size_t)12 << 20;   // [6144][1024]
  u16*   WoT  = (u16*)W;   W += (size_t)4  << 20;   // [1024][2048]
  u16*   qt   = (u16*)W;   W += (size_t)8  << 20;   // [8][2048][256]
  u16*   kt   = (u16*)W;   W += (size_t)8  << 20;
  u16*   vr   = (u16*)W;   W += (size_t)16 << 20;   // [8][2048][512]
  u16*   vT   = (u16*)W;   W += (size_t)16 << 20;   // [8][512][2048]
  u16*   ktT  = (u16*)W;   W += (size_t)8  << 20;   // [8][256][2048]
  u16*   gpre = (u16*)W;   W += (size_t)16 << 20;   // [4096][2048]
  float* tmp  = (float*)W; W += (size_t)256 << 10;  // [4096][16]
  float* Dc   = (float*)W; W += (size_t)128 << 10;  // [8][16][256]
  u16*   dq   = (u16*)W;   W += (size_t)8  << 20;   // [8][2048][256] bf16 e^B
  u16*   dk   = (u16*)W;   W += (size_t)8  << 20;   // e^-B
  u16*   UT   = (u16*)W;   W += (size_t)32 << 20;   // [8][512][16][256]
  u16*   Aw   = (u16*)W;   W += (size_t)4  << 20;   // [128][128][128]
  u16*   ob   = (u16*)W;   W += (size_t)16 << 20;   // [4096][2048]
  float* pout = (float*)W; W += (size_t)32 << 20;   // [2][4096][1024]

  // gate pipeline first (dq/dk needed by proj_all)
  hipLaunchKernelGGL(lowrank1, dim3(256), dim3(256), 0, stream, x, w1, tmp);
  hipLaunchKernelGGL(gate_cum, dim3(4, 32), dim3(256), 0, stream,
                     tmp, w2, gb, dq, dk, Dc);

  // bf16 conversions / weight transposes (fused)
  hipLaunchKernelGGL(cast_b, dim3(4096), dim3(256), 0, stream, x, xb);
  hipLaunchKernelGGL(wtrans_all, dim3(8192), dim3(256), 0, stream,
                     Wq, Wk, Wv, Wg, Wo, WTa, WoT);

  // fused q/k/v/g projections with decay applied in epilogue
  hipLaunchKernelGGL(proj_all, dim3(1536), dim3(256), 0, stream,
                     xb, WTa, dq, dk, qt, kt, vr, gpre);

  // layout transposes for the scan GEMMs (fused)
  hipLaunchKernelGGL(trans_all, dim3(12288), dim3(256), 0, stream,
                     kt, ktT, vr, vT);

  // chunked scan: (chunk_state || qk_causal) -> state_scan -> intra
  hipLaunchKernelGGL(scan_gemms, dim3(9, 128), dim3(256), 0, stream,
                     vT, ktT, qt, kt, UT, Aw);
  hipLaunchKernelGGL(state_scan, dim3(4096), dim3(256), 0, stream, UT, Dc);
  hipLaunchKernelGGL(intra_k, dim3(4, 128), dim3(256), 0, stream, Aw, qt, vT, UT, ob);

  // group RMSNorm + SiLU gate (in place), then output projection (split-K)
  hipLaunchKernelGGL(rms_silu, dim3(4096), dim3(256), 0, stream, ob, gpre, rmsw);
  hipLaunchKernelGGL(gemm_out, dim3(512), dim3(256), 0, stream, ob, WoT, pout);
  hipLaunchKernelGGL(reduce_out, dim3(4096), dim3(256), 0, stream, pout, out);
}

// Round 10
// 258.960 us; speedup vs baseline: 10.8537x; 1.0712x over previous
//
#include <hip/hip_runtime.h>
#include <cstdint>
#include <cstddef>

// GLA forward, bf16 MFMA pipeline: 2-slot counted-vmcnt loop, XOR-swizzled LDS,
// coalesced LDS-roundtrip epilogues; v emitted transposed directly from proj.
// B=2, T=2048, D=1024, H=4, HK=256, HV=512, DK=1024, DV=2048, LR=16, CHUNK=128

typedef unsigned short u16;
typedef __attribute__((ext_vector_type(8))) short s8v;   // 8 x bf16 (4 VGPR)
typedef __attribute__((ext_vector_type(4))) short s4v;   // 4 x bf16 (8B)
typedef __attribute__((ext_vector_type(4))) float f4v;   // MFMA accumulator

__device__ __forceinline__ u16 f2b(float f) {
  unsigned u = __builtin_bit_cast(unsigned, f);
  unsigned r = u + 0x7FFFu + ((u >> 16) & 1u);   // RNE
  return (u16)(r >> 16);
}
__device__ __forceinline__ float b2f(u16 h) {
  unsigned u = ((unsigned)h) << 16;
  return __builtin_bit_cast(float, u);
}

// async global->LDS, 16B per lane; LDS dest is wave-uniform base + lane*16
__device__ __forceinline__ void cp16(const void* g, void* l) {
  __builtin_amdgcn_global_load_lds(
      (const __attribute__((address_space(1))) unsigned int*)g,
      (__attribute__((address_space(3))) unsigned int*)l, 16, 0, 0);
}

// ---- shared MFMA core: C[128x128] += A[128xK] * BT[128xK]^T, bf16, BK=32 ----
// LDS tile logical [128 rows][32 cols]; element (R, quarter Q) stored at
// physical quarter Q ^ ((R>>1)&3). Stage keeps LDS dest linear; global SOURCE
// is quarter-permuted (rule #21 both-sides). 2-slot double buffer,
// counted vmcnt(4) so next tile's loads stay in flight across barriers.
__device__ __forceinline__ void stage_tile(const u16* g, int ld, u16* lds,
                                           int wv, int ln) {
  const int q = (ln & 3) ^ ((ln >> 3) & 3);
#pragma unroll
  for (int i = 0; i < 2; ++i) {
    const int c = wv * 2 + i;                       // 1KB chunk id 0..7
    const u16* src = g + (size_t)(c * 16 + (ln >> 2)) * ld + q * 8;
    cp16(src, lds + c * 512);
  }
}

__device__ __forceinline__ void gemm_core(
    const u16* __restrict__ A, int lda, const u16* __restrict__ BT, int ldb,
    int K, u16* As, u16* Bs, f4v acc[4][4])
{
  const int tid = threadIdx.x;
  const int ln = tid & 63, wv = tid >> 6;
  const int arow = (wv >> 1) * 64 + (ln & 15);
  const int brow = (wv & 1) * 64 + (ln & 15);
  const int koff = (((ln >> 4) ^ ((ln >> 1) & 3)) * 8);
  const int nt = K >> 5;                     // #K-tiles, >= 4 for all callers
  // prologue: fill both slots (8 loads per wave in flight)
  stage_tile(A, lda, As, wv, ln);
  stage_tile(BT, ldb, Bs, wv, ln);
  stage_tile(A + 32, lda, As + 4096, wv, ln);
  stage_tile(BT + 32, ldb, Bs + 4096, wv, ln);
  int slot = 0;
  for (int t = 0; t < nt; ++t) {
    if (t + 1 < nt) asm volatile("s_waitcnt vmcnt(4)" ::: "memory");
    else            asm volatile("s_waitcnt vmcnt(0)" ::: "memory");
    __builtin_amdgcn_s_barrier();            // all waves: slot data ready
    __builtin_amdgcn_sched_barrier(0);
    const u16* Ab = As + slot * 4096;
    const u16* Bb = Bs + slot * 4096;
    s8v af[4], bf[4];
#pragma unroll
    for (int f = 0; f < 4; ++f)
      af[f] = *(const s8v*)(Ab + (arow + f * 16) * 32 + koff);
#pragma unroll
    for (int f = 0; f < 4; ++f)
      bf[f] = *(const s8v*)(Bb + (brow + f * 16) * 32 + koff);
#pragma unroll
    for (int mf = 0; mf < 4; ++mf)
#pragma unroll
      for (int nf = 0; nf < 4; ++nf)
        acc[mf][nf] = __builtin_amdgcn_mfma_f32_16x16x32_bf16(
            af[mf], bf[nf], acc[mf][nf], 0, 0, 0);
    __builtin_amdgcn_sched_barrier(0);
    __builtin_amdgcn_s_barrier();            // all waves done reading slot
    if (t + 2 < nt) {                        // refill freed slot
      stage_tile(A + (t + 2) * 32, lda, As + slot * 4096, wv, ln);
      stage_tile(BT + (t + 2) * 32, ldb, Bs + slot * 4096, wv, ln);
    }
    slot ^= 1;
  }
}

// ---- epilogue: fragments -> LDS (bf16, row stride 72 = 16B aligned) --------
// Normal: tile element (r,c) at quad((r>>6)<<1 | c>>6)*4608 + (r&63)*72+(c&63)
__device__ __forceinline__ void frag_to_lds(u16* S, const f4v acc[4][4],
                                            int ln, int wv) {
  u16* q = S + wv * 4608;
#pragma unroll
  for (int mf = 0; mf < 4; ++mf)
#pragma unroll
    for (int nf = 0; nf < 4; ++nf)
#pragma unroll
      for (int r = 0; r < 4; ++r)
        q[(mf * 16 + ((ln >> 4) << 2) + r) * 72 + nf * 16 + (ln & 15)] =
            f2b(acc[mf][nf][r]);
}

// Transposed: T(c,r) at quad((c>>6)<<1 | r>>6)*4608 + (c&63)*72 + (r&63).
// Lane's 4 row-consecutive values -> 4 col-consecutive -> one 8B ds_write.
__device__ __forceinline__ void frag_to_lds_T(u16* S, const f4v acc[4][4],
                                              int ln, int wv) {
  const int wr = wv >> 1, wc = wv & 1;
  u16* q = S + ((wc << 1) + wr) * 4608;
#pragma unroll
  for (int mf = 0; mf < 4; ++mf)
#pragma unroll
    for (int nf = 0; nf < 4; ++nf) {
      const int cl = nf * 16 + (ln & 15);
      const int rl = mf * 16 + ((ln >> 4) << 2);
      s4v o4;
#pragma unroll
      for (int r = 0; r < 4; ++r) o4[r] = (short)f2b(acc[mf][nf][r]);
      *(s4v*)(q + cl * 72 + rl) = o4;
    }
}

// epilogue part 2: 8 passes, 16 threads/row, one b128 LDS read per thread,
// then the caller's functor issues one coalesced 16B global store.
template <typename F>
__device__ __forceinline__ void epi_loop(u16* S, const f4v acc[4][4], F f) {
  const int tid = threadIdx.x;
  frag_to_lds(S, acc, tid & 63, tid >> 6);
  __syncthreads();
#pragma unroll
  for (int p = 0; p < 8; ++p) {
    const int r = p * 16 + (tid >> 4);
    const int c0 = (tid & 15) * 8;
    const int quad = ((r >> 6) << 1) + (c0 >> 6);
    s8v vv = *(const s8v*)(S + quad * 4608 + (r & 63) * 72 + (c0 & 63));
    f(r, c0, vv);
  }
}

// transposed variant: r is the ORIGINAL COLUMN, c0 the ORIGINAL ROW base.
template <typename F>
__device__ __forceinline__ void epi_loop_T(u16* S, const f4v acc[4][4], F f) {
  const int tid = threadIdx.x;
  frag_to_lds_T(S, acc, tid & 63, tid >> 6);
  __syncthreads();
#pragma unroll
  for (int p = 0; p < 8; ++p) {
    const int r = p * 16 + (tid >> 4);        // column index 0..127
    const int c0 = (tid & 15) * 8;            // row base 0..120
    const int quad = ((r >> 6) << 1) + (c0 >> 6);
    s8v vv = *(const s8v*)(S + quad * 4608 + (r & 63) * 72 + (c0 & 63));
    f(r, c0, vv);
  }
}

// -------- fused bf16 cast of x + all 5 weight transposes --------------------
__global__ __launch_bounds__(256) void castw_all(
    const float* __restrict__ x, const float* __restrict__ Wq,
    const float* __restrict__ Wk, const float* __restrict__ Wv,
    const float* __restrict__ Wg, const float* __restrict__ Wo,
    u16* __restrict__ xb, u16* __restrict__ WTa, u16* __restrict__ WoT)
{
  __shared__ float t[32][33];
  const int id = blockIdx.x;
  if (id < 4096) {                      // cast x -> xb (float4 per thread)
    const int i = id * 256 + threadIdx.x;
    const float4 v = ((const float4*)x)[i];
    u16* p = xb + i * 4;
    p[0] = f2b(v.x); p[1] = f2b(v.y); p[2] = f2b(v.z); p[3] = f2b(v.w);
    return;
  }
  const int wid = id - 4096;
  const float* src; u16* dst; int R, C, local;
  if (wid < 1024)      { src = Wq; dst = WTa;           R = 1024; C = 1024; local = wid; }
  else if (wid < 2048) { src = Wk; dst = WTa + 1048576; R = 1024; C = 1024; local = wid - 1024; }
  else if (wid < 4096) { src = Wv; dst = WTa + 2097152; R = 1024; C = 2048; local = wid - 2048; }
  else if (wid < 6144) { src = Wg; dst = WTa + 4194304; R = 1024; C = 2048; local = wid - 4096; }
  else                 { src = Wo; dst = WoT;           R = 2048; C = 1024; local = wid - 6144; }
  const int nx = C >> 5;
  const int c0 = (local % nx) * 32, r0 = (local / nx) * 32;
  const int lx = threadIdx.x & 31, ly = threadIdx.x >> 5;
#pragma unroll
  for (int i = 0; i < 32; i += 8)
    t[ly + i][lx] = src[(size_t)(r0 + ly + i) * C + c0 + lx];
  __syncthreads();
#pragma unroll
  for (int i = 0; i < 32; i += 8)
    dst[(size_t)(c0 + ly + i) * R + r0 + lx] = f2b(t[lx][ly + i]);
}

// kt [bh][2048][256] -> ktT [bh][256][2048]
__global__ __launch_bounds__(256) void trans_kt(
    const u16* __restrict__ kt, u16* __restrict__ ktT)
{
  __shared__ u16 t[32][33];
  const int id = blockIdx.x;                  // 4096
  const int z = id >> 9, local = id & 511;
  const int c0 = (local & 7) * 32, r0 = (local >> 3) * 32;
  const size_t boff = (size_t)z * 2048 * 256;
  const int lx = threadIdx.x & 31, ly = threadIdx.x >> 5;
#pragma unroll
  for (int i = 0; i < 32; i += 8)
    t[ly + i][lx] = kt[boff + (size_t)(r0 + ly + i) * 256 + c0 + lx];
  __syncthreads();
#pragma unroll
  for (int i = 0; i < 32; i += 8)
    ktT[boff + (size_t)(c0 + ly + i) * 2048 + r0 + lx] = t[lx][ly + i];
}

// ---------------- low-rank gate part 1: tmp[4096,16] = x @ w1 ----------------
__global__ __launch_bounds__(256) void lowrank1(
    const float* __restrict__ x, const float* __restrict__ w1,
    float* __restrict__ tmp)
{
  const int idx = blockIdx.x * 256 + threadIdx.x;
  const int m = idx >> 4, i = idx & 15;
  const float* xr = x + (size_t)m * 1024;
  float acc = 0.f;
#pragma unroll 4
  for (int kk = 0; kk < 1024; kk += 4) {
    const float4 xv = *(const float4*)(xr + kk);
    acc = fmaf(xv.x, w1[(kk + 0) * 16 + i], acc);
    acc = fmaf(xv.y, w1[(kk + 1) * 16 + i], acc);
    acc = fmaf(xv.z, w1[(kk + 2) * 16 + i], acc);
    acc = fmaf(xv.w, w1[(kk + 3) * 16 + i], acc);
  }
  tmp[idx] = acc;
}

// -------- gate cumsum -> bf16 decay factors dq = e^B, dk = e^-B; Dc = e^B_end
__global__ __launch_bounds__(256) void gate_cum(
    const float* __restrict__ tmp, const float* __restrict__ w2,
    const float* __restrict__ bias, u16* __restrict__ dq, u16* __restrict__ dk,
    float* __restrict__ Dc)
{
  __shared__ float ls_t[2048];   // tmp slice for this (b, c): 128 t x 16
  const int b = blockIdx.y >> 4, c = blockIdx.y & 15;
  const int h = blockIdx.x;
  const int i = threadIdx.x;
  const int n = h * 256 + i;
  const int bh = b * 4 + h;
  const float* tp = tmp + ((size_t)(b * 2048 + c * 128)) * 16;
#pragma unroll
  for (int r = 0; r < 8; ++r) ls_t[r * 256 + threadIdx.x] = tp[r * 256 + threadIdx.x];
  __syncthreads();
  float w2c[16];
#pragma unroll
  for (int r = 0; r < 16; ++r) w2c[r] = w2[r * 1024 + n];
  const float bn = bias[n];
  const size_t base = ((size_t)bh * 2048 + c * 128) * 256 + i;
  float B = 0.f;
  for (int t = 0; t < 128; ++t) {
    float gl = bn;
    const float* tr = ls_t + t * 16;
#pragma unroll
    for (int r = 0; r < 16; ++r) gl = fmaf(tr[r], w2c[r], gl);
    const float ls = fminf(gl, 0.f) - log1pf(expf(-fabsf(gl)));
    B += ls * 0.0625f;
    const float eB = expf(B);
    dq[base + (size_t)t * 256] = f2b(eB);
    dk[base + (size_t)t * 256] = f2b(1.f / eB);
  }
  Dc[(bh * 16 + c) * 256 + i] = expf(B);
}

// ---------------- fused projections: xb[4096,1024] @ [Wq|Wk|Wv|Wg] ----------
// q/k: decay fused, row-major. v: written TRANSPOSED directly to vT[bh][j][t].
__global__ __launch_bounds__(256) void proj_all(
    const u16* __restrict__ xb, const u16* __restrict__ WT,
    const u16* __restrict__ dq, const u16* __restrict__ dk,
    u16* __restrict__ qt, u16* __restrict__ kt,
    u16* __restrict__ vT, u16* __restrict__ gpre)
{
  __shared__ __align__(16) u16 S[18432];
  u16* As = S; u16* Bs = S + 8192;
  // XCD-chunked swizzle, n-fast within XCD
  const int id = blockIdx.x;
  const int xcd = id & 7, jb = id >> 3;
  const int m0 = (jb / 6) * 128;
  const int n0 = (xcd * 6 + (jb % 6)) * 128;
  f4v acc[4][4];
#pragma unroll
  for (int zi = 0; zi < 4; ++zi)
#pragma unroll
    for (int zj = 0; zj < 4; ++zj) acc[zi][zj] = (f4v){0.f, 0.f, 0.f, 0.f};
  gemm_core(xb + (size_t)m0 * 1024, 1024, WT + (size_t)n0 * 1024, 1024, 1024,
            As, Bs, acc);
  const int bb = m0 >> 11;              // batch (tile is within one b)
  const int t0 = m0 & 2047;
  if (n0 < 1024) {
    epi_loop(S, acc, [&](int r, int c0, s8v vv) {
      const int t = t0 + r;
      const int n = n0 + c0;
      const int bh = bb * 4 + (n >> 8);
      const size_t off = ((size_t)bh * 2048 + t) * 256 + (n & 255);
      const s8v dv = *(const s8v*)(dq + off);
      s8v o8;
#pragma unroll
      for (int e = 0; e < 8; ++e)
        o8[e] = (short)f2b(b2f((u16)vv[e]) * 0.0625f * b2f((u16)dv[e]));
      *(s8v*)(qt + off) = o8;
    });
  } else if (n0 < 2048) {
    epi_loop(S, acc, [&](int r, int c0, s8v vv) {
      const int t = t0 + r;
      const int nn = n0 + c0 - 1024;
      const int bh = bb * 4 + (nn >> 8);
      const size_t off = ((size_t)bh * 2048 + t) * 256 + (nn & 255);
      const s8v dv = *(const s8v*)(dk + off);
      s8v o8;
#pragma unroll
      for (int e = 0; e < 8; ++e)
        o8[e] = (short)f2b(b2f((u16)vv[e]) * b2f((u16)dv[e]));
      *(s8v*)(kt + off) = o8;
    });
  } else if (n0 < 4096) {
    const int nn0 = n0 - 2048;
    const int bh = bb * 4 + (nn0 >> 9);
    const int jj0 = nn0 & 511;
    epi_loop_T(S, acc, [&](int r, int c0, s8v vv) {
      // r = column offset (j), c0 = row base (t)
      *(s8v*)(vT + ((size_t)(bh * 512 + jj0 + r)) * 2048 + t0 + c0) = vv;
    });
  } else {
    epi_loop(S, acc, [&](int r, int c0, s8v vv) {
      *(s8v*)(gpre + (size_t)(m0 + r) * 2048 + (n0 + c0 - 4096)) = vv;
    });
  }
}

// ------- merged scan GEMMs: x<8 -> chunk_state tile, x==8 -> qk_causal ------
__global__ __launch_bounds__(256) void scan_gemms(
    const u16* __restrict__ vT, const u16* __restrict__ ktT,
    const u16* __restrict__ qt, const u16* __restrict__ kt,
    u16* __restrict__ UT, u16* __restrict__ Aw)
{
  __shared__ __align__(16) u16 S[18432];
  u16* As = S; u16* Bs = S + 8192;
  const int bhc = blockIdx.y, bh = bhc >> 4, c = bhc & 15;
  f4v acc[4][4];
#pragma unroll
  for (int zi = 0; zi < 4; ++zi)
#pragma unroll
    for (int zj = 0; zj < 4; ++zj) acc[zi][zj] = (f4v){0.f, 0.f, 0.f, 0.f};
  if (blockIdx.x < 8) {
    const int mt = blockIdx.x >> 1, nt = blockIdx.x & 1;
    gemm_core(vT + ((size_t)bh * 512 + mt * 128) * 2048 + c * 128, 2048,
              ktT + ((size_t)bh * 256 + nt * 128) * 2048 + c * 128, 2048, 128,
              As, Bs, acc);
    epi_loop(S, acc, [&](int r, int c0, s8v vv) {
      const int j = mt * 128 + r;
      const int i = nt * 128 + c0;
      *(s8v*)(UT + (((size_t)(bh * 512 + j)) * 16 + c) * 256 + i) = vv;
    });
  } else {
    const size_t base = ((size_t)bh * 2048 + c * 128) * 256;
    gemm_core(qt + base, 256, kt + base, 256, 256, As, Bs, acc);
    u16* Ap = Aw + (size_t)bhc * 16384;
    epi_loop(S, acc, [&](int r, int c0, s8v vv) {
      s8v o8;
#pragma unroll
      for (int e = 0; e < 8; ++e)
        o8[e] = (c0 + e <= r) ? vv[e] : (short)0;
      *(s8v*)(Ap + r * 128 + c0) = o8;
    });
  }
}

// ------ serial inter-chunk scan, in place on UT (bf16, fp32 accum) ----------
__global__ __launch_bounds__(256) void state_scan(
    u16* __restrict__ UT, const float* __restrict__ Dc)
{
  const int blk = blockIdx.x;               // 4096 = bh*512 + j
  const int bh = blk >> 9, j = blk & 511;
  const int i = threadIdx.x;
  u16* Up = UT + ((size_t)(bh * 512 + j)) * 16 * 256 + i;
  const float* Dp = Dc + bh * 16 * 256 + i;
  float Sa = 0.f;
  for (int c = 0; c < 16; ++c) {
    const float u = b2f(Up[c * 256]);
    Up[c * 256] = f2b(Sa);
    Sa = Dp[c * 256] * (Sa + u);
  }
}

// -------- ob = Aw @ V + qt @ S  (per bhc, 128-col tile of HV) ---------------
__global__ __launch_bounds__(256) void intra_k(
    const u16* __restrict__ Aw, const u16* __restrict__ qt,
    const u16* __restrict__ vT, const u16* __restrict__ UT, u16* __restrict__ ob)
{
  __shared__ __align__(16) u16 S[18432];
  u16* As = S; u16* Bs = S + 8192;
  const int jt = blockIdx.x;
  const int bhc = blockIdx.y, bh = bhc >> 4, c = bhc & 15;
  f4v acc[4][4];
#pragma unroll
  for (int zi = 0; zi < 4; ++zi)
#pragma unroll
    for (int zj = 0; zj < 4; ++zj) acc[zi][zj] = (f4v){0.f, 0.f, 0.f, 0.f};
  gemm_core(Aw + (size_t)bhc * 16384, 128,
            vT + ((size_t)bh * 512 + jt * 128) * 2048 + c * 128, 2048, 128,
            As, Bs, acc);
  gemm_core(qt + ((size_t)bh * 2048 + c * 128) * 256, 256,
            UT + ((size_t)(bh * 512 + jt * 128)) * 4096 + (size_t)c * 256, 4096, 256,
            As, Bs, acc);
  const int b = bh >> 2, h = bh & 3;
  epi_loop(S, acc, [&](int r, int c0, s8v vv) {
    const int t = c * 128 + r;
    const int j = jt * 128 + c0;
    *(s8v*)(ob + ((size_t)(b * 2048 + t)) * 2048 + h * 512 + j) = vv;
  });
}

// ---------------- group RMSNorm (512) + SiLU gate, in place on ob -----------
__global__ __launch_bounds__(256) void rms_silu(
    u16* __restrict__ o, const u16* __restrict__ gpre, const float* __restrict__ w)
{
  const int grp = blockIdx.x * 4 + (threadIdx.x >> 6);
  const int lane = threadIdx.x & 63;
  const size_t base = (size_t)(grp >> 2) * 2048 + (grp & 3) * 512;
  float xv[8];
  float ss = 0.f;
#pragma unroll
  for (int i = 0; i < 8; ++i) {
    xv[i] = b2f(o[base + i * 64 + lane]);
    ss = fmaf(xv[i], xv[i], ss);
  }
#pragma unroll
  for (int off = 1; off < 64; off <<= 1) ss += __shfl_xor(ss, off, 64);
  const float r = rsqrtf(ss * (1.f / 512.f) + 1e-5f);
#pragma unroll
  for (int i = 0; i < 8; ++i) {
    const int cidx = i * 64 + lane;
    const float gp = b2f(gpre[base + cidx]);
    const float sig = 1.f / (1.f + expf(-gp));
    o[base + cidx] = f2b(xv[i] * r * w[cidx] * gp * sig);
  }
}

// ---------------- final: out = ob @ Wo, split-K=2 into pout -----------------
__global__ __launch_bounds__(256) void gemm_out(
    const u16* __restrict__ ob, const u16* __restrict__ WoT,
    float* __restrict__ pout)
{
  __shared__ __align__(16) u16 S[18432];
  u16* As = S; u16* Bs = S + 8192;
  const int id = blockIdx.x;                 // 512 blocks, 64 per XCD
  const int wg = (id & 7) * 64 + (id >> 3);
  const int ks = wg >> 8;                    // K-half
  const int tt = wg & 255;
  const int m0 = (tt & 31) * 128, n0 = (tt >> 5) * 128;
  f4v acc[4][4];
#pragma unroll
  for (int zi = 0; zi < 4; ++zi)
#pragma unroll
    for (int zj = 0; zj < 4; ++zj) acc[zi][zj] = (f4v){0.f, 0.f, 0.f, 0.f};
  gemm_core(ob + (size_t)m0 * 2048 + ks * 1024, 2048,
            WoT + (size_t)n0 * 2048 + ks * 1024, 2048, 1024, As, Bs, acc);
  const int tid = threadIdx.x;
  const int ln = tid & 63, wv = tid >> 6;
  const int wr = wv >> 1, wc = wv & 1;
  float* po = pout + (size_t)ks * 4194304;
#pragma unroll
  for (int mf = 0; mf < 4; ++mf)
#pragma unroll
    for (int nf = 0; nf < 4; ++nf)
#pragma unroll
      for (int r = 0; r < 4; ++r) {
        const int m = m0 + wr * 64 + mf * 16 + ((ln >> 4) << 2) + r;
        const int n = n0 + wc * 64 + nf * 16 + (ln & 15);
        po[(size_t)m * 1024 + n] = acc[mf][nf][r];
      }
}

__global__ __launch_bounds__(256) void reduce_out(
    const float* __restrict__ p, float* __restrict__ out)
{
  const int i = blockIdx.x * 256 + threadIdx.x;   // float4 granularity
  const float4 a = ((const float4*)p)[i];
  const float4 b = ((const float4*)(p + 4194304))[i];
  ((float4*)out)[i] = make_float4(a.x + b.x, a.y + b.y, a.z + b.z, a.w + b.w);
}

extern "C" void kernel_launch(void* const* d_in, const int* in_sizes, int n_in,
                              void* d_out, int out_size, void* d_ws, size_t ws_size,
                              hipStream_t stream) {
  const float* x    = (const float*)d_in[0];
  const float* Wq   = (const float*)d_in[1];
  const float* Wk   = (const float*)d_in[2];
  const float* Wv   = (const float*)d_in[3];
  const float* Wg   = (const float*)d_in[4];
  const float* w1   = (const float*)d_in[5];
  const float* w2   = (const float*)d_in[6];
  const float* gb   = (const float*)d_in[7];
  const float* Wo   = (const float*)d_in[8];
  const float* rmsw = (const float*)d_in[9];
  float* out = (float*)d_out;

  char* W = (char*)d_ws;
  u16*   xb   = (u16*)W;   W += (size_t)8  << 20;   // [4096][1024]
  u16*   WTa  = (u16*)W;   W += (size_t)12 << 20;   // [6144][1024]
  u16*   WoT  = (u16*)W;   W += (size_t)4  << 20;   // [1024][2048]
  u16*   qt   = (u16*)W;   W += (size_t)8  << 20;   // [8][2048][256]
  u16*   kt   = (u16*)W;   W += (size_t)8  << 20;
  u16*   vT   = (u16*)W;   W += (size_t)16 << 20;   // [8][512][2048]
  u16*   ktT  = (u16*)W;   W += (size_t)8  << 20;   // [8][256][2048]
  u16*   gpre = (u16*)W;   W += (size_t)16 << 20;   // [4096][2048]
  float* tmp  = (float*)W; W += (size_t)256 << 10;  // [4096][16]
  float* Dc   = (float*)W; W += (size_t)128 << 10;  // [8][16][256]
  u16*   dq   = (u16*)W;   W += (size_t)8  << 20;   // [8][2048][256] bf16 e^B
  u16*   dk   = (u16*)W;   W += (size_t)8  << 20;   // e^-B
  u16*   UT   = (u16*)W;   W += (size_t)32 << 20;   // [8][512][16][256]
  u16*   Aw   = (u16*)W;   W += (size_t)4  << 20;   // [128][128][128]
  u16*   ob   = (u16*)W;   W += (size_t)16 << 20;   // [4096][2048]
  float* pout = (float*)W; W += (size_t)32 << 20;   // [2][4096][1024]

  // gate pipeline first (dq/dk needed by proj_all)
  hipLaunchKernelGGL(lowrank1, dim3(256), dim3(256), 0, stream, x, w1, tmp);
  hipLaunchKernelGGL(gate_cum, dim3(4, 32), dim3(256), 0, stream,
                     tmp, w2, gb, dq, dk, Dc);

  // bf16 cast of x + all weight transposes, one kernel
  hipLaunchKernelGGL(castw_all, dim3(12288), dim3(256), 0, stream,
                     x, Wq, Wk, Wv, Wg, Wo, xb, WTa, WoT);

  // fused q/k/v/g projections; v emitted transposed, decay fused
  hipLaunchKernelGGL(proj_all, dim3(1536), dim3(256), 0, stream,
                     xb, WTa, dq, dk, qt, kt, vT, gpre);

  // kt -> ktT (only remaining layout pass)
  hipLaunchKernelGGL(trans_kt, dim3(4096), dim3(256), 0, stream, kt, ktT);

  // chunked scan: (chunk_state || qk_causal) -> state_scan -> intra
  hipLaunchKernelGGL(scan_gemms, dim3(9, 128), dim3(256), 0, stream,
                     vT, ktT, qt, kt, UT, Aw);
  hipLaunchKernelGGL(state_scan, dim3(4096), dim3(256), 0, stream, UT, Dc);
  hipLaunchKernelGGL(intra_k, dim3(4, 128), dim3(256), 0, stream, Aw, qt, vT, UT, ob);

  // group RMSNorm + SiLU gate (in place), then output projection (split-K)
  hipLaunchKernelGGL(rms_silu, dim3(4096), dim3(256), 0, stream, ob, gpre, rmsw);
  hipLaunchKernelGGL(gemm_out, dim3(512), dim3(256), 0, stream, ob, WoT, pout);
  hipLaunchKernelGGL(reduce_out, dim3(4096), dim3(256), 0, stream, pout, out);
}